// Round 7
// baseline (205.179 us; speedup 1.0000x reference)
//
#include <hip/hip_runtime.h>
#include <hip/hip_bf16.h>

typedef __bf16 bf16_t;
typedef __bf16 bf16x8 __attribute__((ext_vector_type(8)));
typedef __bf16 bf16x4 __attribute__((ext_vector_type(4)));
typedef float f32x4 __attribute__((ext_vector_type(4)));
typedef float f32x16 __attribute__((ext_vector_type(16)));

#define NB 2
#define SEQ 2048
#define DMODEL 1024
#define NHEAD 16
#define DHEAD 64

__device__ inline void gload_lds16(const void* g, void* lds) {
  __builtin_amdgcn_global_load_lds((const __attribute__((address_space(1))) void*)g,
                                   (__attribute__((address_space(3))) void*)lds,
                                   16, 0, 0);
}

// ---------------- fused fp32 -> bf16 convert (H + 4 weights, one launch) ----------------
__global__ __launch_bounds__(256) void cvt_all_kernel(
    const float* __restrict__ H,  const float* __restrict__ Wq, const float* __restrict__ Wk,
    const float* __restrict__ Wv, const float* __restrict__ Wo,
    bf16_t* __restrict__ Hb, bf16_t* __restrict__ Wqb, bf16_t* __restrict__ Wkb,
    bf16_t* __restrict__ Wvb, bf16_t* __restrict__ Wob)
{
  const int b = blockIdx.x;
  const float* src; bf16_t* dst; int idx;
  if (b < 4096) { src = H; dst = Hb; idx = b; }
  else {
    const int r = b - 4096; const int s = r >> 10; idx = r & 1023;
    src = (s == 0) ? Wq : (s == 1) ? Wk : (s == 2) ? Wv : Wo;
    dst = (s == 0) ? Wqb : (s == 1) ? Wkb : (s == 2) ? Wvb : Wob;
  }
  const int i = idx * 256 + threadIdx.x;
  float4 v = ((const float4*)src)[i];
  bf16x4 o;
  o[0] = (bf16_t)v.x; o[1] = (bf16_t)v.y; o[2] = (bf16_t)v.z; o[3] = (bf16_t)v.w;
  ((bf16x4*)dst)[i] = o;
}

// ---------------- bf16 TN GEMM: C[M][N] = A[M][K] * W[N][K]^T + bias ----------------
// 128x128 tile, BK=64 (XOR-swizzled LDS), 4 waves (2x2), 16x16x32 MFMA.
// MODE 0: plain fp32 out. MODE 1: per-head normalize; z=0/1 -> bf16 Q/K; z=2 -> bf16 V^T.
template<int MODE>
__global__ __launch_bounds__(256) void gemm_bt_kernel(
    const bf16_t* __restrict__ A,
    const bf16_t* __restrict__ W0, const bf16_t* __restrict__ W1, const bf16_t* __restrict__ W2,
    const float* __restrict__ bias0, const float* __restrict__ bias1, const float* __restrict__ bias2,
    void* out0, void* out1, void* out2)
{
  __shared__ bf16_t As[128 * 64];   // [row][64 bf16 = 128B], XOR-swizzled
  __shared__ bf16_t Bs[128 * 64];
  const int tid = threadIdx.x;
  const int lane = tid & 63;
  const int w = tid >> 6;
  const int mt = blockIdx.y, nt = blockIdx.x, z = blockIdx.z;
  const bf16_t* Wp = (z == 0) ? W0 : ((z == 1) ? W1 : W2);
  const float* bp  = (z == 0) ? bias0 : ((z == 1) ? bias1 : bias2);

  const int wr = w >> 1, wc = w & 1;
  const int fr = lane & 15, fq = lane >> 4;

  // staging: wave w owns chunks 4w..4w+3 (chunk = 8 rows x 128B = 1KB)
  const int r_in = lane >> 3;                            // row within chunk
  const int cswz = ((lane & 7) ^ (r_in & 7)) << 4;       // pre-swizzled source col byte
  const unsigned lbase = (unsigned)__builtin_amdgcn_readfirstlane(w * 4096);

  f32x4 acc[4][4] = {};

  const char* Ab = (const char*)(A + (size_t)mt * 128 * DMODEL);
  const char* Bb = (const char*)(Wp + (size_t)nt * 128 * DMODEL);

  for (int kt = 0; kt < DMODEL / 64; ++kt) {
    const size_t k0b = (size_t)kt * 128;                 // 64 bf16 = 128B
    #pragma unroll
    for (int i = 0; i < 4; ++i) {
      const size_t row = (size_t)(w * 32 + i * 8 + r_in);
      gload_lds16(Ab + row * (DMODEL * 2) + k0b + cswz, (char*)As + lbase + i * 1024);
      gload_lds16(Bb + row * (DMODEL * 2) + k0b + cswz, (char*)Bs + lbase + i * 1024);
    }
    __syncthreads();

    bf16x8 a[4][2], b[4][2];
    #pragma unroll
    for (int m = 0; m < 4; ++m)
      #pragma unroll
      for (int ks = 0; ks < 2; ++ks)
        a[m][ks] = *(const bf16x8*)((const char*)As + (wr * 64 + m * 16 + fr) * 128 +
                                    ((ks * 64 + fq * 16) ^ ((fr & 7) << 4)));
    #pragma unroll
    for (int n = 0; n < 4; ++n)
      #pragma unroll
      for (int ks = 0; ks < 2; ++ks)
        b[n][ks] = *(const bf16x8*)((const char*)Bs + (wc * 64 + n * 16 + fr) * 128 +
                                    ((ks * 64 + fq * 16) ^ ((fr & 7) << 4)));
    __builtin_amdgcn_s_setprio(1);
    #pragma unroll
    for (int m = 0; m < 4; ++m)
      #pragma unroll
      for (int n = 0; n < 4; ++n)
        #pragma unroll
        for (int ks = 0; ks < 2; ++ks)
          acc[m][n] = __builtin_amdgcn_mfma_f32_16x16x32_bf16(a[m][ks], b[n][ks], acc[m][n], 0, 0, 0);
    __builtin_amdgcn_s_setprio(0);
    __syncthreads();
  }

  float bv[4];
  const int cb = nt * 128 + wc * 64;
  #pragma unroll
  for (int n = 0; n < 4; ++n) bv[n] = bp[cb + n * 16 + fr];

  if constexpr (MODE == 0) {
    float* outp = (float*)out0;
    #pragma unroll
    for (int m = 0; m < 4; ++m) {
      #pragma unroll
      for (int j = 0; j < 4; ++j) {
        const int row = mt * 128 + wr * 64 + m * 16 + fq * 4 + j;
        float* orow = outp + (size_t)row * DMODEL + cb;
        #pragma unroll
        for (int n = 0; n < 4; ++n)
          orow[n * 16 + fr] = acc[m][n][j] + bv[n];
      }
    }
  } else {
    const int h = nt * 2 + wc;  // head index
    #pragma unroll
    for (int m = 0; m < 4; ++m) {
      #pragma unroll
      for (int j = 0; j < 4; ++j) {
        float v0 = acc[m][0][j] + bv[0];
        float v1 = acc[m][1][j] + bv[1];
        float v2 = acc[m][2][j] + bv[2];
        float v3 = acc[m][3][j] + bv[3];
        float ss = v0 * v0 + v1 * v1 + v2 * v2 + v3 * v3;
        ss += __shfl_xor(ss, 1);
        ss += __shfl_xor(ss, 2);
        ss += __shfl_xor(ss, 4);
        ss += __shfl_xor(ss, 8);
        const float inv = 1.0f / fmaxf(sqrtf(ss), 1e-10f);
        const int row = mt * 128 + wr * 64 + m * 16 + fq * 4 + j;
        const int bb = row >> 11, sr = row & (SEQ - 1);
        if (z < 2) {
          bf16_t* op = ((z == 0) ? (bf16_t*)out0 : (bf16_t*)out1)
                       + (((size_t)(bb * NHEAD + h)) * SEQ + sr) * DHEAD;
          op[0 * 16 + fr] = (bf16_t)(v0 * inv);
          op[1 * 16 + fr] = (bf16_t)(v1 * inv);
          op[2 * 16 + fr] = (bf16_t)(v2 * inv);
          op[3 * 16 + fr] = (bf16_t)(v3 * inv);
        } else {
          bf16_t* vp = (bf16_t*)out2 + ((size_t)(bb * NHEAD + h)) * DHEAD * SEQ + sr;
          vp[(size_t)(0 * 16 + fr) * SEQ] = (bf16_t)(v0 * inv);
          vp[(size_t)(1 * 16 + fr) * SEQ] = (bf16_t)(v1 * inv);
          vp[(size_t)(2 * 16 + fr) * SEQ] = (bf16_t)(v2 * inv);
          vp[(size_t)(3 * 16 + fr) * SEQ] = (bf16_t)(v3 * inv);
        }
      }
    }
  }
}

// ---------------- MFMA spherical flash attention: 32x32x16, LDS-free, prefetched ------
// Wave owns 32 q-rows, half the keys (2-way key-split per block). Swapped QK^T:
// S[key][q] with q = lane&31. P -> bf16 PV B-operand via cvt_pk + permlane32_swap.
// K frags prefetched one tile ahead (ping-pong regs); V frags issued at iter top so
// their latency hides under QK MFMA + score VALU. No barriers in the main loop.
#define PSWAP(x, y) asm("v_permlane32_swap_b32 %0, %1" : "+v"(x), "+v"(y))
#define CVTPK(d, a, b) asm("v_cvt_pk_bf16_f32 %0, %1, %2" : "=v"(d) : "v"(a), "v"(b))

__global__ __launch_bounds__(256, 3) void mfma_attn_kernel(
    const bf16_t* __restrict__ Qb, const bf16_t* __restrict__ Kb,
    const bf16_t* __restrict__ Vt, bf16_t* __restrict__ Oat)
{
  // grid 1024; XCD-aware: xcd = p&7 gets heads 4*xcd..4*xcd+3 (L2 set ~2MB/XCD)
  const int p = blockIdx.x;
  const int xcd = p & 7;
  const int j = p >> 3;                 // 0..127
  const int bh = xcd * 4 + (j >> 5);
  const int qblk = j & 31;              // 32 q-blocks of 64 rows

  const int lane = threadIdx.x & 63;
  const int w = threadIdx.x >> 6;
  const int qh = w & 1, kh = w >> 1;    // q-half (32 rows), key-half (1024 keys)
  const int l31 = lane & 31, l5 = lane >> 5;
  const int q0 = qblk * 64 + qh * 32;

  // Q B-fragments (persistent)
  const bf16_t* Qp = Qb + ((size_t)bh * SEQ + q0 + l31) * DHEAD + l5 * 8;
  bf16x8 b_q[4];
  #pragma unroll
  for (int m = 0; m < 4; ++m)
    b_q[m] = *(const bf16x8*)(Qp + m * 16);

  const bf16_t* Kp = Kb + (size_t)bh * SEQ * DHEAD + (size_t)kh * 1024 * DHEAD + l31 * DHEAD + l5 * 8;
  const bf16_t* Vp = Vt + (size_t)bh * DHEAD * SEQ + (size_t)l31 * SEQ + kh * 1024 + l5 * 8;

  f32x16 acc_o0 = {}, acc_o1 = {};
  float l_acc = 0.0f;

  #define KLOAD(d0, d1, d2, d3, kbn)                                   \
    do {                                                               \
      const bf16_t* kp_ = Kp + (size_t)(kbn) * 32 * DHEAD;             \
      d0 = *(const bf16x8*)(kp_);                                      \
      d1 = *(const bf16x8*)(kp_ + 16);                                 \
      d2 = *(const bf16x8*)(kp_ + 32);                                 \
      d3 = *(const bf16x8*)(kp_ + 48);                                 \
    } while (0)

  #define ITER(c0, c1, c2, c3, n0, n1, n2, n3, kb)                                         \
    do {                                                                                   \
      const bf16_t* vp_ = Vp + (kb) * 32;                                                  \
      bf16x8 av00 = *(const bf16x8*)(vp_);                                                 \
      bf16x8 av01 = *(const bf16x8*)(vp_ + 16);                                            \
      bf16x8 av10 = *(const bf16x8*)(vp_ + (size_t)32 * SEQ);                              \
      bf16x8 av11 = *(const bf16x8*)(vp_ + (size_t)32 * SEQ + 16);                         \
      KLOAD(n0, n1, n2, n3, (kb) + 1);                                                     \
      f32x16 accp = {};                                                                    \
      __builtin_amdgcn_s_setprio(1);                                                       \
      accp = __builtin_amdgcn_mfma_f32_32x32x16_bf16(c0, b_q[0], accp, 0, 0, 0);           \
      accp = __builtin_amdgcn_mfma_f32_32x32x16_bf16(c1, b_q[1], accp, 0, 0, 0);           \
      accp = __builtin_amdgcn_mfma_f32_32x32x16_bf16(c2, b_q[2], accp, 0, 0, 0);           \
      accp = __builtin_amdgcn_mfma_f32_32x32x16_bf16(c3, b_q[3], accp, 0, 0, 0);           \
      __builtin_amdgcn_s_setprio(0);                                                       \
      float pv[16];                                                                        \
      _Pragma("unroll")                                                                    \
      for (int r = 0; r < 16; ++r) {                                                       \
        const float cval = accp[r];                                                        \
        const float c2_ = cval * cval;                                                     \
        float a_ = fmaf(c2_, 0.00379774f, 0.00558036f);                                    \
        a_ = fmaf(c2_, a_, 0.00937500f);                                                   \
        a_ = fmaf(c2_, a_, 0.02083333f);                                                   \
        a_ = fmaf(c2_, a_, 0.12500000f);                                                   \
        const float s_ = a_ * cval;        /* asin(c)/8 */                                 \
        float e_ = fmaf(s_, 0.16666667f, 0.5f);                                            \
        e_ = fmaf(s_, e_, 1.0f);                                                           \
        e_ = fmaf(s_, e_, 1.0f);           /* exp(s), deg-3 */                             \
        pv[r] = e_;                                                                        \
      }                                                                                    \
      float s01 = (pv[0] + pv[1]) + (pv[2] + pv[3]);                                       \
      float s23 = (pv[4] + pv[5]) + (pv[6] + pv[7]);                                       \
      float s45 = (pv[8] + pv[9]) + (pv[10] + pv[11]);                                     \
      float s67 = (pv[12] + pv[13]) + (pv[14] + pv[15]);                                   \
      l_acc += (s01 + s23) + (s45 + s67);                                                  \
      unsigned dwA0, dwA1, dwA2, dwA3, dwB0, dwB1, dwB2, dwB3;                             \
      CVTPK(dwA0, pv[0], pv[1]);  CVTPK(dwB0, pv[2], pv[3]);                               \
      CVTPK(dwA1, pv[4], pv[5]);  CVTPK(dwB1, pv[6], pv[7]);                               \
      CVTPK(dwA2, pv[8], pv[9]);  CVTPK(dwB2, pv[10], pv[11]);                             \
      CVTPK(dwA3, pv[12], pv[13]); CVTPK(dwB3, pv[14], pv[15]);                            \
      PSWAP(dwA0, dwA1);  PSWAP(dwB0, dwB1);                                               \
      PSWAP(dwA2, dwA3);  PSWAP(dwB2, dwB3);                                               \
      typedef unsigned u32x4_ __attribute__((ext_vector_type(4)));                         \
      u32x4_ t0 = { dwA0, dwB0, dwA1, dwB1 };                                              \
      u32x4_ t1 = { dwA2, dwB2, dwA3, dwB3 };                                              \
      bf16x8 pf0 = __builtin_bit_cast(bf16x8, t0);                                         \
      bf16x8 pf1 = __builtin_bit_cast(bf16x8, t1);                                         \
      __builtin_amdgcn_s_setprio(1);                                                       \
      acc_o0 = __builtin_amdgcn_mfma_f32_32x32x16_bf16(av00, pf0, acc_o0, 0, 0, 0);        \
      acc_o0 = __builtin_amdgcn_mfma_f32_32x32x16_bf16(av01, pf1, acc_o0, 0, 0, 0);        \
      acc_o1 = __builtin_amdgcn_mfma_f32_32x32x16_bf16(av10, pf0, acc_o1, 0, 0, 0);        \
      acc_o1 = __builtin_amdgcn_mfma_f32_32x32x16_bf16(av11, pf1, acc_o1, 0, 0, 0);        \
      __builtin_amdgcn_s_setprio(0);                                                       \
    } while (0)

  bf16x8 kA0, kA1, kA2, kA3, kB0, kB1, kB2, kB3;
  KLOAD(kA0, kA1, kA2, kA3, 0);

  for (int kb2 = 0; kb2 < 16; ++kb2) {
    ITER(kA0, kA1, kA2, kA3, kB0, kB1, kB2, kB3, 2 * kb2);
    ITER(kB0, kB1, kB2, kB3, kA0, kA1, kA2, kA3, 2 * kb2 + 1);
  }
  #undef ITER
  #undef KLOAD

  // ---- epilogue: combine l halves, then key-split combine via LDS ----
  l_acc += __shfl_xor(l_acc, 32);

  __shared__ float combO[2][2][16][64];   // [qh][blk][reg][lane]
  __shared__ float combL[2][64];
  if (kh == 1) {
    #pragma unroll
    for (int r = 0; r < 16; ++r) {
      combO[qh][0][r][lane] = acc_o0[r];
      combO[qh][1][r][lane] = acc_o1[r];
    }
    combL[qh][lane] = l_acc;
  }
  __syncthreads();
  if (kh == 0) {
    #pragma unroll
    for (int r = 0; r < 16; ++r) {
      acc_o0[r] += combO[qh][0][r][lane];
      acc_o1[r] += combO[qh][1][r][lane];
    }
    l_acc += combL[qh][lane];
    const float invl = __builtin_amdgcn_rcpf(l_acc);
    const int bb = bh >> 4, h = bh & 15;
    bf16_t* op = Oat + ((size_t)bb * SEQ + q0 + l31) * DMODEL + h * DHEAD;
    #pragma unroll
    for (int blk = 0; blk < 2; ++blk) {
      const f32x16& ao = blk ? acc_o1 : acc_o0;
      #pragma unroll
      for (int g = 0; g < 4; ++g) {
        bf16x4 ov;
        ov[0] = (bf16_t)(ao[4 * g + 0] * invl);
        ov[1] = (bf16_t)(ao[4 * g + 1] * invl);
        ov[2] = (bf16_t)(ao[4 * g + 2] * invl);
        ov[3] = (bf16_t)(ao[4 * g + 3] * invl);
        const int dh0 = blk * 32 + 8 * g + 4 * l5;
        *(bf16x4*)(op + dh0) = ov;
      }
    }
  }
}

extern "C" void kernel_launch(void* const* d_in, const int* in_sizes, int n_in,
                              void* d_out, int out_size, void* d_ws, size_t ws_size,
                              hipStream_t stream)
{
  const float* H  = (const float*)d_in[0];
  const float* Wq = (const float*)d_in[1];
  const float* bq = (const float*)d_in[2];
  const float* Wk = (const float*)d_in[3];
  const float* bk = (const float*)d_in[4];
  const float* Wv = (const float*)d_in[5];
  const float* bv = (const float*)d_in[6];
  const float* Wo = (const float*)d_in[7];
  const float* bo = (const float*)d_in[8];
  float* out = (float*)d_out;

  char* ws = (char*)d_ws;
  bf16_t* Hb  = (bf16_t*)(ws);                    // 8 MB  [B*S][1024]
  bf16_t* Wqb = (bf16_t*)(ws + (8u << 20));       // 2 MB each
  bf16_t* Wkb = (bf16_t*)(ws + (10u << 20));
  bf16_t* Wvb = (bf16_t*)(ws + (12u << 20));
  bf16_t* Wob = (bf16_t*)(ws + (14u << 20));
  bf16_t* Qbf = (bf16_t*)(ws + (16u << 20));      // 8 MB  [BH][S][64]
  bf16_t* Kbf = (bf16_t*)(ws + (24u << 20));      // 8 MB  [BH][S][64]
  bf16_t* Vtb = (bf16_t*)(ws + (32u << 20));      // 8 MB  [BH][64][S]
  bf16_t* Oat = (bf16_t*)(ws + (40u << 20));      // 8 MB  [B][S][1024]

  // fp32 -> bf16 converts (single launch)
  cvt_all_kernel<<<8192, 256, 0, stream>>>(H, Wq, Wk, Wv, Wo, Hb, Wqb, Wkb, Wvb, Wob);

  // Q/K/V projections + bias + per-head normalize -> bf16 Q,K,[V^T]
  gemm_bt_kernel<1><<<dim3(8, 32, 3), 256, 0, stream>>>(
      Hb, Wqb, Wkb, Wvb, bq, bk, bv, Qbf, Kbf, Vtb);

  // MFMA spherical flash attention (LDS-free, 32x32x16, prefetched, key-split x2)
  mfma_attn_kernel<<<1024, 256, 0, stream>>>(Qbf, Kbf, Vtb, Oat);

  // output projection -> d_out fp32 [B][S][1024]
  gemm_bt_kernel<0><<<dim3(8, 32, 1), 256, 0, stream>>>(
      Oat, Wob, Wob, Wob, bo, bo, bo, out, out, out);
}

// Round 8
// 172.882 us; speedup vs baseline: 1.1868x; 1.1868x over previous
//
#include <hip/hip_runtime.h>
#include <hip/hip_bf16.h>

typedef __bf16 bf16_t;
typedef __bf16 bf16x8 __attribute__((ext_vector_type(8)));
typedef __bf16 bf16x4 __attribute__((ext_vector_type(4)));
typedef float f32x4 __attribute__((ext_vector_type(4)));
typedef float f32x16 __attribute__((ext_vector_type(16)));

#define NB 2
#define SEQ 2048
#define DMODEL 1024
#define NHEAD 16
#define DHEAD 64

__device__ inline void gload_lds16(const void* g, void* lds) {
  __builtin_amdgcn_global_load_lds((const __attribute__((address_space(1))) void*)g,
                                   (__attribute__((address_space(3))) void*)lds,
                                   16, 0, 0);
}

// ---------------- fused fp32 -> bf16 convert (H + 4 weights, one launch) ----------------
__global__ __launch_bounds__(256) void cvt_all_kernel(
    const float* __restrict__ H,  const float* __restrict__ Wq, const float* __restrict__ Wk,
    const float* __restrict__ Wv, const float* __restrict__ Wo,
    bf16_t* __restrict__ Hb, bf16_t* __restrict__ Wqb, bf16_t* __restrict__ Wkb,
    bf16_t* __restrict__ Wvb, bf16_t* __restrict__ Wob)
{
  const int b = blockIdx.x;
  const float* src; bf16_t* dst; int idx;
  if (b < 4096) { src = H; dst = Hb; idx = b; }
  else {
    const int r = b - 4096; const int s = r >> 10; idx = r & 1023;
    src = (s == 0) ? Wq : (s == 1) ? Wk : (s == 2) ? Wv : Wo;
    dst = (s == 0) ? Wqb : (s == 1) ? Wkb : (s == 2) ? Wvb : Wob;
  }
  const int i = idx * 256 + threadIdx.x;
  float4 v = ((const float4*)src)[i];
  bf16x4 o;
  o[0] = (bf16_t)v.x; o[1] = (bf16_t)v.y; o[2] = (bf16_t)v.z; o[3] = (bf16_t)v.w;
  ((bf16x4*)dst)[i] = o;
}

// ---------------- bf16 TN GEMM: C[M][N] = A[M][K] * W[N][K]^T + bias ----------------
template<int MODE>
__global__ __launch_bounds__(256) void gemm_bt_kernel(
    const bf16_t* __restrict__ A,
    const bf16_t* __restrict__ W0, const bf16_t* __restrict__ W1, const bf16_t* __restrict__ W2,
    const float* __restrict__ bias0, const float* __restrict__ bias1, const float* __restrict__ bias2,
    void* out0, void* out1, void* out2)
{
  __shared__ bf16_t As[128 * 64];   // [row][64 bf16 = 128B], XOR-swizzled
  __shared__ bf16_t Bs[128 * 64];
  const int tid = threadIdx.x;
  const int lane = tid & 63;
  const int w = tid >> 6;
  const int mt = blockIdx.y, nt = blockIdx.x, z = blockIdx.z;
  const bf16_t* Wp = (z == 0) ? W0 : ((z == 1) ? W1 : W2);
  const float* bp  = (z == 0) ? bias0 : ((z == 1) ? bias1 : bias2);

  const int wr = w >> 1, wc = w & 1;
  const int fr = lane & 15, fq = lane >> 4;

  const int r_in = lane >> 3;
  const int cswz = ((lane & 7) ^ (r_in & 7)) << 4;
  const unsigned lbase = (unsigned)__builtin_amdgcn_readfirstlane(w * 4096);

  f32x4 acc[4][4] = {};

  const char* Ab = (const char*)(A + (size_t)mt * 128 * DMODEL);
  const char* Bb = (const char*)(Wp + (size_t)nt * 128 * DMODEL);

  for (int kt = 0; kt < DMODEL / 64; ++kt) {
    const size_t k0b = (size_t)kt * 128;
    #pragma unroll
    for (int i = 0; i < 4; ++i) {
      const size_t row = (size_t)(w * 32 + i * 8 + r_in);
      gload_lds16(Ab + row * (DMODEL * 2) + k0b + cswz, (char*)As + lbase + i * 1024);
      gload_lds16(Bb + row * (DMODEL * 2) + k0b + cswz, (char*)Bs + lbase + i * 1024);
    }
    __syncthreads();

    bf16x8 a[4][2], b[4][2];
    #pragma unroll
    for (int m = 0; m < 4; ++m)
      #pragma unroll
      for (int ks = 0; ks < 2; ++ks)
        a[m][ks] = *(const bf16x8*)((const char*)As + (wr * 64 + m * 16 + fr) * 128 +
                                    ((ks * 64 + fq * 16) ^ ((fr & 7) << 4)));
    #pragma unroll
    for (int n = 0; n < 4; ++n)
      #pragma unroll
      for (int ks = 0; ks < 2; ++ks)
        b[n][ks] = *(const bf16x8*)((const char*)Bs + (wc * 64 + n * 16 + fr) * 128 +
                                    ((ks * 64 + fq * 16) ^ ((fr & 7) << 4)));
    __builtin_amdgcn_s_setprio(1);
    #pragma unroll
    for (int m = 0; m < 4; ++m)
      #pragma unroll
      for (int n = 0; n < 4; ++n)
        #pragma unroll
        for (int ks = 0; ks < 2; ++ks)
          acc[m][n] = __builtin_amdgcn_mfma_f32_16x16x32_bf16(a[m][ks], b[n][ks], acc[m][n], 0, 0, 0);
    __builtin_amdgcn_s_setprio(0);
    __syncthreads();
  }

  float bv[4];
  const int cb = nt * 128 + wc * 64;
  #pragma unroll
  for (int n = 0; n < 4; ++n) bv[n] = bp[cb + n * 16 + fr];

  if constexpr (MODE == 0) {
    float* outp = (float*)out0;
    #pragma unroll
    for (int m = 0; m < 4; ++m) {
      #pragma unroll
      for (int j = 0; j < 4; ++j) {
        const int row = mt * 128 + wr * 64 + m * 16 + fq * 4 + j;
        float* orow = outp + (size_t)row * DMODEL + cb;
        #pragma unroll
        for (int n = 0; n < 4; ++n)
          orow[n * 16 + fr] = acc[m][n][j] + bv[n];
      }
    }
  } else {
    const int h = nt * 2 + wc;
    #pragma unroll
    for (int m = 0; m < 4; ++m) {
      #pragma unroll
      for (int j = 0; j < 4; ++j) {
        float v0 = acc[m][0][j] + bv[0];
        float v1 = acc[m][1][j] + bv[1];
        float v2 = acc[m][2][j] + bv[2];
        float v3 = acc[m][3][j] + bv[3];
        float ss = v0 * v0 + v1 * v1 + v2 * v2 + v3 * v3;
        ss += __shfl_xor(ss, 1);
        ss += __shfl_xor(ss, 2);
        ss += __shfl_xor(ss, 4);
        ss += __shfl_xor(ss, 8);
        const float inv = 1.0f / fmaxf(sqrtf(ss), 1e-10f);
        const int row = mt * 128 + wr * 64 + m * 16 + fq * 4 + j;
        const int bb = row >> 11, sr = row & (SEQ - 1);
        if (z < 2) {
          bf16_t* op = ((z == 0) ? (bf16_t*)out0 : (bf16_t*)out1)
                       + (((size_t)(bb * NHEAD + h)) * SEQ + sr) * DHEAD;
          op[0 * 16 + fr] = (bf16_t)(v0 * inv);
          op[1 * 16 + fr] = (bf16_t)(v1 * inv);
          op[2 * 16 + fr] = (bf16_t)(v2 * inv);
          op[3 * 16 + fr] = (bf16_t)(v3 * inv);
        } else {
          bf16_t* vp = (bf16_t*)out2 + ((size_t)(bb * NHEAD + h)) * DHEAD * SEQ + sr;
          vp[(size_t)(0 * 16 + fr) * SEQ] = (bf16_t)(v0 * inv);
          vp[(size_t)(1 * 16 + fr) * SEQ] = (bf16_t)(v1 * inv);
          vp[(size_t)(2 * 16 + fr) * SEQ] = (bf16_t)(v2 * inv);
          vp[(size_t)(3 * 16 + fr) * SEQ] = (bf16_t)(v3 * inv);
        }
      }
    }
  }
}

// ---------------- MFMA spherical flash attention: 32x32x16, LDS-staged, permlane P ----
// Block = 8 waves: qw = w&3 (32 q-rows each => 128 q/block), kh = w>>2 (key half, 1024 keys).
// KV tiles of 64 keys per half, double-buffered. LDS tiles stored [32 rows][256B]
// (row r holds key r and r+32 side by side), XOR-swizzled c ^= (row&15)<<4 => 2-way max.
// Swapped QK^T (S[key][q], q=lane&31), P exchange via cvt_pk + permlane32_swap (R6-validated),
// PV transposed (O^T[dh][q]). In-block key-half combine via LDS at the end.
#define PSWAP(x, y) asm("v_permlane32_swap_b32 %0, %1" : "+v"(x), "+v"(y))
#define CVTPK(d, a, b) asm("v_cvt_pk_bf16_f32 %0, %1, %2" : "=v"(d) : "v"(a), "v"(b))

__global__ __launch_bounds__(512, 4) void mfma_attn_kernel(
    const bf16_t* __restrict__ Qb, const bf16_t* __restrict__ Kb,
    const bf16_t* __restrict__ Vt, bf16_t* __restrict__ Oat)
{
  __shared__ char smem[65536];   // [kh][buf][ K 8KB | V 8KB ]

  const int tid = threadIdx.x;
  const int lane = tid & 63;
  const int w = tid >> 6;
  const int qw = w & 3, kh = w >> 2;
  const int l31 = lane & 31, l5 = lane >> 5;

  // grid 512; XCD-aware: xcd gets heads 4*xcd..4*xcd+3 (L2 set ~2MB/XCD)
  const int p = blockIdx.x;
  const int xcd = p & 7;
  const int j = p >> 3;                 // 0..63
  const int bh = xcd * 4 + (j >> 4);
  const int qt = j & 15;
  const int q0 = qt * 128 + qw * 32;

  // persistent Q B-fragments: lane holds Q[q=q0+l31][seg*16 + l5*8 .. +7]
  const bf16_t* Qp = Qb + ((size_t)bh * SEQ + q0 + l31) * DHEAD + l5 * 8;
  bf16x8 b_q[4];
  #pragma unroll
  for (int m = 0; m < 4; ++m)
    b_q[m] = *(const bf16x8*)(Qp + m * 16);

  const char* KbaseH = (const char*)(Kb + (size_t)bh * SEQ * DHEAD) + (size_t)kh * 1024 * DHEAD * 2;
  const char* VbaseH = (const char*)(Vt + (size_t)bh * DHEAD * SEQ) + (size_t)kh * 1024 * 2;

  // staging: per half-tile, K = 8 chunks of 1KB (4 rows x 256B), V likewise; wave qw owns
  // chunks 2qw, 2qw+1 of each. Pre-swizzled per-lane global source offsets:
  const int chA = 2 * qw, chB = 2 * qw + 1;
  int koffA, koffB, voffA, voffB;
  {
    const int rA = chA * 4 + (lane >> 4), rB = chB * 4 + (lane >> 4);
    const int c = (lane & 15) * 16;
    const int cpA = c ^ ((rA & 15) << 4), cpB = c ^ ((rB & 15) << 4);
    koffA = (rA + ((cpA >> 7) << 5)) * 128 + (cpA & 127);
    koffB = (rB + ((cpB >> 7) << 5)) * 128 + (cpB & 127);
    voffA = (rA + ((cpA >> 7) << 5)) * (SEQ * 2) + (cpA & 127);
    voffB = (rB + ((cpB >> 7) << 5)) * (SEQ * 2) + (cpB & 127);
  }
  const unsigned stKA = (unsigned)__builtin_amdgcn_readfirstlane(kh * 32768 + chA * 1024);
  const unsigned stKB = (unsigned)__builtin_amdgcn_readfirstlane(kh * 32768 + chB * 1024);
  const unsigned rb0  = (unsigned)__builtin_amdgcn_readfirstlane(kh * 32768);

  const int swz = (l31 & 15) << 4;
  const unsigned kRow = l31 * 256;

  f32x16 acc_o0 = {}, acc_o1 = {};
  float l_acc = 0.0f;

  #define STAGE(t, buf)                                                                    \
    do {                                                                                   \
      const char* Kt_ = KbaseH + (size_t)(t) * 8192;                                       \
      const char* Vc_ = VbaseH + (size_t)(t) * 128;                                        \
      gload_lds16(Kt_ + koffA, smem + stKA + (buf) * 16384);                               \
      gload_lds16(Kt_ + koffB, smem + stKB + (buf) * 16384);                               \
      gload_lds16(Vc_ + voffA, smem + stKA + (buf) * 16384 + 8192);                        \
      gload_lds16(Vc_ + voffB, smem + stKB + (buf) * 16384 + 8192);                        \
    } while (0)

  // one 32-key chunk (c0 = 0/1) of the current 64-key tile in buffer `buf`
  #define CHUNK(buf, c0)                                                                   \
    do {                                                                                   \
      const char* kb_ = smem + rb0 + (buf) * 16384 + kRow;                                 \
      bf16x8 ak0 = *(const bf16x8*)(kb_ + (((c0) * 128 +  0 + l5 * 16) ^ swz));            \
      bf16x8 ak1 = *(const bf16x8*)(kb_ + (((c0) * 128 + 32 + l5 * 16) ^ swz));            \
      bf16x8 ak2 = *(const bf16x8*)(kb_ + (((c0) * 128 + 64 + l5 * 16) ^ swz));            \
      bf16x8 ak3 = *(const bf16x8*)(kb_ + (((c0) * 128 + 96 + l5 * 16) ^ swz));            \
      f32x16 accp = {};                                                                    \
      __builtin_amdgcn_s_setprio(1);                                                       \
      accp = __builtin_amdgcn_mfma_f32_32x32x16_bf16(ak0, b_q[0], accp, 0, 0, 0);          \
      accp = __builtin_amdgcn_mfma_f32_32x32x16_bf16(ak1, b_q[1], accp, 0, 0, 0);          \
      accp = __builtin_amdgcn_mfma_f32_32x32x16_bf16(ak2, b_q[2], accp, 0, 0, 0);          \
      accp = __builtin_amdgcn_mfma_f32_32x32x16_bf16(ak3, b_q[3], accp, 0, 0, 0);          \
      __builtin_amdgcn_s_setprio(0);                                                       \
      const char* vb_ = smem + rb0 + (buf) * 16384 + 8192 + kRow;                          \
      bf16x8 av00 = *(const bf16x8*)(vb_ + ((      (c0) * 64 +  0 + l5 * 16) ^ swz));      \
      bf16x8 av01 = *(const bf16x8*)(vb_ + ((      (c0) * 64 + 32 + l5 * 16) ^ swz));      \
      bf16x8 av10 = *(const bf16x8*)(vb_ + ((128 + (c0) * 64 +  0 + l5 * 16) ^ swz));      \
      bf16x8 av11 = *(const bf16x8*)(vb_ + ((128 + (c0) * 64 + 32 + l5 * 16) ^ swz));      \
      float pv[16];                                                                        \
      _Pragma("unroll")                                                                    \
      for (int r = 0; r < 16; ++r) {                                                       \
        const float cval = accp[r];                                                        \
        const float c2_ = cval * cval;                                                     \
        float a_ = fmaf(c2_, 0.00379774f, 0.00558036f);                                    \
        a_ = fmaf(c2_, a_, 0.00937500f);                                                   \
        a_ = fmaf(c2_, a_, 0.02083333f);                                                   \
        a_ = fmaf(c2_, a_, 0.12500000f);                                                   \
        const float s_ = a_ * cval;        /* asin(c)/8 */                                 \
        float e_ = fmaf(s_, 0.16666667f, 0.5f);                                            \
        e_ = fmaf(s_, e_, 1.0f);                                                           \
        e_ = fmaf(s_, e_, 1.0f);           /* exp(s), deg-3 */                             \
        pv[r] = e_;                                                                        \
      }                                                                                    \
      float s01 = (pv[0] + pv[1]) + (pv[2] + pv[3]);                                       \
      float s23 = (pv[4] + pv[5]) + (pv[6] + pv[7]);                                       \
      float s45 = (pv[8] + pv[9]) + (pv[10] + pv[11]);                                     \
      float s67 = (pv[12] + pv[13]) + (pv[14] + pv[15]);                                   \
      l_acc += (s01 + s23) + (s45 + s67);                                                  \
      unsigned dwA0, dwA1, dwA2, dwA3, dwB0, dwB1, dwB2, dwB3;                             \
      CVTPK(dwA0, pv[0], pv[1]);  CVTPK(dwB0, pv[2], pv[3]);                               \
      CVTPK(dwA1, pv[4], pv[5]);  CVTPK(dwB1, pv[6], pv[7]);                               \
      CVTPK(dwA2, pv[8], pv[9]);  CVTPK(dwB2, pv[10], pv[11]);                             \
      CVTPK(dwA3, pv[12], pv[13]); CVTPK(dwB3, pv[14], pv[15]);                            \
      PSWAP(dwA0, dwA1);  PSWAP(dwB0, dwB1);                                               \
      PSWAP(dwA2, dwA3);  PSWAP(dwB2, dwB3);                                               \
      typedef unsigned u32x4_ __attribute__((ext_vector_type(4)));                         \
      u32x4_ t0_ = { dwA0, dwB0, dwA1, dwB1 };                                             \
      u32x4_ t1_ = { dwA2, dwB2, dwA3, dwB3 };                                             \
      bf16x8 pf0 = __builtin_bit_cast(bf16x8, t0_);                                        \
      bf16x8 pf1 = __builtin_bit_cast(bf16x8, t1_);                                        \
      __builtin_amdgcn_s_setprio(1);                                                       \
      acc_o0 = __builtin_amdgcn_mfma_f32_32x32x16_bf16(av00, pf0, acc_o0, 0, 0, 0);        \
      acc_o0 = __builtin_amdgcn_mfma_f32_32x32x16_bf16(av01, pf1, acc_o0, 0, 0, 0);        \
      acc_o1 = __builtin_amdgcn_mfma_f32_32x32x16_bf16(av10, pf0, acc_o1, 0, 0, 0);        \
      acc_o1 = __builtin_amdgcn_mfma_f32_32x32x16_bf16(av11, pf1, acc_o1, 0, 0, 0);        \
      __builtin_amdgcn_s_setprio(0);                                                       \
    } while (0)

  #define TILE(buf) do { CHUNK(buf, 0); CHUNK(buf, 1); } while (0)

  STAGE(0, 0);

  for (int t2 = 0; t2 < 8; ++t2) {
    __syncthreads();
    STAGE(2 * t2 + 1, 1);
    TILE(0);
    __syncthreads();
    if (t2 < 7) STAGE(2 * t2 + 2, 0);
    TILE(1);
  }
  #undef TILE
  #undef CHUNK
  #undef STAGE

  // ---- epilogue: finish l, combine key halves via LDS, write Oat ----
  l_acc += __shfl_xor(l_acc, 32);

  __syncthreads();                       // all tile reads done; smem reusable
  float* cO = (float*)smem;              // [qw][32][64] fp32 = 32KB
  float* cL = (float*)(smem + 32768);    // [qw][64]
  if (kh == 1) {
    #pragma unroll
    for (int r = 0; r < 16; ++r) {
      cO[(qw * 32 + r) * 64 + lane] = acc_o0[r];
      cO[(qw * 32 + 16 + r) * 64 + lane] = acc_o1[r];
    }
    cL[qw * 64 + lane] = l_acc;
  }
  __syncthreads();
  if (kh == 0) {
    #pragma unroll
    for (int r = 0; r < 16; ++r) {
      acc_o0[r] += cO[(qw * 32 + r) * 64 + lane];
      acc_o1[r] += cO[(qw * 32 + 16 + r) * 64 + lane];
    }
    l_acc += cL[qw * 64 + lane];
    const float invl = __builtin_amdgcn_rcpf(l_acc);
    const int bb = bh >> 4, h = bh & 15;
    bf16_t* op = Oat + ((size_t)bb * SEQ + q0 + l31) * DMODEL + h * DHEAD;
    #pragma unroll
    for (int blk = 0; blk < 2; ++blk) {
      const f32x16& ao = blk ? acc_o1 : acc_o0;
      #pragma unroll
      for (int g = 0; g < 4; ++g) {
        bf16x4 ov;
        ov[0] = (bf16_t)(ao[4 * g + 0] * invl);
        ov[1] = (bf16_t)(ao[4 * g + 1] * invl);
        ov[2] = (bf16_t)(ao[4 * g + 2] * invl);
        ov[3] = (bf16_t)(ao[4 * g + 3] * invl);
        const int dh0 = blk * 32 + 8 * g + 4 * l5;
        *(bf16x4*)(op + dh0) = ov;
      }
    }
  }
}

extern "C" void kernel_launch(void* const* d_in, const int* in_sizes, int n_in,
                              void* d_out, int out_size, void* d_ws, size_t ws_size,
                              hipStream_t stream)
{
  const float* H  = (const float*)d_in[0];
  const float* Wq = (const float*)d_in[1];
  const float* bq = (const float*)d_in[2];
  const float* Wk = (const float*)d_in[3];
  const float* bk = (const float*)d_in[4];
  const float* Wv = (const float*)d_in[5];
  const float* bv = (const float*)d_in[6];
  const float* Wo = (const float*)d_in[7];
  const float* bo = (const float*)d_in[8];
  float* out = (float*)d_out;

  char* ws = (char*)d_ws;
  bf16_t* Hb  = (bf16_t*)(ws);                    // 8 MB  [B*S][1024]
  bf16_t* Wqb = (bf16_t*)(ws + (8u << 20));       // 2 MB each
  bf16_t* Wkb = (bf16_t*)(ws + (10u << 20));
  bf16_t* Wvb = (bf16_t*)(ws + (12u << 20));
  bf16_t* Wob = (bf16_t*)(ws + (14u << 20));
  bf16_t* Qbf = (bf16_t*)(ws + (16u << 20));      // 8 MB  [BH][S][64]
  bf16_t* Kbf = (bf16_t*)(ws + (24u << 20));      // 8 MB  [BH][S][64]
  bf16_t* Vtb = (bf16_t*)(ws + (32u << 20));      // 8 MB  [BH][64][S]
  bf16_t* Oat = (bf16_t*)(ws + (40u << 20));      // 8 MB  [B][S][1024]

  // fp32 -> bf16 converts (single launch)
  cvt_all_kernel<<<8192, 256, 0, stream>>>(H, Wq, Wk, Wv, Wo, Hb, Wqb, Wkb, Wvb, Wob);

  // Q/K/V projections + bias + per-head normalize -> bf16 Q,K,[V^T]
  gemm_bt_kernel<1><<<dim3(8, 32, 3), 256, 0, stream>>>(
      Hb, Wqb, Wkb, Wvb, bq, bk, bv, Qbf, Kbf, Vtb);

  // MFMA spherical flash attention (LDS-staged, 32x32x16, permlane P, key-split in block)
  mfma_attn_kernel<<<512, 512, 0, stream>>>(Qbf, Kbf, Vtb, Oat);

  // output projection -> d_out fp32 [B][S][1024]
  gemm_bt_kernel<0><<<dim3(8, 32, 1), 256, 0, stream>>>(
      Oat, Wob, Wob, Wob, bo, bo, bo, out, out, out);
}

// Round 9
// 168.134 us; speedup vs baseline: 1.2203x; 1.0282x over previous
//
#include <hip/hip_runtime.h>
#include <hip/hip_bf16.h>

typedef __bf16 bf16_t;
typedef __bf16 bf16x8 __attribute__((ext_vector_type(8)));
typedef __bf16 bf16x4 __attribute__((ext_vector_type(4)));
typedef float f32x2 __attribute__((ext_vector_type(2)));
typedef float f32x4 __attribute__((ext_vector_type(4)));
typedef float f32x16 __attribute__((ext_vector_type(16)));

#define NB 2
#define SEQ 2048
#define DMODEL 1024
#define NHEAD 16
#define DHEAD 64

__device__ inline void gload_lds16(const void* g, void* lds) {
  __builtin_amdgcn_global_load_lds((const __attribute__((address_space(1))) void*)g,
                                   (__attribute__((address_space(3))) void*)lds,
                                   16, 0, 0);
}

// ---------------- fused fp32 -> bf16 convert (H + 4 weights, one launch) ----------------
__global__ __launch_bounds__(256) void cvt_all_kernel(
    const float* __restrict__ H,  const float* __restrict__ Wq, const float* __restrict__ Wk,
    const float* __restrict__ Wv, const float* __restrict__ Wo,
    bf16_t* __restrict__ Hb, bf16_t* __restrict__ Wqb, bf16_t* __restrict__ Wkb,
    bf16_t* __restrict__ Wvb, bf16_t* __restrict__ Wob)
{
  const int b = blockIdx.x;
  const float* src; bf16_t* dst; int idx;
  if (b < 4096) { src = H; dst = Hb; idx = b; }
  else {
    const int r = b - 4096; const int s = r >> 10; idx = r & 1023;
    src = (s == 0) ? Wq : (s == 1) ? Wk : (s == 2) ? Wv : Wo;
    dst = (s == 0) ? Wqb : (s == 1) ? Wkb : (s == 2) ? Wvb : Wob;
  }
  const int i = idx * 256 + threadIdx.x;
  float4 v = ((const float4*)src)[i];
  bf16x4 o;
  o[0] = (bf16_t)v.x; o[1] = (bf16_t)v.y; o[2] = (bf16_t)v.z; o[3] = (bf16_t)v.w;
  ((bf16x4*)dst)[i] = o;
}

// ---------------- bf16 TN GEMM: C[M][N] = A[M][K] * W[N][K]^T + bias ----------------
template<int MODE>
__global__ __launch_bounds__(256) void gemm_bt_kernel(
    const bf16_t* __restrict__ A,
    const bf16_t* __restrict__ W0, const bf16_t* __restrict__ W1, const bf16_t* __restrict__ W2,
    const float* __restrict__ bias0, const float* __restrict__ bias1, const float* __restrict__ bias2,
    void* out0, void* out1, void* out2)
{
  __shared__ bf16_t As[128 * 64];   // [row][64 bf16 = 128B], XOR-swizzled
  __shared__ bf16_t Bs[128 * 64];
  const int tid = threadIdx.x;
  const int lane = tid & 63;
  const int w = tid >> 6;
  const int mt = blockIdx.y, nt = blockIdx.x, z = blockIdx.z;
  const bf16_t* Wp = (z == 0) ? W0 : ((z == 1) ? W1 : W2);
  const float* bp  = (z == 0) ? bias0 : ((z == 1) ? bias1 : bias2);

  const int wr = w >> 1, wc = w & 1;
  const int fr = lane & 15, fq = lane >> 4;

  const int r_in = lane >> 3;
  const int cswz = ((lane & 7) ^ (r_in & 7)) << 4;
  const unsigned lbase = (unsigned)__builtin_amdgcn_readfirstlane(w * 4096);

  f32x4 acc[4][4] = {};

  const char* Ab = (const char*)(A + (size_t)mt * 128 * DMODEL);
  const char* Bb = (const char*)(Wp + (size_t)nt * 128 * DMODEL);

  for (int kt = 0; kt < DMODEL / 64; ++kt) {
    const size_t k0b = (size_t)kt * 128;
    #pragma unroll
    for (int i = 0; i < 4; ++i) {
      const size_t row = (size_t)(w * 32 + i * 8 + r_in);
      gload_lds16(Ab + row * (DMODEL * 2) + k0b + cswz, (char*)As + lbase + i * 1024);
      gload_lds16(Bb + row * (DMODEL * 2) + k0b + cswz, (char*)Bs + lbase + i * 1024);
    }
    __syncthreads();

    bf16x8 a[4][2], b[4][2];
    #pragma unroll
    for (int m = 0; m < 4; ++m)
      #pragma unroll
      for (int ks = 0; ks < 2; ++ks)
        a[m][ks] = *(const bf16x8*)((const char*)As + (wr * 64 + m * 16 + fr) * 128 +
                                    ((ks * 64 + fq * 16) ^ ((fr & 7) << 4)));
    #pragma unroll
    for (int n = 0; n < 4; ++n)
      #pragma unroll
      for (int ks = 0; ks < 2; ++ks)
        b[n][ks] = *(const bf16x8*)((const char*)Bs + (wc * 64 + n * 16 + fr) * 128 +
                                    ((ks * 64 + fq * 16) ^ ((fr & 7) << 4)));
    __builtin_amdgcn_s_setprio(1);
    #pragma unroll
    for (int m = 0; m < 4; ++m)
      #pragma unroll
      for (int n = 0; n < 4; ++n)
        #pragma unroll
        for (int ks = 0; ks < 2; ++ks)
          acc[m][n] = __builtin_amdgcn_mfma_f32_16x16x32_bf16(a[m][ks], b[n][ks], acc[m][n], 0, 0, 0);
    __builtin_amdgcn_s_setprio(0);
    __syncthreads();
  }

  float bv[4];
  const int cb = nt * 128 + wc * 64;
  #pragma unroll
  for (int n = 0; n < 4; ++n) bv[n] = bp[cb + n * 16 + fr];

  if constexpr (MODE == 0) {
    float* outp = (float*)out0;
    #pragma unroll
    for (int m = 0; m < 4; ++m) {
      #pragma unroll
      for (int j = 0; j < 4; ++j) {
        const int row = mt * 128 + wr * 64 + m * 16 + fq * 4 + j;
        float* orow = outp + (size_t)row * DMODEL + cb;
        #pragma unroll
        for (int n = 0; n < 4; ++n)
          orow[n * 16 + fr] = acc[m][n][j] + bv[n];
      }
    }
  } else {
    const int h = nt * 2 + wc;
    #pragma unroll
    for (int m = 0; m < 4; ++m) {
      #pragma unroll
      for (int j = 0; j < 4; ++j) {
        float v0 = acc[m][0][j] + bv[0];
        float v1 = acc[m][1][j] + bv[1];
        float v2 = acc[m][2][j] + bv[2];
        float v3 = acc[m][3][j] + bv[3];
        float ss = v0 * v0 + v1 * v1 + v2 * v2 + v3 * v3;
        ss += __shfl_xor(ss, 1);
        ss += __shfl_xor(ss, 2);
        ss += __shfl_xor(ss, 4);
        ss += __shfl_xor(ss, 8);
        const float inv = 1.0f / fmaxf(sqrtf(ss), 1e-10f);
        const int row = mt * 128 + wr * 64 + m * 16 + fq * 4 + j;
        const int bb = row >> 11, sr = row & (SEQ - 1);
        if (z < 2) {
          bf16_t* op = ((z == 0) ? (bf16_t*)out0 : (bf16_t*)out1)
                       + (((size_t)(bb * NHEAD + h)) * SEQ + sr) * DHEAD;
          op[0 * 16 + fr] = (bf16_t)(v0 * inv);
          op[1 * 16 + fr] = (bf16_t)(v1 * inv);
          op[2 * 16 + fr] = (bf16_t)(v2 * inv);
          op[3 * 16 + fr] = (bf16_t)(v3 * inv);
        } else {
          bf16_t* vp = (bf16_t*)out2 + ((size_t)(bb * NHEAD + h)) * DHEAD * SEQ + sr;
          vp[(size_t)(0 * 16 + fr) * SEQ] = (bf16_t)(v0 * inv);
          vp[(size_t)(1 * 16 + fr) * SEQ] = (bf16_t)(v1 * inv);
          vp[(size_t)(2 * 16 + fr) * SEQ] = (bf16_t)(v2 * inv);
          vp[(size_t)(3 * 16 + fr) * SEQ] = (bf16_t)(v3 * inv);
        }
      }
    }
  }
}

// ---------------- MFMA spherical flash attention: 32x32x16, LDS-staged, permlane P ----
// Block = 4 waves x 32 q-rows = 128 q. KS=2: blocks also split keys (z = 0/1, 1024 keys),
// writing fp32 partials; combine kernel finishes. LDS: 64-key K+V tiles, double-buffered,
// [32 rows][256B] with c ^= (row&15)<<4 swizzle (2-way max). Swapped QK^T (S[key][q],
// q=lane&31), P via cvt_pk + permlane32_swap (R6-validated), PV transposed.
#define PSWAP(x, y) asm("v_permlane32_swap_b32 %0, %1" : "+v"(x), "+v"(y))
#define CVTPK(d, a, b) asm("v_cvt_pk_bf16_f32 %0, %1, %2" : "=v"(d) : "v"(a), "v"(b))
#define V2(x) ((f32x2){(x), (x)})

// score transform w = exp(asin(c)/8) (scale-invariant, pure FMA) on packed f32x2,
// then pack to the PV B-fragment pair via cvt_pk + permlane32_swap.
__device__ inline void score_pack(const f32x16& accp, float& l_acc, bf16x8& pf0, bf16x8& pf1) {
  f32x2 p2[8];
  #pragma unroll
  for (int i = 0; i < 8; ++i) {
    f32x2 cv; cv[0] = accp[2 * i]; cv[1] = accp[2 * i + 1];
    const f32x2 c2 = cv * cv;
    f32x2 a = __builtin_elementwise_fma(c2, V2(0.00379774f), V2(0.00558036f));
    a = __builtin_elementwise_fma(c2, a, V2(0.00937500f));
    a = __builtin_elementwise_fma(c2, a, V2(0.02083333f));
    a = __builtin_elementwise_fma(c2, a, V2(0.12500000f));
    const f32x2 s = a * cv;                       // asin(c)/8
    f32x2 e = __builtin_elementwise_fma(s, V2(0.16666667f), V2(0.5f));
    e = __builtin_elementwise_fma(s, e, V2(1.0f));
    e = __builtin_elementwise_fma(s, e, V2(1.0f)); // exp(s), deg-3
    p2[i] = e;
  }
  const f32x2 t01 = p2[0] + p2[1], t23 = p2[2] + p2[3];
  const f32x2 t45 = p2[4] + p2[5], t67 = p2[6] + p2[7];
  const f32x2 tt = (t01 + t23) + (t45 + t67);
  l_acc += tt[0] + tt[1];
  unsigned dwA0, dwA1, dwA2, dwA3, dwB0, dwB1, dwB2, dwB3;
  CVTPK(dwA0, p2[0][0], p2[0][1]);  CVTPK(dwB0, p2[1][0], p2[1][1]);
  CVTPK(dwA1, p2[2][0], p2[2][1]);  CVTPK(dwB1, p2[3][0], p2[3][1]);
  CVTPK(dwA2, p2[4][0], p2[4][1]);  CVTPK(dwB2, p2[5][0], p2[5][1]);
  CVTPK(dwA3, p2[6][0], p2[6][1]);  CVTPK(dwB3, p2[7][0], p2[7][1]);
  PSWAP(dwA0, dwA1);  PSWAP(dwB0, dwB1);
  PSWAP(dwA2, dwA3);  PSWAP(dwB2, dwB3);
  typedef unsigned u32x4_ __attribute__((ext_vector_type(4)));
  u32x4_ t0_ = { dwA0, dwB0, dwA1, dwB1 };
  u32x4_ t1_ = { dwA2, dwB2, dwA3, dwB3 };
  pf0 = __builtin_bit_cast(bf16x8, t0_);
  pf1 = __builtin_bit_cast(bf16x8, t1_);
}

template<int KS>
__global__ __launch_bounds__(256, 4) void mfma_attn_kernel(
    const bf16_t* __restrict__ Qb, const bf16_t* __restrict__ Kb,
    const bf16_t* __restrict__ Vt, bf16_t* __restrict__ Oat,
    float* __restrict__ o_part, float* __restrict__ l_part)
{
  __shared__ char smem[32768];   // [buf][ K 8KB | V 8KB ]

  const int tid = threadIdx.x;
  const int lane = tid & 63;
  const int qw = tid >> 6;              // 4 q-waves
  const int l31 = lane & 31, l5 = lane >> 5;

  // XCD-aware decode: xcd gets heads 4*xcd..4*xcd+3
  const int p = blockIdx.x;
  const int xcd = p & 7;
  const int j = p >> 3;
  int bh, qt, z;
  if (KS == 2) { bh = xcd * 4 + (j >> 5); qt = (j & 31) >> 1; z = j & 1; }
  else         { bh = xcd * 4 + (j >> 4); qt = j & 15;        z = 0;     }
  const int q0 = qt * 128 + qw * 32;
  const int NT = (KS == 2) ? 16 : 32;   // 64-key tiles for this block

  // persistent Q B-fragments: lane holds Q[q=q0+l31][seg*16 + l5*8 .. +7]
  const bf16_t* Qp = Qb + ((size_t)bh * SEQ + q0 + l31) * DHEAD + l5 * 8;
  bf16x8 b_q[4];
  #pragma unroll
  for (int m = 0; m < 4; ++m)
    b_q[m] = *(const bf16x8*)(Qp + m * 16);

  const char* KbaseH = (const char*)(Kb + (size_t)bh * SEQ * DHEAD) + (size_t)z * 1024 * DHEAD * 2;
  const char* VbaseH = (const char*)(Vt + (size_t)bh * DHEAD * SEQ) + (size_t)z * 1024 * 2;

  // staging: 8 chunks of 1KB per K (resp. V) tile; wave qw owns chunks 2qw, 2qw+1
  const int chA = 2 * qw, chB = 2 * qw + 1;
  int koffA, koffB, voffA, voffB;
  {
    const int rA = chA * 4 + (lane >> 4), rB = chB * 4 + (lane >> 4);
    const int c = (lane & 15) * 16;
    const int cpA = c ^ ((rA & 15) << 4), cpB = c ^ ((rB & 15) << 4);
    koffA = (rA + ((cpA >> 7) << 5)) * 128 + (cpA & 127);
    koffB = (rB + ((cpB >> 7) << 5)) * 128 + (cpB & 127);
    voffA = (rA + ((cpA >> 7) << 5)) * (SEQ * 2) + (cpA & 127);
    voffB = (rB + ((cpB >> 7) << 5)) * (SEQ * 2) + (cpB & 127);
  }
  const unsigned stKA = (unsigned)__builtin_amdgcn_readfirstlane(chA * 1024);
  const unsigned stKB = (unsigned)__builtin_amdgcn_readfirstlane(chB * 1024);

  const int swz = (l31 & 15) << 4;
  const unsigned kRow = l31 * 256;

  f32x16 acc_o0 = {}, acc_o1 = {};
  float l_acc = 0.0f;

  #define STAGE(t, buf)                                                                    \
    do {                                                                                   \
      const char* Kt_ = KbaseH + (size_t)(t) * 8192;                                       \
      const char* Vc_ = VbaseH + (size_t)(t) * 128;                                        \
      gload_lds16(Kt_ + koffA, smem + stKA + (buf) * 16384);                               \
      gload_lds16(Kt_ + koffB, smem + stKB + (buf) * 16384);                               \
      gload_lds16(Vc_ + voffA, smem + stKA + (buf) * 16384 + 8192);                        \
      gload_lds16(Vc_ + voffB, smem + stKB + (buf) * 16384 + 8192);                        \
    } while (0)

  #define CHUNK(buf, c0)                                                                   \
    do {                                                                                   \
      const char* kb_ = smem + (buf) * 16384 + kRow;                                       \
      bf16x8 ak0 = *(const bf16x8*)(kb_ + (((c0) * 128 +  0 + l5 * 16) ^ swz));            \
      bf16x8 ak1 = *(const bf16x8*)(kb_ + (((c0) * 128 + 32 + l5 * 16) ^ swz));            \
      bf16x8 ak2 = *(const bf16x8*)(kb_ + (((c0) * 128 + 64 + l5 * 16) ^ swz));            \
      bf16x8 ak3 = *(const bf16x8*)(kb_ + (((c0) * 128 + 96 + l5 * 16) ^ swz));            \
      f32x16 accp = {};                                                                    \
      __builtin_amdgcn_s_setprio(1);                                                       \
      accp = __builtin_amdgcn_mfma_f32_32x32x16_bf16(ak0, b_q[0], accp, 0, 0, 0);          \
      accp = __builtin_amdgcn_mfma_f32_32x32x16_bf16(ak1, b_q[1], accp, 0, 0, 0);          \
      accp = __builtin_amdgcn_mfma_f32_32x32x16_bf16(ak2, b_q[2], accp, 0, 0, 0);          \
      accp = __builtin_amdgcn_mfma_f32_32x32x16_bf16(ak3, b_q[3], accp, 0, 0, 0);          \
      __builtin_amdgcn_s_setprio(0);                                                       \
      const char* vb_ = smem + (buf) * 16384 + 8192 + kRow;                                \
      bf16x8 av00 = *(const bf16x8*)(vb_ + ((      (c0) * 64 +  0 + l5 * 16) ^ swz));      \
      bf16x8 av01 = *(const bf16x8*)(vb_ + ((      (c0) * 64 + 32 + l5 * 16) ^ swz));      \
      bf16x8 av10 = *(const bf16x8*)(vb_ + ((128 + (c0) * 64 +  0 + l5 * 16) ^ swz));      \
      bf16x8 av11 = *(const bf16x8*)(vb_ + ((128 + (c0) * 64 + 32 + l5 * 16) ^ swz));      \
      bf16x8 pf0, pf1;                                                                     \
      score_pack(accp, l_acc, pf0, pf1);                                                   \
      __builtin_amdgcn_s_setprio(1);                                                       \
      acc_o0 = __builtin_amdgcn_mfma_f32_32x32x16_bf16(av00, pf0, acc_o0, 0, 0, 0);        \
      acc_o0 = __builtin_amdgcn_mfma_f32_32x32x16_bf16(av01, pf1, acc_o0, 0, 0, 0);        \
      acc_o1 = __builtin_amdgcn_mfma_f32_32x32x16_bf16(av10, pf0, acc_o1, 0, 0, 0);        \
      acc_o1 = __builtin_amdgcn_mfma_f32_32x32x16_bf16(av11, pf1, acc_o1, 0, 0, 0);        \
      __builtin_amdgcn_s_setprio(0);                                                       \
    } while (0)

  #define TILE(buf) do { CHUNK(buf, 0); CHUNK(buf, 1); } while (0)

  STAGE(0, 0);

  for (int t2 = 0; t2 < NT / 2; ++t2) {
    __syncthreads();
    STAGE(2 * t2 + 1, 1);
    TILE(0);
    __syncthreads();
    if (t2 < NT / 2 - 1) STAGE(2 * t2 + 2, 0);
    TILE(1);
  }
  #undef TILE
  #undef CHUNK
  #undef STAGE

  // ---- epilogue ----
  l_acc += __shfl_xor(l_acc, 32);       // full l for q = q0 + l31

  if (KS == 2) {
    float* po = o_part + ((size_t)z * (32 * SEQ) + (size_t)bh * SEQ + q0 + l31) * 64;
    #pragma unroll
    for (int blk = 0; blk < 2; ++blk) {
      const f32x16& ao = blk ? acc_o1 : acc_o0;
      #pragma unroll
      for (int g = 0; g < 4; ++g) {
        f32x4 ov = { ao[4 * g + 0], ao[4 * g + 1], ao[4 * g + 2], ao[4 * g + 3] };
        *(f32x4*)(po + blk * 32 + 8 * g + 4 * l5) = ov;
      }
    }
    if (lane < 32)
      l_part[(size_t)z * (32 * SEQ) + (size_t)bh * SEQ + q0 + l31] = l_acc;
  } else {
    const float invl = __builtin_amdgcn_rcpf(l_acc);
    const int bb = bh >> 4, h = bh & 15;
    bf16_t* op = Oat + ((size_t)bb * SEQ + q0 + l31) * DMODEL + h * DHEAD;
    #pragma unroll
    for (int blk = 0; blk < 2; ++blk) {
      const f32x16& ao = blk ? acc_o1 : acc_o0;
      #pragma unroll
      for (int g = 0; g < 4; ++g) {
        bf16x4 ov;
        ov[0] = (bf16_t)(ao[4 * g + 0] * invl);
        ov[1] = (bf16_t)(ao[4 * g + 1] * invl);
        ov[2] = (bf16_t)(ao[4 * g + 2] * invl);
        ov[3] = (bf16_t)(ao[4 * g + 3] * invl);
        *(bf16x4*)(op + blk * 32 + 8 * g + 4 * l5) = ov;
      }
    }
  }
}

// ---------------- key-split combine: O = (o0+o1)/(l0+l1), fp32 -> bf16 Oat ----------------
__global__ __launch_bounds__(256) void attn_combine_kernel(
    const float* __restrict__ o_part, const float* __restrict__ l_part,
    bf16_t* __restrict__ Oat)
{
  const int idx = blockIdx.x * 256 + threadIdx.x;   // 0 .. 1048575
  const int row = idx >> 4, u = idx & 15;           // row = bh*2048 + q
  const float l = l_part[row] + l_part[32 * SEQ + row];
  const float inv = __builtin_amdgcn_rcpf(l);
  const f32x4 a = ((const f32x4*)o_part)[idx];
  const f32x4 b = ((const f32x4*)o_part)[(32 * SEQ * 16) + idx];
  bf16x4 o;
  o[0] = (bf16_t)((a[0] + b[0]) * inv);
  o[1] = (bf16_t)((a[1] + b[1]) * inv);
  o[2] = (bf16_t)((a[2] + b[2]) * inv);
  o[3] = (bf16_t)((a[3] + b[3]) * inv);
  const int bh = row >> 11, q = row & (SEQ - 1);
  const int bb = bh >> 4, h = bh & 15;
  ((bf16x4*)(Oat + ((size_t)bb * SEQ + q) * DMODEL + h * DHEAD))[u] = o;
}

extern "C" void kernel_launch(void* const* d_in, const int* in_sizes, int n_in,
                              void* d_out, int out_size, void* d_ws, size_t ws_size,
                              hipStream_t stream)
{
  const float* H  = (const float*)d_in[0];
  const float* Wq = (const float*)d_in[1];
  const float* bq = (const float*)d_in[2];
  const float* Wk = (const float*)d_in[3];
  const float* bk = (const float*)d_in[4];
  const float* Wv = (const float*)d_in[5];
  const float* bv = (const float*)d_in[6];
  const float* Wo = (const float*)d_in[7];
  const float* bo = (const float*)d_in[8];
  float* out = (float*)d_out;

  char* ws = (char*)d_ws;
  bf16_t* Hb  = (bf16_t*)(ws);                    // 8 MB  [B*S][1024]
  bf16_t* Wqb = (bf16_t*)(ws + (8u << 20));       // 2 MB each
  bf16_t* Wkb = (bf16_t*)(ws + (10u << 20));
  bf16_t* Wvb = (bf16_t*)(ws + (12u << 20));
  bf16_t* Wob = (bf16_t*)(ws + (14u << 20));
  bf16_t* Qbf = (bf16_t*)(ws + (16u << 20));      // 8 MB  [BH][S][64]
  bf16_t* Kbf = (bf16_t*)(ws + (24u << 20));      // 8 MB  [BH][S][64]
  bf16_t* Vtb = (bf16_t*)(ws + (32u << 20));      // 8 MB  [BH][64][S]
  bf16_t* Oat = (bf16_t*)(ws + (40u << 20));      // 8 MB  [B][S][1024]
  float*  o_part = (float*)(ws + (48u << 20));    // 32 MB [2][BH][S][64] fp32
  float*  l_part = (float*)(ws + (80u << 20));    // 512KB [2][BH][S]
  const bool ks2 = ws_size >= ((80ull << 20) + 524288ull);

  // fp32 -> bf16 converts (single launch)
  cvt_all_kernel<<<8192, 256, 0, stream>>>(H, Wq, Wk, Wv, Wo, Hb, Wqb, Wkb, Wvb, Wob);

  // Q/K/V projections + bias + per-head normalize -> bf16 Q,K,[V^T]
  gemm_bt_kernel<1><<<dim3(8, 32, 3), 256, 0, stream>>>(
      Hb, Wqb, Wkb, Wvb, bq, bk, bv, Qbf, Kbf, Vtb);

  // MFMA spherical flash attention
  if (ks2) {
    mfma_attn_kernel<2><<<1024, 256, 0, stream>>>(Qbf, Kbf, Vtb, Oat, o_part, l_part);
    attn_combine_kernel<<<4096, 256, 0, stream>>>(o_part, l_part, Oat);
  } else {
    mfma_attn_kernel<1><<<512, 256, 0, stream>>>(Qbf, Kbf, Vtb, Oat, o_part, l_part);
  }

  // output projection -> d_out fp32 [B][S][1024]
  gemm_bt_kernel<0><<<dim3(8, 32, 1), 256, 0, stream>>>(
      Oat, Wob, Wob, Wob, bo, bo, bo, out, out, out);
}

// Round 10
// 144.843 us; speedup vs baseline: 1.4166x; 1.1608x over previous
//
#include <hip/hip_runtime.h>
#include <hip/hip_bf16.h>

typedef __bf16 bf16_t;
typedef __bf16 bf16x8 __attribute__((ext_vector_type(8)));
typedef __bf16 bf16x4 __attribute__((ext_vector_type(4)));
typedef float f32x2 __attribute__((ext_vector_type(2)));
typedef float f32x4 __attribute__((ext_vector_type(4)));
typedef float f32x16 __attribute__((ext_vector_type(16)));

#define NB 2
#define SEQ 2048
#define DMODEL 1024
#define NHEAD 16
#define DHEAD 64

__device__ inline void gload_lds16(const void* g, void* lds) {
  __builtin_amdgcn_global_load_lds((const __attribute__((address_space(1))) void*)g,
                                   (__attribute__((address_space(3))) void*)lds,
                                   16, 0, 0);
}

// ---------------- fused fp32 -> bf16 convert (H + 4 weights, one launch) ----------------
__global__ __launch_bounds__(256) void cvt_all_kernel(
    const float* __restrict__ H,  const float* __restrict__ Wq, const float* __restrict__ Wk,
    const float* __restrict__ Wv, const float* __restrict__ Wo,
    bf16_t* __restrict__ Hb, bf16_t* __restrict__ Wqb, bf16_t* __restrict__ Wkb,
    bf16_t* __restrict__ Wvb, bf16_t* __restrict__ Wob)
{
  const int b = blockIdx.x;
  const float* src; bf16_t* dst; int idx;
  if (b < 4096) { src = H; dst = Hb; idx = b; }
  else {
    const int r = b - 4096; const int s = r >> 10; idx = r & 1023;
    src = (s == 0) ? Wq : (s == 1) ? Wk : (s == 2) ? Wv : Wo;
    dst = (s == 0) ? Wqb : (s == 1) ? Wkb : (s == 2) ? Wvb : Wob;
  }
  const int i = idx * 256 + threadIdx.x;
  float4 v = ((const float4*)src)[i];
  bf16x4 o;
  o[0] = (bf16_t)v.x; o[1] = (bf16_t)v.y; o[2] = (bf16_t)v.z; o[3] = (bf16_t)v.w;
  ((bf16x4*)dst)[i] = o;
}

// ---------------- bf16 TN GEMM: C[M][N] = A[M][K] * W[N][K]^T + bias ----------------
template<int MODE>
__global__ __launch_bounds__(256) void gemm_bt_kernel(
    const bf16_t* __restrict__ A,
    const bf16_t* __restrict__ W0, const bf16_t* __restrict__ W1, const bf16_t* __restrict__ W2,
    const float* __restrict__ bias0, const float* __restrict__ bias1, const float* __restrict__ bias2,
    void* out0, void* out1, void* out2)
{
  __shared__ bf16_t As[128 * 64];   // [row][64 bf16 = 128B], XOR-swizzled
  __shared__ bf16_t Bs[128 * 64];
  const int tid = threadIdx.x;
  const int lane = tid & 63;
  const int w = tid >> 6;
  const int mt = blockIdx.y, nt = blockIdx.x, z = blockIdx.z;
  const bf16_t* Wp = (z == 0) ? W0 : ((z == 1) ? W1 : W2);
  const float* bp  = (z == 0) ? bias0 : ((z == 1) ? bias1 : bias2);

  const int wr = w >> 1, wc = w & 1;
  const int fr = lane & 15, fq = lane >> 4;

  const int r_in = lane >> 3;
  const int cswz = ((lane & 7) ^ (r_in & 7)) << 4;
  const unsigned lbase = (unsigned)__builtin_amdgcn_readfirstlane(w * 4096);

  f32x4 acc[4][4] = {};

  const char* Ab = (const char*)(A + (size_t)mt * 128 * DMODEL);
  const char* Bb = (const char*)(Wp + (size_t)nt * 128 * DMODEL);

  for (int kt = 0; kt < DMODEL / 64; ++kt) {
    const size_t k0b = (size_t)kt * 128;
    #pragma unroll
    for (int i = 0; i < 4; ++i) {
      const size_t row = (size_t)(w * 32 + i * 8 + r_in);
      gload_lds16(Ab + row * (DMODEL * 2) + k0b + cswz, (char*)As + lbase + i * 1024);
      gload_lds16(Bb + row * (DMODEL * 2) + k0b + cswz, (char*)Bs + lbase + i * 1024);
    }
    __syncthreads();

    bf16x8 a[4][2], b[4][2];
    #pragma unroll
    for (int m = 0; m < 4; ++m)
      #pragma unroll
      for (int ks = 0; ks < 2; ++ks)
        a[m][ks] = *(const bf16x8*)((const char*)As + (wr * 64 + m * 16 + fr) * 128 +
                                    ((ks * 64 + fq * 16) ^ ((fr & 7) << 4)));
    #pragma unroll
    for (int n = 0; n < 4; ++n)
      #pragma unroll
      for (int ks = 0; ks < 2; ++ks)
        b[n][ks] = *(const bf16x8*)((const char*)Bs + (wc * 64 + n * 16 + fr) * 128 +
                                    ((ks * 64 + fq * 16) ^ ((fr & 7) << 4)));
    __builtin_amdgcn_s_setprio(1);
    #pragma unroll
    for (int m = 0; m < 4; ++m)
      #pragma unroll
      for (int n = 0; n < 4; ++n)
        #pragma unroll
        for (int ks = 0; ks < 2; ++ks)
          acc[m][n] = __builtin_amdgcn_mfma_f32_16x16x32_bf16(a[m][ks], b[n][ks], acc[m][n], 0, 0, 0);
    __builtin_amdgcn_s_setprio(0);
    __syncthreads();
  }

  float bv[4];
  const int cb = nt * 128 + wc * 64;
  #pragma unroll
  for (int n = 0; n < 4; ++n) bv[n] = bp[cb + n * 16 + fr];

  if constexpr (MODE == 0) {
    float* outp = (float*)out0;
    #pragma unroll
    for (int m = 0; m < 4; ++m) {
      #pragma unroll
      for (int j = 0; j < 4; ++j) {
        const int row = mt * 128 + wr * 64 + m * 16 + fq * 4 + j;
        float* orow = outp + (size_t)row * DMODEL + cb;
        #pragma unroll
        for (int n = 0; n < 4; ++n)
          orow[n * 16 + fr] = acc[m][n][j] + bv[n];
      }
    }
  } else {
    const int h = nt * 2 + wc;
    #pragma unroll
    for (int m = 0; m < 4; ++m) {
      #pragma unroll
      for (int j = 0; j < 4; ++j) {
        float v0 = acc[m][0][j] + bv[0];
        float v1 = acc[m][1][j] + bv[1];
        float v2 = acc[m][2][j] + bv[2];
        float v3 = acc[m][3][j] + bv[3];
        float ss = v0 * v0 + v1 * v1 + v2 * v2 + v3 * v3;
        ss += __shfl_xor(ss, 1);
        ss += __shfl_xor(ss, 2);
        ss += __shfl_xor(ss, 4);
        ss += __shfl_xor(ss, 8);
        const float inv = 1.0f / fmaxf(sqrtf(ss), 1e-10f);
        const int row = mt * 128 + wr * 64 + m * 16 + fq * 4 + j;
        const int bb = row >> 11, sr = row & (SEQ - 1);
        if (z < 2) {
          bf16_t* op = ((z == 0) ? (bf16_t*)out0 : (bf16_t*)out1)
                       + (((size_t)(bb * NHEAD + h)) * SEQ + sr) * DHEAD;
          op[0 * 16 + fr] = (bf16_t)(v0 * inv);
          op[1 * 16 + fr] = (bf16_t)(v1 * inv);
          op[2 * 16 + fr] = (bf16_t)(v2 * inv);
          op[3 * 16 + fr] = (bf16_t)(v3 * inv);
        } else {
          bf16_t* vp = (bf16_t*)out2 + ((size_t)(bb * NHEAD + h)) * DHEAD * SEQ + sr;
          vp[(size_t)(0 * 16 + fr) * SEQ] = (bf16_t)(v0 * inv);
          vp[(size_t)(1 * 16 + fr) * SEQ] = (bf16_t)(v1 * inv);
          vp[(size_t)(2 * 16 + fr) * SEQ] = (bf16_t)(v2 * inv);
          vp[(size_t)(3 * 16 + fr) * SEQ] = (bf16_t)(v3 * inv);
        }
      }
    }
  }
}

// ---------------- MFMA spherical flash attention: 32x32x16, counted-vmcnt pipeline ----
// Block = 4 waves x 32 q-rows = 128 q. KS=2: blocks split keys (z = 0/1, 1024 keys),
// fp32 partials + combine kernel. LDS: 64-key K+V tiles, double-buffered, [32 rows][256B]
// with c ^= (row&15)<<4 swizzle. Swapped QK^T (S[key][q], q=lane&31), P via
// cvt_pk + permlane32_swap, PV transposed. Loop uses raw s_barrier + counted
// s_waitcnt vmcnt(4): next tile's 4 global_load_lds stay in flight across barriers.
#define PSWAP(x, y) asm("v_permlane32_swap_b32 %0, %1" : "+v"(x), "+v"(y))
#define CVTPK(d, a, b) asm("v_cvt_pk_bf16_f32 %0, %1, %2" : "=v"(d) : "v"(a), "v"(b))
#define WAITVM(n) asm volatile("s_waitcnt vmcnt(" #n ")" ::: "memory")
#define V2(x) ((f32x2){(x), (x)})

// score transform w = exp(asin(c)/8) (scale-invariant, pure FMA) on packed f32x2,
// then pack to the PV B-fragment pair via cvt_pk + permlane32_swap.
__device__ inline void score_pack(const f32x16& accp, float& l_acc, bf16x8& pf0, bf16x8& pf1) {
  f32x2 p2[8];
  #pragma unroll
  for (int i = 0; i < 8; ++i) {
    f32x2 cv; cv[0] = accp[2 * i]; cv[1] = accp[2 * i + 1];
    const f32x2 c2 = cv * cv;
    f32x2 a = __builtin_elementwise_fma(c2, V2(0.00379774f), V2(0.00558036f));
    a = __builtin_elementwise_fma(c2, a, V2(0.00937500f));
    a = __builtin_elementwise_fma(c2, a, V2(0.02083333f));
    a = __builtin_elementwise_fma(c2, a, V2(0.12500000f));
    const f32x2 s = a * cv;                       // asin(c)/8
    f32x2 e = __builtin_elementwise_fma(s, V2(0.16666667f), V2(0.5f));
    e = __builtin_elementwise_fma(s, e, V2(1.0f));
    e = __builtin_elementwise_fma(s, e, V2(1.0f)); // exp(s), deg-3
    p2[i] = e;
  }
  const f32x2 t01 = p2[0] + p2[1], t23 = p2[2] + p2[3];
  const f32x2 t45 = p2[4] + p2[5], t67 = p2[6] + p2[7];
  const f32x2 tt = (t01 + t23) + (t45 + t67);
  l_acc += tt[0] + tt[1];
  unsigned dwA0, dwA1, dwA2, dwA3, dwB0, dwB1, dwB2, dwB3;
  CVTPK(dwA0, p2[0][0], p2[0][1]);  CVTPK(dwB0, p2[1][0], p2[1][1]);
  CVTPK(dwA1, p2[2][0], p2[2][1]);  CVTPK(dwB1, p2[3][0], p2[3][1]);
  CVTPK(dwA2, p2[4][0], p2[4][1]);  CVTPK(dwB2, p2[5][0], p2[5][1]);
  CVTPK(dwA3, p2[6][0], p2[6][1]);  CVTPK(dwB3, p2[7][0], p2[7][1]);
  PSWAP(dwA0, dwA1);  PSWAP(dwB0, dwB1);
  PSWAP(dwA2, dwA3);  PSWAP(dwB2, dwB3);
  typedef unsigned u32x4_ __attribute__((ext_vector_type(4)));
  u32x4_ t0_ = { dwA0, dwB0, dwA1, dwB1 };
  u32x4_ t1_ = { dwA2, dwB2, dwA3, dwB3 };
  pf0 = __builtin_bit_cast(bf16x8, t0_);
  pf1 = __builtin_bit_cast(bf16x8, t1_);
}

template<int KS>
__global__ __launch_bounds__(256, 3) void mfma_attn_kernel(
    const bf16_t* __restrict__ Qb, const bf16_t* __restrict__ Kb,
    const bf16_t* __restrict__ Vt, bf16_t* __restrict__ Oat,
    float* __restrict__ o_part, float* __restrict__ l_part)
{
  __shared__ char smem[32768];   // [buf][ K 8KB | V 8KB ]

  const int tid = threadIdx.x;
  const int lane = tid & 63;
  const int qw = tid >> 6;              // 4 q-waves
  const int l31 = lane & 31, l5 = lane >> 5;

  // XCD-aware decode: xcd gets heads 4*xcd..4*xcd+3
  const int p = blockIdx.x;
  const int xcd = p & 7;
  const int j = p >> 3;
  int bh, qt, z;
  if (KS == 2) { bh = xcd * 4 + (j >> 5); qt = (j & 31) >> 1; z = j & 1; }
  else         { bh = xcd * 4 + (j >> 4); qt = j & 15;        z = 0;     }
  const int q0 = qt * 128 + qw * 32;
  const int NT = (KS == 2) ? 16 : 32;   // 64-key tiles for this block

  // persistent Q B-fragments: lane holds Q[q=q0+l31][seg*16 + l5*8 .. +7]
  const bf16_t* Qp = Qb + ((size_t)bh * SEQ + q0 + l31) * DHEAD + l5 * 8;
  bf16x8 b_q[4];
  #pragma unroll
  for (int m = 0; m < 4; ++m)
    b_q[m] = *(const bf16x8*)(Qp + m * 16);

  const char* KbaseH = (const char*)(Kb + (size_t)bh * SEQ * DHEAD) + (size_t)z * 1024 * DHEAD * 2;
  const char* VbaseH = (const char*)(Vt + (size_t)bh * DHEAD * SEQ) + (size_t)z * 1024 * 2;

  // staging: 8 chunks of 1KB per K (resp. V) tile; wave qw owns chunks 2qw, 2qw+1
  const int chA = 2 * qw, chB = 2 * qw + 1;
  int koffA, koffB, voffA, voffB;
  {
    const int rA = chA * 4 + (lane >> 4), rB = chB * 4 + (lane >> 4);
    const int c = (lane & 15) * 16;
    const int cpA = c ^ ((rA & 15) << 4), cpB = c ^ ((rB & 15) << 4);
    koffA = (rA + ((cpA >> 7) << 5)) * 128 + (cpA & 127);
    koffB = (rB + ((cpB >> 7) << 5)) * 128 + (cpB & 127);
    voffA = (rA + ((cpA >> 7) << 5)) * (SEQ * 2) + (cpA & 127);
    voffB = (rB + ((cpB >> 7) << 5)) * (SEQ * 2) + (cpB & 127);
  }
  const unsigned stKA = (unsigned)__builtin_amdgcn_readfirstlane(chA * 1024);
  const unsigned stKB = (unsigned)__builtin_amdgcn_readfirstlane(chB * 1024);

  const int swz = (l31 & 15) << 4;
  const unsigned kRow = l31 * 256;

  f32x16 acc_o0 = {}, acc_o1 = {};
  float l_acc = 0.0f;

  #define STAGE(t, buf)                                                                    \
    do {                                                                                   \
      const char* Kt_ = KbaseH + (size_t)(t) * 8192;                                       \
      const char* Vc_ = VbaseH + (size_t)(t) * 128;                                        \
      gload_lds16(Kt_ + koffA, smem + stKA + (buf) * 16384);                               \
      gload_lds16(Kt_ + koffB, smem + stKB + (buf) * 16384);                               \
      gload_lds16(Vc_ + voffA, smem + stKA + (buf) * 16384 + 8192);                        \
      gload_lds16(Vc_ + voffB, smem + stKB + (buf) * 16384 + 8192);                        \
    } while (0)

  #define CHUNK(buf, c0)                                                                   \
    do {                                                                                   \
      const char* kb_ = smem + (buf) * 16384 + kRow;                                       \
      bf16x8 ak0 = *(const bf16x8*)(kb_ + (((c0) * 128 +  0 + l5 * 16) ^ swz));            \
      bf16x8 ak1 = *(const bf16x8*)(kb_ + (((c0) * 128 + 32 + l5 * 16) ^ swz));            \
      bf16x8 ak2 = *(const bf16x8*)(kb_ + (((c0) * 128 + 64 + l5 * 16) ^ swz));            \
      bf16x8 ak3 = *(const bf16x8*)(kb_ + (((c0) * 128 + 96 + l5 * 16) ^ swz));            \
      f32x16 accp = {};                                                                    \
      __builtin_amdgcn_s_setprio(1);                                                       \
      accp = __builtin_amdgcn_mfma_f32_32x32x16_bf16(ak0, b_q[0], accp, 0, 0, 0);          \
      accp = __builtin_amdgcn_mfma_f32_32x32x16_bf16(ak1, b_q[1], accp, 0, 0, 0);          \
      accp = __builtin_amdgcn_mfma_f32_32x32x16_bf16(ak2, b_q[2], accp, 0, 0, 0);          \
      accp = __builtin_amdgcn_mfma_f32_32x32x16_bf16(ak3, b_q[3], accp, 0, 0, 0);          \
      __builtin_amdgcn_s_setprio(0);                                                       \
      const char* vb_ = smem + (buf) * 16384 + 8192 + kRow;                                \
      bf16x8 av00 = *(const bf16x8*)(vb_ + ((      (c0) * 64 +  0 + l5 * 16) ^ swz));      \
      bf16x8 av01 = *(const bf16x8*)(vb_ + ((      (c0) * 64 + 32 + l5 * 16) ^ swz));      \
      bf16x8 av10 = *(const bf16x8*)(vb_ + ((128 + (c0) * 64 +  0 + l5 * 16) ^ swz));      \
      bf16x8 av11 = *(const bf16x8*)(vb_ + ((128 + (c0) * 64 + 32 + l5 * 16) ^ swz));      \
      bf16x8 pf0, pf1;                                                                     \
      score_pack(accp, l_acc, pf0, pf1);                                                   \
      __builtin_amdgcn_s_setprio(1);                                                       \
      acc_o0 = __builtin_amdgcn_mfma_f32_32x32x16_bf16(av00, pf0, acc_o0, 0, 0, 0);        \
      acc_o0 = __builtin_amdgcn_mfma_f32_32x32x16_bf16(av01, pf1, acc_o0, 0, 0, 0);        \
      acc_o1 = __builtin_amdgcn_mfma_f32_32x32x16_bf16(av10, pf0, acc_o1, 0, 0, 0);        \
      acc_o1 = __builtin_amdgcn_mfma_f32_32x32x16_bf16(av11, pf1, acc_o1, 0, 0, 0);        \
      __builtin_amdgcn_s_setprio(0);                                                       \
    } while (0)

  #define TILE(buf) do { CHUNK(buf, 0); CHUNK(buf, 1); } while (0)

  // counted-vmcnt double-buffer pipeline: tiles t and t+1 always in flight.
  STAGE(0, 0);
  STAGE(1, 1);

  for (int t2 = 0; t2 < NT / 2 - 1; ++t2) {
    WAITVM(4);                          // tile 2*t2 landed (own 4 loads)
    __builtin_amdgcn_s_barrier();       // all waves' loads landed
    TILE(0);
    __builtin_amdgcn_s_barrier();       // all waves done reading buf 0
    STAGE(2 * t2 + 2, 0);
    WAITVM(4);                          // tile 2*t2+1 landed
    __builtin_amdgcn_s_barrier();
    TILE(1);
    __builtin_amdgcn_s_barrier();
    STAGE(2 * t2 + 3, 1);
  }
  // tail: tiles NT-2, NT-1 (no further prefetch)
  WAITVM(4);
  __builtin_amdgcn_s_barrier();
  TILE(0);
  WAITVM(0);
  __builtin_amdgcn_s_barrier();
  TILE(1);
  #undef TILE
  #undef CHUNK
  #undef STAGE

  // ---- epilogue ----
  l_acc += __shfl_xor(l_acc, 32);       // full l for q = q0 + l31

  if (KS == 2) {
    float* po = o_part + ((size_t)z * (32 * SEQ) + (size_t)bh * SEQ + q0 + l31) * 64;
    #pragma unroll
    for (int blk = 0; blk < 2; ++blk) {
      const f32x16& ao = blk ? acc_o1 : acc_o0;
      #pragma unroll
      for (int g = 0; g < 4; ++g) {
        f32x4 ov = { ao[4 * g + 0], ao[4 * g + 1], ao[4 * g + 2], ao[4 * g + 3] };
        *(f32x4*)(po + blk * 32 + 8 * g + 4 * l5) = ov;
      }
    }
    if (lane < 32)
      l_part[(size_t)z * (32 * SEQ) + (size_t)bh * SEQ + q0 + l31] = l_acc;
  } else {
    const float invl = __builtin_amdgcn_rcpf(l_acc);
    const int bb = bh >> 4, h = bh & 15;
    bf16_t* op = Oat + ((size_t)bb * SEQ + q0 + l31) * DMODEL + h * DHEAD;
    #pragma unroll
    for (int blk = 0; blk < 2; ++blk) {
      const f32x16& ao = blk ? acc_o1 : acc_o0;
      #pragma unroll
      for (int g = 0; g < 4; ++g) {
        bf16x4 ov;
        ov[0] = (bf16_t)(ao[4 * g + 0] * invl);
        ov[1] = (bf16_t)(ao[4 * g + 1] * invl);
        ov[2] = (bf16_t)(ao[4 * g + 2] * invl);
        ov[3] = (bf16_t)(ao[4 * g + 3] * invl);
        *(bf16x4*)(op + blk * 32 + 8 * g + 4 * l5) = ov;
      }
    }
  }
}

// ---------------- key-split combine: O = (o0+o1)/(l0+l1), fp32 -> bf16 Oat ----------------
__global__ __launch_bounds__(256) void attn_combine_kernel(
    const float* __restrict__ o_part, const float* __restrict__ l_part,
    bf16_t* __restrict__ Oat)
{
  const int idx = blockIdx.x * 256 + threadIdx.x;   // 0 .. 1048575
  const int row = idx >> 4, u = idx & 15;           // row = bh*2048 + q
  const float l = l_part[row] + l_part[32 * SEQ + row];
  const float inv = __builtin_amdgcn_rcpf(l);
  const f32x4 a = ((const f32x4*)o_part)[idx];
  const f32x4 b = ((const f32x4*)o_part)[(32 * SEQ * 16) + idx];
  bf16x4 o;
  o[0] = (bf16_t)((a[0] + b[0]) * inv);
  o[1] = (bf16_t)((a[1] + b[1]) * inv);
  o[2] = (bf16_t)((a[2] + b[2]) * inv);
  o[3] = (bf16_t)((a[3] + b[3]) * inv);
  const int bh = row >> 11, q = row & (SEQ - 1);
  const int bb = bh >> 4, h = bh & 15;
  ((bf16x4*)(Oat + ((size_t)bb * SEQ + q) * DMODEL + h * DHEAD))[u] = o;
}

extern "C" void kernel_launch(void* const* d_in, const int* in_sizes, int n_in,
                              void* d_out, int out_size, void* d_ws, size_t ws_size,
                              hipStream_t stream)
{
  const float* H  = (const float*)d_in[0];
  const float* Wq = (const float*)d_in[1];
  const float* bq = (const float*)d_in[2];
  const float* Wk = (const float*)d_in[3];
  const float* bk = (const float*)d_in[4];
  const float* Wv = (const float*)d_in[5];
  const float* bv = (const float*)d_in[6];
  const float* Wo = (const float*)d_in[7];
  const float* bo = (const float*)d_in[8];
  float* out = (float*)d_out;

  char* ws = (char*)d_ws;
  bf16_t* Hb  = (bf16_t*)(ws);                    // 8 MB  [B*S][1024]
  bf16_t* Wqb = (bf16_t*)(ws + (8u << 20));       // 2 MB each
  bf16_t* Wkb = (bf16_t*)(ws + (10u << 20));
  bf16_t* Wvb = (bf16_t*)(ws + (12u << 20));
  bf16_t* Wob = (bf16_t*)(ws + (14u << 20));
  bf16_t* Qbf = (bf16_t*)(ws + (16u << 20));      // 8 MB  [BH][S][64]
  bf16_t* Kbf = (bf16_t*)(ws + (24u << 20));      // 8 MB  [BH][S][64]
  bf16_t* Vtb = (bf16_t*)(ws + (32u << 20));      // 8 MB  [BH][64][S]
  bf16_t* Oat = (bf16_t*)(ws + (40u << 20));      // 8 MB  [B][S][1024]
  float*  o_part = (float*)(ws + (48u << 20));    // 32 MB [2][BH][S][64] fp32
  float*  l_part = (float*)(ws + (80u << 20));    // 512KB [2][BH][S]
  const bool ks2 = ws_size >= ((80ull << 20) + 524288ull);

  // fp32 -> bf16 converts (single launch)
  cvt_all_kernel<<<8192, 256, 0, stream>>>(H, Wq, Wk, Wv, Wo, Hb, Wqb, Wkb, Wvb, Wob);

  // Q/K/V projections + bias + per-head normalize -> bf16 Q,K,[V^T]
  gemm_bt_kernel<1><<<dim3(8, 32, 3), 256, 0, stream>>>(
      Hb, Wqb, Wkb, Wvb, bq, bk, bv, Qbf, Kbf, Vtb);

  // MFMA spherical flash attention
  if (ks2) {
    mfma_attn_kernel<2><<<1024, 256, 0, stream>>>(Qbf, Kbf, Vtb, Oat, o_part, l_part);
    attn_combine_kernel<<<4096, 256, 0, stream>>>(o_part, l_part, Oat);
  } else {
    mfma_attn_kernel<1><<<512, 256, 0, stream>>>(Qbf, Kbf, Vtb, Oat, o_part, l_part);
  }

  // output projection -> d_out fp32 [B][S][1024]
  gemm_bt_kernel<0><<<dim3(8, 32, 1), 256, 0, stream>>>(
      Oat, Wob, Wob, Wob, bo, bo, bo, out, out, out);
}

// Round 11
// 140.486 us; speedup vs baseline: 1.4605x; 1.0310x over previous
//
#include <hip/hip_runtime.h>
#include <hip/hip_bf16.h>

typedef __bf16 bf16_t;
typedef __bf16 bf16x8 __attribute__((ext_vector_type(8)));
typedef __bf16 bf16x4 __attribute__((ext_vector_type(4)));
typedef float f32x2 __attribute__((ext_vector_type(2)));
typedef float f32x4 __attribute__((ext_vector_type(4)));
typedef float f32x16 __attribute__((ext_vector_type(16)));

#define NB 2
#define SEQ 2048
#define DMODEL 1024
#define NHEAD 16
#define DHEAD 64

__device__ inline void gload_lds16(const void* g, void* lds) {
  __builtin_amdgcn_global_load_lds((const __attribute__((address_space(1))) void*)g,
                                   (__attribute__((address_space(3))) void*)lds,
                                   16, 0, 0);
}

// ---------------- fused fp32 -> bf16 convert (H + 4 weights, one launch) ----------------
__global__ __launch_bounds__(256) void cvt_all_kernel(
    const float* __restrict__ H,  const float* __restrict__ Wq, const float* __restrict__ Wk,
    const float* __restrict__ Wv, const float* __restrict__ Wo,
    bf16_t* __restrict__ Hb, bf16_t* __restrict__ Wqb, bf16_t* __restrict__ Wkb,
    bf16_t* __restrict__ Wvb, bf16_t* __restrict__ Wob)
{
  const int b = blockIdx.x;
  const float* src; bf16_t* dst; int idx;
  if (b < 4096) { src = H; dst = Hb; idx = b; }
  else {
    const int r = b - 4096; const int s = r >> 10; idx = r & 1023;
    src = (s == 0) ? Wq : (s == 1) ? Wk : (s == 2) ? Wv : Wo;
    dst = (s == 0) ? Wqb : (s == 1) ? Wkb : (s == 2) ? Wvb : Wob;
  }
  const int i = idx * 256 + threadIdx.x;
  float4 v = ((const float4*)src)[i];
  bf16x4 o;
  o[0] = (bf16_t)v.x; o[1] = (bf16_t)v.y; o[2] = (bf16_t)v.z; o[3] = (bf16_t)v.w;
  ((bf16x4*)dst)[i] = o;
}

// ---------------- bf16 TN GEMM: C[M][N] = A[M][K] * W[N][K]^T + bias ----------------
template<int MODE>
__global__ __launch_bounds__(256) void gemm_bt_kernel(
    const bf16_t* __restrict__ A,
    const bf16_t* __restrict__ W0, const bf16_t* __restrict__ W1, const bf16_t* __restrict__ W2,
    const float* __restrict__ bias0, const float* __restrict__ bias1, const float* __restrict__ bias2,
    void* out0, void* out1, void* out2)
{
  __shared__ bf16_t As[128 * 64];   // [row][64 bf16 = 128B], XOR-swizzled
  __shared__ bf16_t Bs[128 * 64];
  const int tid = threadIdx.x;
  const int lane = tid & 63;
  const int w = tid >> 6;
  const int mt = blockIdx.y, nt = blockIdx.x, z = blockIdx.z;
  const bf16_t* Wp = (z == 0) ? W0 : ((z == 1) ? W1 : W2);
  const float* bp  = (z == 0) ? bias0 : ((z == 1) ? bias1 : bias2);

  const int wr = w >> 1, wc = w & 1;
  const int fr = lane & 15, fq = lane >> 4;

  const int r_in = lane >> 3;
  const int cswz = ((lane & 7) ^ (r_in & 7)) << 4;
  const unsigned lbase = (unsigned)__builtin_amdgcn_readfirstlane(w * 4096);

  f32x4 acc[4][4] = {};

  const char* Ab = (const char*)(A + (size_t)mt * 128 * DMODEL);
  const char* Bb = (const char*)(Wp + (size_t)nt * 128 * DMODEL);

  for (int kt = 0; kt < DMODEL / 64; ++kt) {
    const size_t k0b = (size_t)kt * 128;
    #pragma unroll
    for (int i = 0; i < 4; ++i) {
      const size_t row = (size_t)(w * 32 + i * 8 + r_in);
      gload_lds16(Ab + row * (DMODEL * 2) + k0b + cswz, (char*)As + lbase + i * 1024);
      gload_lds16(Bb + row * (DMODEL * 2) + k0b + cswz, (char*)Bs + lbase + i * 1024);
    }
    __syncthreads();

    bf16x8 a[4][2], b[4][2];
    #pragma unroll
    for (int m = 0; m < 4; ++m)
      #pragma unroll
      for (int ks = 0; ks < 2; ++ks)
        a[m][ks] = *(const bf16x8*)((const char*)As + (wr * 64 + m * 16 + fr) * 128 +
                                    ((ks * 64 + fq * 16) ^ ((fr & 7) << 4)));
    #pragma unroll
    for (int n = 0; n < 4; ++n)
      #pragma unroll
      for (int ks = 0; ks < 2; ++ks)
        b[n][ks] = *(const bf16x8*)((const char*)Bs + (wc * 64 + n * 16 + fr) * 128 +
                                    ((ks * 64 + fq * 16) ^ ((fr & 7) << 4)));
    __builtin_amdgcn_s_setprio(1);
    #pragma unroll
    for (int m = 0; m < 4; ++m)
      #pragma unroll
      for (int n = 0; n < 4; ++n)
        #pragma unroll
        for (int ks = 0; ks < 2; ++ks)
          acc[m][n] = __builtin_amdgcn_mfma_f32_16x16x32_bf16(a[m][ks], b[n][ks], acc[m][n], 0, 0, 0);
    __builtin_amdgcn_s_setprio(0);
    __syncthreads();
  }

  float bv[4];
  const int cb = nt * 128 + wc * 64;
  #pragma unroll
  for (int n = 0; n < 4; ++n) bv[n] = bp[cb + n * 16 + fr];

  if constexpr (MODE == 0) {
    float* outp = (float*)out0;
    #pragma unroll
    for (int m = 0; m < 4; ++m) {
      #pragma unroll
      for (int j = 0; j < 4; ++j) {
        const int row = mt * 128 + wr * 64 + m * 16 + fq * 4 + j;
        float* orow = outp + (size_t)row * DMODEL + cb;
        #pragma unroll
        for (int n = 0; n < 4; ++n)
          orow[n * 16 + fr] = acc[m][n][j] + bv[n];
      }
    }
  } else {
    const int h = nt * 2 + wc;
    #pragma unroll
    for (int m = 0; m < 4; ++m) {
      #pragma unroll
      for (int j = 0; j < 4; ++j) {
        float v0 = acc[m][0][j] + bv[0];
        float v1 = acc[m][1][j] + bv[1];
        float v2 = acc[m][2][j] + bv[2];
        float v3 = acc[m][3][j] + bv[3];
        float ss = v0 * v0 + v1 * v1 + v2 * v2 + v3 * v3;
        ss += __shfl_xor(ss, 1);
        ss += __shfl_xor(ss, 2);
        ss += __shfl_xor(ss, 4);
        ss += __shfl_xor(ss, 8);
        const float inv = 1.0f / fmaxf(sqrtf(ss), 1e-10f);
        const int row = mt * 128 + wr * 64 + m * 16 + fq * 4 + j;
        const int bb = row >> 11, sr = row & (SEQ - 1);
        if (z < 2) {
          bf16_t* op = ((z == 0) ? (bf16_t*)out0 : (bf16_t*)out1)
                       + (((size_t)(bb * NHEAD + h)) * SEQ + sr) * DHEAD;
          op[0 * 16 + fr] = (bf16_t)(v0 * inv);
          op[1 * 16 + fr] = (bf16_t)(v1 * inv);
          op[2 * 16 + fr] = (bf16_t)(v2 * inv);
          op[3 * 16 + fr] = (bf16_t)(v3 * inv);
        } else {
          bf16_t* vp = (bf16_t*)out2 + ((size_t)(bb * NHEAD + h)) * DHEAD * SEQ + sr;
          vp[(size_t)(0 * 16 + fr) * SEQ] = (bf16_t)(v0 * inv);
          vp[(size_t)(1 * 16 + fr) * SEQ] = (bf16_t)(v1 * inv);
          vp[(size_t)(2 * 16 + fr) * SEQ] = (bf16_t)(v2 * inv);
          vp[(size_t)(3 * 16 + fr) * SEQ] = (bf16_t)(v3 * inv);
        }
      }
    }
  }
}

// ---------------- MFMA spherical flash attention: 8-wave, in-block key-split ----------
// Block = 512 thr = 8 waves: qw = w&3 (4 x 32 q-rows = 128 q), kh = w>>2 (2 x 1024 keys).
// LDS 64KB: [kh][buf][ K 8KB | V 8KB ], 64-key tiles, [32 rows][256B], c ^= (row&15)<<4.
// Counted-vmcnt double-buffer pipeline (R10-verified). Swapped QK^T (S[key][q], q=lane&31),
// P via cvt_pk + permlane32_swap, PV transposed. Epilogue: LDS combine across kh, write Oat.
#define PSWAP(x, y) asm("v_permlane32_swap_b32 %0, %1" : "+v"(x), "+v"(y))
#define CVTPK(d, a, b) asm("v_cvt_pk_bf16_f32 %0, %1, %2" : "=v"(d) : "v"(a), "v"(b))
#define WAITVM(n) asm volatile("s_waitcnt vmcnt(" #n ")" ::: "memory")
#define V2(x) ((f32x2){(x), (x)})

// score transform w = exp(asin(c)/8) (scale-invariant, pure FMA) on packed f32x2,
// then pack to the PV B-fragment pair via cvt_pk + permlane32_swap.
__device__ inline void score_pack(const f32x16& accp, float& l_acc, bf16x8& pf0, bf16x8& pf1) {
  f32x2 p2[8];
  #pragma unroll
  for (int i = 0; i < 8; ++i) {
    f32x2 cv; cv[0] = accp[2 * i]; cv[1] = accp[2 * i + 1];
    const f32x2 c2 = cv * cv;
    f32x2 a = __builtin_elementwise_fma(c2, V2(0.00379774f), V2(0.00558036f));
    a = __builtin_elementwise_fma(c2, a, V2(0.00937500f));
    a = __builtin_elementwise_fma(c2, a, V2(0.02083333f));
    a = __builtin_elementwise_fma(c2, a, V2(0.12500000f));
    const f32x2 s = a * cv;                       // asin(c)/8
    f32x2 e = __builtin_elementwise_fma(s, V2(0.16666667f), V2(0.5f));
    e = __builtin_elementwise_fma(s, e, V2(1.0f));
    e = __builtin_elementwise_fma(s, e, V2(1.0f)); // exp(s), deg-3
    p2[i] = e;
  }
  const f32x2 t01 = p2[0] + p2[1], t23 = p2[2] + p2[3];
  const f32x2 t45 = p2[4] + p2[5], t67 = p2[6] + p2[7];
  const f32x2 tt = (t01 + t23) + (t45 + t67);
  l_acc += tt[0] + tt[1];
  unsigned dwA0, dwA1, dwA2, dwA3, dwB0, dwB1, dwB2, dwB3;
  CVTPK(dwA0, p2[0][0], p2[0][1]);  CVTPK(dwB0, p2[1][0], p2[1][1]);
  CVTPK(dwA1, p2[2][0], p2[2][1]);  CVTPK(dwB1, p2[3][0], p2[3][1]);
  CVTPK(dwA2, p2[4][0], p2[4][1]);  CVTPK(dwB2, p2[5][0], p2[5][1]);
  CVTPK(dwA3, p2[6][0], p2[6][1]);  CVTPK(dwB3, p2[7][0], p2[7][1]);
  PSWAP(dwA0, dwA1);  PSWAP(dwB0, dwB1);
  PSWAP(dwA2, dwA3);  PSWAP(dwB2, dwB3);
  typedef unsigned u32x4_ __attribute__((ext_vector_type(4)));
  u32x4_ t0_ = { dwA0, dwB0, dwA1, dwB1 };
  u32x4_ t1_ = { dwA2, dwB2, dwA3, dwB3 };
  pf0 = __builtin_bit_cast(bf16x8, t0_);
  pf1 = __builtin_bit_cast(bf16x8, t1_);
}

__global__ __launch_bounds__(512, 2) void mfma_attn_kernel(
    const bf16_t* __restrict__ Qb, const bf16_t* __restrict__ Kb,
    const bf16_t* __restrict__ Vt, bf16_t* __restrict__ Oat)
{
  __shared__ char smem[65536];   // [kh][buf][ K 8KB | V 8KB ]

  const int tid = threadIdx.x;
  const int lane = tid & 63;
  const int w = tid >> 6;
  const int qw = w & 3, kh = w >> 2;
  const int l31 = lane & 31, l5 = lane >> 5;

  // grid 512; XCD-aware: xcd gets heads 4*xcd..4*xcd+3 (L2 set ~2MB/XCD)
  const int p = blockIdx.x;
  const int xcd = p & 7;
  const int j = p >> 3;                 // 0..63
  const int bh = xcd * 4 + (j >> 4);
  const int qt = j & 15;
  const int q0 = qt * 128 + qw * 32;
  const int NT = 16;                    // 64-key tiles per key-half

  // persistent Q B-fragments: lane holds Q[q=q0+l31][seg*16 + l5*8 .. +7]
  const bf16_t* Qp = Qb + ((size_t)bh * SEQ + q0 + l31) * DHEAD + l5 * 8;
  bf16x8 b_q[4];
  #pragma unroll
  for (int m = 0; m < 4; ++m)
    b_q[m] = *(const bf16x8*)(Qp + m * 16);

  const char* KbaseH = (const char*)(Kb + (size_t)bh * SEQ * DHEAD) + (size_t)kh * 1024 * DHEAD * 2;
  const char* VbaseH = (const char*)(Vt + (size_t)bh * DHEAD * SEQ) + (size_t)kh * 1024 * 2;

  // staging: 8 chunks of 1KB per K (resp. V) tile; q-wave qw owns chunks 2qw, 2qw+1
  const int chA = 2 * qw, chB = 2 * qw + 1;
  int koffA, koffB, voffA, voffB;
  {
    const int rA = chA * 4 + (lane >> 4), rB = chB * 4 + (lane >> 4);
    const int c = (lane & 15) * 16;
    const int cpA = c ^ ((rA & 15) << 4), cpB = c ^ ((rB & 15) << 4);
    koffA = (rA + ((cpA >> 7) << 5)) * 128 + (cpA & 127);
    koffB = (rB + ((cpB >> 7) << 5)) * 128 + (cpB & 127);
    voffA = (rA + ((cpA >> 7) << 5)) * (SEQ * 2) + (cpA & 127);
    voffB = (rB + ((cpB >> 7) << 5)) * (SEQ * 2) + (cpB & 127);
  }
  const unsigned stKA = (unsigned)__builtin_amdgcn_readfirstlane(kh * 32768 + chA * 1024);
  const unsigned stKB = (unsigned)__builtin_amdgcn_readfirstlane(kh * 32768 + chB * 1024);
  const unsigned rb0  = (unsigned)__builtin_amdgcn_readfirstlane(kh * 32768);

  const int swz = (l31 & 15) << 4;
  const unsigned kRow = l31 * 256;

  f32x16 acc_o0 = {}, acc_o1 = {};
  float l_acc = 0.0f;

  #define STAGE(t, buf)                                                                    \
    do {                                                                                   \
      const char* Kt_ = KbaseH + (size_t)(t) * 8192;                                       \
      const char* Vc_ = VbaseH + (size_t)(t) * 128;                                        \
      gload_lds16(Kt_ + koffA, smem + stKA + (buf) * 16384);                               \
      gload_lds16(Kt_ + koffB, smem + stKB + (buf) * 16384);                               \
      gload_lds16(Vc_ + voffA, smem + stKA + (buf) * 16384 + 8192);                        \
      gload_lds16(Vc_ + voffB, smem + stKB + (buf) * 16384 + 8192);                        \
    } while (0)

  #define CHUNK(buf, c0)                                                                   \
    do {                                                                                   \
      const char* kb_ = smem + rb0 + (buf) * 16384 + kRow;                                 \
      bf16x8 ak0 = *(const bf16x8*)(kb_ + (((c0) * 128 +  0 + l5 * 16) ^ swz));            \
      bf16x8 ak1 = *(const bf16x8*)(kb_ + (((c0) * 128 + 32 + l5 * 16) ^ swz));            \
      bf16x8 ak2 = *(const bf16x8*)(kb_ + (((c0) * 128 + 64 + l5 * 16) ^ swz));            \
      bf16x8 ak3 = *(const bf16x8*)(kb_ + (((c0) * 128 + 96 + l5 * 16) ^ swz));            \
      f32x16 accp = {};                                                                    \
      __builtin_amdgcn_s_setprio(1);                                                       \
      accp = __builtin_amdgcn_mfma_f32_32x32x16_bf16(ak0, b_q[0], accp, 0, 0, 0);          \
      accp = __builtin_amdgcn_mfma_f32_32x32x16_bf16(ak1, b_q[1], accp, 0, 0, 0);          \
      accp = __builtin_amdgcn_mfma_f32_32x32x16_bf16(ak2, b_q[2], accp, 0, 0, 0);          \
      accp = __builtin_amdgcn_mfma_f32_32x32x16_bf16(ak3, b_q[3], accp, 0, 0, 0);          \
      __builtin_amdgcn_s_setprio(0);                                                       \
      const char* vb_ = smem + rb0 + (buf) * 16384 + 8192 + kRow;                          \
      bf16x8 av00 = *(const bf16x8*)(vb_ + ((      (c0) * 64 +  0 + l5 * 16) ^ swz));      \
      bf16x8 av01 = *(const bf16x8*)(vb_ + ((      (c0) * 64 + 32 + l5 * 16) ^ swz));      \
      bf16x8 av10 = *(const bf16x8*)(vb_ + ((128 + (c0) * 64 +  0 + l5 * 16) ^ swz));      \
      bf16x8 av11 = *(const bf16x8*)(vb_ + ((128 + (c0) * 64 + 32 + l5 * 16) ^ swz));      \
      bf16x8 pf0, pf1;                                                                     \
      score_pack(accp, l_acc, pf0, pf1);                                                   \
      __builtin_amdgcn_s_setprio(1);                                                       \
      acc_o0 = __builtin_amdgcn_mfma_f32_32x32x16_bf16(av00, pf0, acc_o0, 0, 0, 0);        \
      acc_o0 = __builtin_amdgcn_mfma_f32_32x32x16_bf16(av01, pf1, acc_o0, 0, 0, 0);        \
      acc_o1 = __builtin_amdgcn_mfma_f32_32x32x16_bf16(av10, pf0, acc_o1, 0, 0, 0);        \
      acc_o1 = __builtin_amdgcn_mfma_f32_32x32x16_bf16(av11, pf1, acc_o1, 0, 0, 0);        \
      __builtin_amdgcn_s_setprio(0);                                                       \
    } while (0)

  #define TILE(buf) do { CHUNK(buf, 0); CHUNK(buf, 1); } while (0)

  // counted-vmcnt double-buffer pipeline: tiles t and t+1 always in flight.
  STAGE(0, 0);
  STAGE(1, 1);

  for (int t2 = 0; t2 < NT / 2 - 1; ++t2) {
    WAITVM(4);                          // tile 2*t2 landed (own 4 loads)
    __builtin_amdgcn_s_barrier();       // all waves' loads landed
    TILE(0);
    __builtin_amdgcn_s_barrier();       // all waves done reading buf 0
    STAGE(2 * t2 + 2, 0);
    WAITVM(4);                          // tile 2*t2+1 landed
    __builtin_amdgcn_s_barrier();
    TILE(1);
    __builtin_amdgcn_s_barrier();
    STAGE(2 * t2 + 3, 1);
  }
  // tail: tiles NT-2, NT-1 (no further prefetch)
  WAITVM(4);
  __builtin_amdgcn_s_barrier();
  TILE(0);
  WAITVM(0);
  __builtin_amdgcn_s_barrier();
  TILE(1);
  #undef TILE
  #undef CHUNK
  #undef STAGE

  // ---- epilogue: finish l within wave, combine key halves via LDS, write Oat ----
  l_acc += __shfl_xor(l_acc, 32);       // l for q = q0 + l31 over this key half

  __syncthreads();                      // all tile reads drained; smem reusable
  float* cO = (float*)smem;             // [qw][32][64] fp32 = 32 KB
  float* cL = (float*)(smem + 32768);   // [qw][64]
  if (kh == 1) {
    #pragma unroll
    for (int r = 0; r < 16; ++r) {
      cO[(qw * 32 + r) * 64 + lane] = acc_o0[r];
      cO[(qw * 32 + 16 + r) * 64 + lane] = acc_o1[r];
    }
    cL[qw * 64 + lane] = l_acc;
  }
  __syncthreads();
  if (kh == 0) {
    #pragma unroll
    for (int r = 0; r < 16; ++r) {
      acc_o0[r] += cO[(qw * 32 + r) * 64 + lane];
      acc_o1[r] += cO[(qw * 32 + 16 + r) * 64 + lane];
    }
    l_acc += cL[qw * 64 + lane];
    const float invl = __builtin_amdgcn_rcpf(l_acc);
    const int bb = bh >> 4, h = bh & 15;
    bf16_t* op = Oat + ((size_t)bb * SEQ + q0 + l31) * DMODEL + h * DHEAD;
    #pragma unroll
    for (int blk = 0; blk < 2; ++blk) {
      const f32x16& ao = blk ? acc_o1 : acc_o0;
      #pragma unroll
      for (int g = 0; g < 4; ++g) {
        bf16x4 ov;
        ov[0] = (bf16_t)(ao[4 * g + 0] * invl);
        ov[1] = (bf16_t)(ao[4 * g + 1] * invl);
        ov[2] = (bf16_t)(ao[4 * g + 2] * invl);
        ov[3] = (bf16_t)(ao[4 * g + 3] * invl);
        *(bf16x4*)(op + blk * 32 + 8 * g + 4 * l5) = ov;
      }
    }
  }
}

extern "C" void kernel_launch(void* const* d_in, const int* in_sizes, int n_in,
                              void* d_out, int out_size, void* d_ws, size_t ws_size,
                              hipStream_t stream)
{
  const float* H  = (const float*)d_in[0];
  const float* Wq = (const float*)d_in[1];
  const float* bq = (const float*)d_in[2];
  const float* Wk = (const float*)d_in[3];
  const float* bk = (const float*)d_in[4];
  const float* Wv = (const float*)d_in[5];
  const float* bv = (const float*)d_in[6];
  const float* Wo = (const float*)d_in[7];
  const float* bo = (const float*)d_in[8];
  float* out = (float*)d_out;

  char* ws = (char*)d_ws;
  bf16_t* Hb  = (bf16_t*)(ws);                    // 8 MB  [B*S][1024]
  bf16_t* Wqb = (bf16_t*)(ws + (8u << 20));       // 2 MB each
  bf16_t* Wkb = (bf16_t*)(ws + (10u << 20));
  bf16_t* Wvb = (bf16_t*)(ws + (12u << 20));
  bf16_t* Wob = (bf16_t*)(ws + (14u << 20));
  bf16_t* Qbf = (bf16_t*)(ws + (16u << 20));      // 8 MB  [BH][S][64]
  bf16_t* Kbf = (bf16_t*)(ws + (24u << 20));      // 8 MB  [BH][S][64]
  bf16_t* Vtb = (bf16_t*)(ws + (32u << 20));      // 8 MB  [BH][64][S]
  bf16_t* Oat = (bf16_t*)(ws + (40u << 20));      // 8 MB  [B][S][1024]

  // fp32 -> bf16 converts (single launch)
  cvt_all_kernel<<<8192, 256, 0, stream>>>(H, Wq, Wk, Wv, Wo, Hb, Wqb, Wkb, Wvb, Wob);

  // Q/K/V projections + bias + per-head normalize -> bf16 Q,K,[V^T]
  gemm_bt_kernel<1><<<dim3(8, 32, 3), 256, 0, stream>>>(
      Hb, Wqb, Wkb, Wvb, bq, bk, bv, Qbf, Kbf, Vtb);

  // MFMA spherical flash attention (8-wave, in-block key-split, counted-vmcnt pipeline)
  mfma_attn_kernel<<<512, 512, 0, stream>>>(Qbf, Kbf, Vtb, Oat);

  // output projection -> d_out fp32 [B][S][1024]
  gemm_bt_kernel<0><<<dim3(8, 32, 1), 256, 0, stream>>>(
      Oat, Wob, Wob, Wob, bo, bo, bo, out, out, out);
}

// Round 12
// 137.169 us; speedup vs baseline: 1.4958x; 1.0242x over previous
//
#include <hip/hip_runtime.h>
#include <hip/hip_bf16.h>

typedef __bf16 bf16_t;
typedef __bf16 bf16x8 __attribute__((ext_vector_type(8)));
typedef __bf16 bf16x4 __attribute__((ext_vector_type(4)));
typedef float f32x2 __attribute__((ext_vector_type(2)));
typedef float f32x4 __attribute__((ext_vector_type(4)));
typedef float f32x16 __attribute__((ext_vector_type(16)));

#define NB 2
#define SEQ 2048
#define DMODEL 1024
#define NHEAD 16
#define DHEAD 64

__device__ inline void gload_lds16(const void* g, void* lds) {
  __builtin_amdgcn_global_load_lds((const __attribute__((address_space(1))) void*)g,
                                   (__attribute__((address_space(3))) void*)lds,
                                   16, 0, 0);
}

// ---------------- fused fp32 -> bf16 convert (H + 4 weights, one launch) ----------------
__global__ __launch_bounds__(256) void cvt_all_kernel(
    const float* __restrict__ H,  const float* __restrict__ Wq, const float* __restrict__ Wk,
    const float* __restrict__ Wv, const float* __restrict__ Wo,
    bf16_t* __restrict__ Hb, bf16_t* __restrict__ Wqb, bf16_t* __restrict__ Wkb,
    bf16_t* __restrict__ Wvb, bf16_t* __restrict__ Wob)
{
  const int b = blockIdx.x;
  const float* src; bf16_t* dst; int idx;
  if (b < 4096) { src = H; dst = Hb; idx = b; }
  else {
    const int r = b - 4096; const int s = r >> 10; idx = r & 1023;
    src = (s == 0) ? Wq : (s == 1) ? Wk : (s == 2) ? Wv : Wo;
    dst = (s == 0) ? Wqb : (s == 1) ? Wkb : (s == 2) ? Wvb : Wob;
  }
  const int i = idx * 256 + threadIdx.x;
  float4 v = ((const float4*)src)[i];
  bf16x4 o;
  o[0] = (bf16_t)v.x; o[1] = (bf16_t)v.y; o[2] = (bf16_t)v.z; o[3] = (bf16_t)v.w;
  ((bf16x4*)dst)[i] = o;
}

// ---------------- bf16 TN GEMM: C[M][N] = A[M][K] * W[N][K]^T + bias ----------------
// MODE 0: plain fp32 out. MODE 1: per-head normalize; z=0/1 -> bf16 Q/K [BH][S][64];
// z=2 -> bf16 V^T [BH][64][S] via LDS-transposed coalesced epilogue (As/Bs reused).
template<int MODE>
__global__ __launch_bounds__(256) void gemm_bt_kernel(
    const bf16_t* __restrict__ A,
    const bf16_t* __restrict__ W0, const bf16_t* __restrict__ W1, const bf16_t* __restrict__ W2,
    const float* __restrict__ bias0, const float* __restrict__ bias1, const float* __restrict__ bias2,
    void* out0, void* out1, void* out2)
{
  __shared__ bf16_t As[128 * 64];   // [row][64 bf16 = 128B], XOR-swizzled
  __shared__ bf16_t Bs[128 * 64];
  const int tid = threadIdx.x;
  const int lane = tid & 63;
  const int w = tid >> 6;
  const int mt = blockIdx.y, nt = blockIdx.x, z = blockIdx.z;
  const bf16_t* Wp = (z == 0) ? W0 : ((z == 1) ? W1 : W2);
  const float* bp  = (z == 0) ? bias0 : ((z == 1) ? bias1 : bias2);

  const int wr = w >> 1, wc = w & 1;
  const int fr = lane & 15, fq = lane >> 4;

  const int r_in = lane >> 3;
  const int cswz = ((lane & 7) ^ (r_in & 7)) << 4;
  const unsigned lbase = (unsigned)__builtin_amdgcn_readfirstlane(w * 4096);

  f32x4 acc[4][4] = {};

  const char* Ab = (const char*)(A + (size_t)mt * 128 * DMODEL);
  const char* Bb = (const char*)(Wp + (size_t)nt * 128 * DMODEL);

  for (int kt = 0; kt < DMODEL / 64; ++kt) {
    const size_t k0b = (size_t)kt * 128;
    #pragma unroll
    for (int i = 0; i < 4; ++i) {
      const size_t row = (size_t)(w * 32 + i * 8 + r_in);
      gload_lds16(Ab + row * (DMODEL * 2) + k0b + cswz, (char*)As + lbase + i * 1024);
      gload_lds16(Bb + row * (DMODEL * 2) + k0b + cswz, (char*)Bs + lbase + i * 1024);
    }
    __syncthreads();

    bf16x8 a[4][2], b[4][2];
    #pragma unroll
    for (int m = 0; m < 4; ++m)
      #pragma unroll
      for (int ks = 0; ks < 2; ++ks)
        a[m][ks] = *(const bf16x8*)((const char*)As + (wr * 64 + m * 16 + fr) * 128 +
                                    ((ks * 64 + fq * 16) ^ ((fr & 7) << 4)));
    #pragma unroll
    for (int n = 0; n < 4; ++n)
      #pragma unroll
      for (int ks = 0; ks < 2; ++ks)
        b[n][ks] = *(const bf16x8*)((const char*)Bs + (wc * 64 + n * 16 + fr) * 128 +
                                    ((ks * 64 + fq * 16) ^ ((fr & 7) << 4)));
    __builtin_amdgcn_s_setprio(1);
    #pragma unroll
    for (int m = 0; m < 4; ++m)
      #pragma unroll
      for (int n = 0; n < 4; ++n)
        #pragma unroll
        for (int ks = 0; ks < 2; ++ks)
          acc[m][n] = __builtin_amdgcn_mfma_f32_16x16x32_bf16(a[m][ks], b[n][ks], acc[m][n], 0, 0, 0);
    __builtin_amdgcn_s_setprio(0);
    __syncthreads();
  }

  float bv[4];
  const int cb = nt * 128 + wc * 64;
  #pragma unroll
  for (int n = 0; n < 4; ++n) bv[n] = bp[cb + n * 16 + fr];

  if constexpr (MODE == 0) {
    float* outp = (float*)out0;
    #pragma unroll
    for (int m = 0; m < 4; ++m) {
      #pragma unroll
      for (int j = 0; j < 4; ++j) {
        const int row = mt * 128 + wr * 64 + m * 16 + fq * 4 + j;
        float* orow = outp + (size_t)row * DMODEL + cb;
        #pragma unroll
        for (int n = 0; n < 4; ++n)
          orow[n * 16 + fr] = acc[m][n][j] + bv[n];
      }
    }
  } else {
    const int h = nt * 2 + wc;
    if (z < 2) {
      #pragma unroll
      for (int m = 0; m < 4; ++m) {
        #pragma unroll
        for (int j = 0; j < 4; ++j) {
          float v0 = acc[m][0][j] + bv[0];
          float v1 = acc[m][1][j] + bv[1];
          float v2 = acc[m][2][j] + bv[2];
          float v3 = acc[m][3][j] + bv[3];
          float ss = v0 * v0 + v1 * v1 + v2 * v2 + v3 * v3;
          ss += __shfl_xor(ss, 1);
          ss += __shfl_xor(ss, 2);
          ss += __shfl_xor(ss, 4);
          ss += __shfl_xor(ss, 8);
          const float inv = 1.0f / fmaxf(sqrtf(ss), 1e-10f);
          const int row = mt * 128 + wr * 64 + m * 16 + fq * 4 + j;
          const int bb = row >> 11, sr = row & (SEQ - 1);
          bf16_t* op = ((z == 0) ? (bf16_t*)out0 : (bf16_t*)out1)
                       + (((size_t)(bb * NHEAD + h)) * SEQ + sr) * DHEAD;
          op[0 * 16 + fr] = (bf16_t)(v0 * inv);
          op[1 * 16 + fr] = (bf16_t)(v1 * inv);
          op[2 * 16 + fr] = (bf16_t)(v2 * inv);
          op[3 * 16 + fr] = (bf16_t)(v3 * inv);
        }
      }
    } else {
      // V path: normalize, stage [128 seq][128 dh] bf16 tile in LDS (As = rows 0..63,
      // Bs = rows 64..127), then write V^T with coalesced 16B stores (8 seq / store).
      bf16_t* dsth = wr ? Bs : As;
      #pragma unroll
      for (int m = 0; m < 4; ++m) {
        #pragma unroll
        for (int j = 0; j < 4; ++j) {
          float v0 = acc[m][0][j] + bv[0];
          float v1 = acc[m][1][j] + bv[1];
          float v2 = acc[m][2][j] + bv[2];
          float v3 = acc[m][3][j] + bv[3];
          float ss = v0 * v0 + v1 * v1 + v2 * v2 + v3 * v3;
          ss += __shfl_xor(ss, 1);
          ss += __shfl_xor(ss, 2);
          ss += __shfl_xor(ss, 4);
          ss += __shfl_xor(ss, 8);
          const float inv = 1.0f / fmaxf(sqrtf(ss), 1e-10f);
          const int r64 = m * 16 + fq * 4 + j;           // seq-row within half
          dsth[r64 * 128 + wc * 64 + 0 * 16 + fr] = (bf16_t)(v0 * inv);
          dsth[r64 * 128 + wc * 64 + 1 * 16 + fr] = (bf16_t)(v1 * inv);
          dsth[r64 * 128 + wc * 64 + 2 * 16 + fr] = (bf16_t)(v2 * inv);
          dsth[r64 * 128 + wc * 64 + 3 * 16 + fr] = (bf16_t)(v3 * inv);
        }
      }
      __syncthreads();
      const int bb16 = (mt >> 4) * 16;       // batch*NHEAD base
      const int srbase = (mt & 15) * 128;    // seq base of this tile
      #pragma unroll
      for (int p = 0; p < 8; ++p) {
        const int id = p * 256 + tid;        // 0..2047 chunk id
        const int c = id >> 4;               // dh-col 0..127
        const int sc = (id & 15) * 8;        // seq offset 0..120
        const bf16_t* srch = (sc < 64) ? As : Bs;
        bf16x8 vv;
        #pragma unroll
        for (int i = 0; i < 8; ++i)
          vv[i] = srch[((sc & 63) + i) * 128 + c];
        const int hh = nt * 2 + (c >> 6);
        const int dh = c & 63;
        bf16_t* gp = (bf16_t*)out2 + (((size_t)(bb16 + hh)) * 64 + dh) * (size_t)SEQ + srbase + sc;
        *(bf16x8*)gp = vv;
      }
    }
  }
}

// ---------------- MFMA spherical flash attention: 8-wave, in-block key-split ----------
// Block = 512 thr = 8 waves: qw = w&3 (4 x 32 q-rows = 128 q), kh = w>>2 (2 x 1024 keys).
// LDS 64KB: [kh][buf][ K 8KB | V 8KB ], 64-key tiles, [32 rows][256B], c ^= (row&15)<<4.
// Counted-vmcnt double-buffer pipeline (R10-verified). Swapped QK^T (S[key][q], q=lane&31),
// P via cvt_pk + permlane32_swap, PV transposed. Epilogue: LDS combine across kh, write Oat.
#define PSWAP(x, y) asm("v_permlane32_swap_b32 %0, %1" : "+v"(x), "+v"(y))
#define CVTPK(d, a, b) asm("v_cvt_pk_bf16_f32 %0, %1, %2" : "=v"(d) : "v"(a), "v"(b))
#define WAITVM(n) asm volatile("s_waitcnt vmcnt(" #n ")" ::: "memory")
#define V2(x) ((f32x2){(x), (x)})

// score transform w = exp(asin(c)/8) (scale-invariant, pure FMA) on packed f32x2,
// then pack to the PV B-fragment pair via cvt_pk + permlane32_swap.
__device__ inline void score_pack(const f32x16& accp, float& l_acc, bf16x8& pf0, bf16x8& pf1) {
  f32x2 p2[8];
  #pragma unroll
  for (int i = 0; i < 8; ++i) {
    f32x2 cv; cv[0] = accp[2 * i]; cv[1] = accp[2 * i + 1];
    const f32x2 c2 = cv * cv;
    f32x2 a = __builtin_elementwise_fma(c2, V2(0.00379774f), V2(0.00558036f));
    a = __builtin_elementwise_fma(c2, a, V2(0.00937500f));
    a = __builtin_elementwise_fma(c2, a, V2(0.02083333f));
    a = __builtin_elementwise_fma(c2, a, V2(0.12500000f));
    const f32x2 s = a * cv;                       // asin(c)/8
    f32x2 e = __builtin_elementwise_fma(s, V2(0.16666667f), V2(0.5f));
    e = __builtin_elementwise_fma(s, e, V2(1.0f));
    e = __builtin_elementwise_fma(s, e, V2(1.0f)); // exp(s), deg-3
    p2[i] = e;
  }
  const f32x2 t01 = p2[0] + p2[1], t23 = p2[2] + p2[3];
  const f32x2 t45 = p2[4] + p2[5], t67 = p2[6] + p2[7];
  const f32x2 tt = (t01 + t23) + (t45 + t67);
  l_acc += tt[0] + tt[1];
  unsigned dwA0, dwA1, dwA2, dwA3, dwB0, dwB1, dwB2, dwB3;
  CVTPK(dwA0, p2[0][0], p2[0][1]);  CVTPK(dwB0, p2[1][0], p2[1][1]);
  CVTPK(dwA1, p2[2][0], p2[2][1]);  CVTPK(dwB1, p2[3][0], p2[3][1]);
  CVTPK(dwA2, p2[4][0], p2[4][1]);  CVTPK(dwB2, p2[5][0], p2[5][1]);
  CVTPK(dwA3, p2[6][0], p2[6][1]);  CVTPK(dwB3, p2[7][0], p2[7][1]);
  PSWAP(dwA0, dwA1);  PSWAP(dwB0, dwB1);
  PSWAP(dwA2, dwA3);  PSWAP(dwB2, dwB3);
  typedef unsigned u32x4_ __attribute__((ext_vector_type(4)));
  u32x4_ t0_ = { dwA0, dwB0, dwA1, dwB1 };
  u32x4_ t1_ = { dwA2, dwB2, dwA3, dwB3 };
  pf0 = __builtin_bit_cast(bf16x8, t0_);
  pf1 = __builtin_bit_cast(bf16x8, t1_);
}

__global__ __launch_bounds__(512, 2) void mfma_attn_kernel(
    const bf16_t* __restrict__ Qb, const bf16_t* __restrict__ Kb,
    const bf16_t* __restrict__ Vt, bf16_t* __restrict__ Oat)
{
  __shared__ char smem[65536];   // [kh][buf][ K 8KB | V 8KB ]

  const int tid = threadIdx.x;
  const int lane = tid & 63;
  const int w = tid >> 6;
  const int qw = w & 3, kh = w >> 2;
  const int l31 = lane & 31, l5 = lane >> 5;

  // grid 512; XCD-aware: xcd gets heads 4*xcd..4*xcd+3 (L2 set ~2MB/XCD)
  const int p = blockIdx.x;
  const int xcd = p & 7;
  const int j = p >> 3;                 // 0..63
  const int bh = xcd * 4 + (j >> 4);
  const int qt = j & 15;
  const int q0 = qt * 128 + qw * 32;
  const int NT = 16;                    // 64-key tiles per key-half

  // persistent Q B-fragments: lane holds Q[q=q0+l31][seg*16 + l5*8 .. +7]
  const bf16_t* Qp = Qb + ((size_t)bh * SEQ + q0 + l31) * DHEAD + l5 * 8;
  bf16x8 b_q[4];
  #pragma unroll
  for (int m = 0; m < 4; ++m)
    b_q[m] = *(const bf16x8*)(Qp + m * 16);

  const char* KbaseH = (const char*)(Kb + (size_t)bh * SEQ * DHEAD) + (size_t)kh * 1024 * DHEAD * 2;
  const char* VbaseH = (const char*)(Vt + (size_t)bh * DHEAD * SEQ) + (size_t)kh * 1024 * 2;

  // staging: 8 chunks of 1KB per K (resp. V) tile; q-wave qw owns chunks 2qw, 2qw+1
  const int chA = 2 * qw, chB = 2 * qw + 1;
  int koffA, koffB, voffA, voffB;
  {
    const int rA = chA * 4 + (lane >> 4), rB = chB * 4 + (lane >> 4);
    const int c = (lane & 15) * 16;
    const int cpA = c ^ ((rA & 15) << 4), cpB = c ^ ((rB & 15) << 4);
    koffA = (rA + ((cpA >> 7) << 5)) * 128 + (cpA & 127);
    koffB = (rB + ((cpB >> 7) << 5)) * 128 + (cpB & 127);
    voffA = (rA + ((cpA >> 7) << 5)) * (SEQ * 2) + (cpA & 127);
    voffB = (rB + ((cpB >> 7) << 5)) * (SEQ * 2) + (cpB & 127);
  }
  const unsigned stKA = (unsigned)__builtin_amdgcn_readfirstlane(kh * 32768 + chA * 1024);
  const unsigned stKB = (unsigned)__builtin_amdgcn_readfirstlane(kh * 32768 + chB * 1024);
  const unsigned rb0  = (unsigned)__builtin_amdgcn_readfirstlane(kh * 32768);

  const int swz = (l31 & 15) << 4;
  const unsigned kRow = l31 * 256;

  f32x16 acc_o0 = {}, acc_o1 = {};
  float l_acc = 0.0f;

  #define STAGE(t, buf)                                                                    \
    do {                                                                                   \
      const char* Kt_ = KbaseH + (size_t)(t) * 8192;                                       \
      const char* Vc_ = VbaseH + (size_t)(t) * 128;                                        \
      gload_lds16(Kt_ + koffA, smem + stKA + (buf) * 16384);                               \
      gload_lds16(Kt_ + koffB, smem + stKB + (buf) * 16384);                               \
      gload_lds16(Vc_ + voffA, smem + stKA + (buf) * 16384 + 8192);                        \
      gload_lds16(Vc_ + voffB, smem + stKB + (buf) * 16384 + 8192);                        \
    } while (0)

  #define CHUNK(buf, c0)                                                                   \
    do {                                                                                   \
      const char* kb_ = smem + rb0 + (buf) * 16384 + kRow;                                 \
      bf16x8 ak0 = *(const bf16x8*)(kb_ + (((c0) * 128 +  0 + l5 * 16) ^ swz));            \
      bf16x8 ak1 = *(const bf16x8*)(kb_ + (((c0) * 128 + 32 + l5 * 16) ^ swz));            \
      bf16x8 ak2 = *(const bf16x8*)(kb_ + (((c0) * 128 + 64 + l5 * 16) ^ swz));            \
      bf16x8 ak3 = *(const bf16x8*)(kb_ + (((c0) * 128 + 96 + l5 * 16) ^ swz));            \
      f32x16 accp = {};                                                                    \
      __builtin_amdgcn_s_setprio(1);                                                       \
      accp = __builtin_amdgcn_mfma_f32_32x32x16_bf16(ak0, b_q[0], accp, 0, 0, 0);          \
      accp = __builtin_amdgcn_mfma_f32_32x32x16_bf16(ak1, b_q[1], accp, 0, 0, 0);          \
      accp = __builtin_amdgcn_mfma_f32_32x32x16_bf16(ak2, b_q[2], accp, 0, 0, 0);          \
      accp = __builtin_amdgcn_mfma_f32_32x32x16_bf16(ak3, b_q[3], accp, 0, 0, 0);          \
      __builtin_amdgcn_s_setprio(0);                                                       \
      const char* vb_ = smem + rb0 + (buf) * 16384 + 8192 + kRow;                          \
      bf16x8 av00 = *(const bf16x8*)(vb_ + ((      (c0) * 64 +  0 + l5 * 16) ^ swz));      \
      bf16x8 av01 = *(const bf16x8*)(vb_ + ((      (c0) * 64 + 32 + l5 * 16) ^ swz));      \
      bf16x8 av10 = *(const bf16x8*)(vb_ + ((128 + (c0) * 64 +  0 + l5 * 16) ^ swz));      \
      bf16x8 av11 = *(const bf16x8*)(vb_ + ((128 + (c0) * 64 + 32 + l5 * 16) ^ swz));      \
      bf16x8 pf0, pf1;                                                                     \
      score_pack(accp, l_acc, pf0, pf1);                                                   \
      __builtin_amdgcn_s_setprio(1);                                                       \
      acc_o0 = __builtin_amdgcn_mfma_f32_32x32x16_bf16(av00, pf0, acc_o0, 0, 0, 0);        \
      acc_o0 = __builtin_amdgcn_mfma_f32_32x32x16_bf16(av01, pf1, acc_o0, 0, 0, 0);        \
      acc_o1 = __builtin_amdgcn_mfma_f32_32x32x16_bf16(av10, pf0, acc_o1, 0, 0, 0);        \
      acc_o1 = __builtin_amdgcn_mfma_f32_32x32x16_bf16(av11, pf1, acc_o1, 0, 0, 0);        \
      __builtin_amdgcn_s_setprio(0);                                                       \
    } while (0)

  #define TILE(buf) do { CHUNK(buf, 0); CHUNK(buf, 1); } while (0)

  // counted-vmcnt double-buffer pipeline: tiles t and t+1 always in flight.
  STAGE(0, 0);
  STAGE(1, 1);

  for (int t2 = 0; t2 < NT / 2 - 1; ++t2) {
    WAITVM(4);                          // tile 2*t2 landed (own 4 loads)
    __builtin_amdgcn_s_barrier();       // all waves' loads landed
    TILE(0);
    __builtin_amdgcn_s_barrier();       // all waves done reading buf 0
    STAGE(2 * t2 + 2, 0);
    WAITVM(4);                          // tile 2*t2+1 landed
    __builtin_amdgcn_s_barrier();
    TILE(1);
    __builtin_amdgcn_s_barrier();
    STAGE(2 * t2 + 3, 1);
  }
  // tail: tiles NT-2, NT-1 (no further prefetch)
  WAITVM(4);
  __builtin_amdgcn_s_barrier();
  TILE(0);
  WAITVM(0);
  __builtin_amdgcn_s_barrier();
  TILE(1);
  #undef TILE
  #undef CHUNK
  #undef STAGE

  // ---- epilogue: finish l within wave, combine key halves via LDS, write Oat ----
  l_acc += __shfl_xor(l_acc, 32);       // l for q = q0 + l31 over this key half

  __syncthreads();                      // all tile reads drained; smem reusable
  float* cO = (float*)smem;             // [qw][32][64] fp32 = 32 KB
  float* cL = (float*)(smem + 32768);   // [qw][64]
  if (kh == 1) {
    #pragma unroll
    for (int r = 0; r < 16; ++r) {
      cO[(qw * 32 + r) * 64 + lane] = acc_o0[r];
      cO[(qw * 32 + 16 + r) * 64 + lane] = acc_o1[r];
    }
    cL[qw * 64 + lane] = l_acc;
  }
  __syncthreads();
  if (kh == 0) {
    #pragma unroll
    for (int r = 0; r < 16; ++r) {
      acc_o0[r] += cO[(qw * 32 + r) * 64 + lane];
      acc_o1[r] += cO[(qw * 32 + 16 + r) * 64 + lane];
    }
    l_acc += cL[qw * 64 + lane];
    const float invl = __builtin_amdgcn_rcpf(l_acc);
    const int bb = bh >> 4, h = bh & 15;
    bf16_t* op = Oat + ((size_t)bb * SEQ + q0 + l31) * DMODEL + h * DHEAD;
    #pragma unroll
    for (int blk = 0; blk < 2; ++blk) {
      const f32x16& ao = blk ? acc_o1 : acc_o0;
      #pragma unroll
      for (int g = 0; g < 4; ++g) {
        bf16x4 ov;
        ov[0] = (bf16_t)(ao[4 * g + 0] * invl);
        ov[1] = (bf16_t)(ao[4 * g + 1] * invl);
        ov[2] = (bf16_t)(ao[4 * g + 2] * invl);
        ov[3] = (bf16_t)(ao[4 * g + 3] * invl);
        *(bf16x4*)(op + blk * 32 + 8 * g + 4 * l5) = ov;
      }
    }
  }
}

extern "C" void kernel_launch(void* const* d_in, const int* in_sizes, int n_in,
                              void* d_out, int out_size, void* d_ws, size_t ws_size,
                              hipStream_t stream)
{
  const float* H  = (const float*)d_in[0];
  const float* Wq = (const float*)d_in[1];
  const float* bq = (const float*)d_in[2];
  const float* Wk = (const float*)d_in[3];
  const float* bk = (const float*)d_in[4];
  const float* Wv = (const float*)d_in[5];
  const float* bv = (const float*)d_in[6];
  const float* Wo = (const float*)d_in[7];
  const float* bo = (const float*)d_in[8];
  float* out = (float*)d_out;

  char* ws = (char*)d_ws;
  bf16_t* Hb  = (bf16_t*)(ws);                    // 8 MB  [B*S][1024]
  bf16_t* Wqb = (bf16_t*)(ws + (8u << 20));       // 2 MB each
  bf16_t* Wkb = (bf16_t*)(ws + (10u << 20));
  bf16_t* Wvb = (bf16_t*)(ws + (12u << 20));
  bf16_t* Wob = (bf16_t*)(ws + (14u << 20));
  bf16_t* Qbf = (bf16_t*)(ws + (16u << 20));      // 8 MB  [BH][S][64]
  bf16_t* Kbf = (bf16_t*)(ws + (24u << 20));      // 8 MB  [BH][S][64]
  bf16_t* Vtb = (bf16_t*)(ws + (32u << 20));      // 8 MB  [BH][64][S]
  bf16_t* Oat = (bf16_t*)(ws + (40u << 20));      // 8 MB  [B][S][1024]

  // fp32 -> bf16 converts (single launch)
  cvt_all_kernel<<<8192, 256, 0, stream>>>(H, Wq, Wk, Wv, Wo, Hb, Wqb, Wkb, Wvb, Wob);

  // Q/K/V projections + bias + per-head normalize -> bf16 Q,K,[V^T]
  gemm_bt_kernel<1><<<dim3(8, 32, 3), 256, 0, stream>>>(
      Hb, Wqb, Wkb, Wvb, bq, bk, bv, Qbf, Kbf, Vtb);

  // MFMA spherical flash attention (8-wave, in-block key-split, counted-vmcnt pipeline)
  mfma_attn_kernel<<<512, 512, 0, stream>>>(Qbf, Kbf, Vtb, Oat);

  // output projection -> d_out fp32 [B][S][1024]
  gemm_bt_kernel<0><<<dim3(8, 32, 1), 256, 0, stream>>>(
      Oat, Wob, Wob, Wob, bo, bo, bo, out, out, out);
}

// Round 13
// 136.268 us; speedup vs baseline: 1.5057x; 1.0066x over previous
//
#include <hip/hip_runtime.h>
#include <hip/hip_bf16.h>

typedef __bf16 bf16_t;
typedef __bf16 bf16x8 __attribute__((ext_vector_type(8)));
typedef __bf16 bf16x4 __attribute__((ext_vector_type(4)));
typedef float f32x2 __attribute__((ext_vector_type(2)));
typedef float f32x4 __attribute__((ext_vector_type(4)));
typedef float f32x16 __attribute__((ext_vector_type(16)));

#define NB 2
#define SEQ 2048
#define DMODEL 1024
#define NHEAD 16
#define DHEAD 64

__device__ inline void gload_lds16(const void* g, void* lds) {
  __builtin_amdgcn_global_load_lds((const __attribute__((address_space(1))) void*)g,
                                   (__attribute__((address_space(3))) void*)lds,
                                   16, 0, 0);
}

// ---------------- fused fp32 -> bf16 convert (H + 4 weights, one launch) ----------------
__global__ __launch_bounds__(256) void cvt_all_kernel(
    const float* __restrict__ H,  const float* __restrict__ Wq, const float* __restrict__ Wk,
    const float* __restrict__ Wv, const float* __restrict__ Wo,
    bf16_t* __restrict__ Hb, bf16_t* __restrict__ Wqb, bf16_t* __restrict__ Wkb,
    bf16_t* __restrict__ Wvb, bf16_t* __restrict__ Wob)
{
  const int b = blockIdx.x;
  const float* src; bf16_t* dst; int idx;
  if (b < 4096) { src = H; dst = Hb; idx = b; }
  else {
    const int r = b - 4096; const int s = r >> 10; idx = r & 1023;
    src = (s == 0) ? Wq : (s == 1) ? Wk : (s == 2) ? Wv : Wo;
    dst = (s == 0) ? Wqb : (s == 1) ? Wkb : (s == 2) ? Wvb : Wob;
  }
  const int i = idx * 256 + threadIdx.x;
  float4 v = ((const float4*)src)[i];
  bf16x4 o;
  o[0] = (bf16_t)v.x; o[1] = (bf16_t)v.y; o[2] = (bf16_t)v.z; o[3] = (bf16_t)v.w;
  ((bf16x4*)dst)[i] = o;
}

// ---------------- bf16 TN GEMM: C[M][N] = A[M][K] * W[N][K]^T + bias ----------------
// MODE 0: plain fp32 out. MODE 1: per-head normalize; z=0/1 -> bf16 Q/K [BH][S][64];
// z=2 -> bf16 V^T [BH][64][S] via LDS-transposed coalesced epilogue (As/Bs reused).
template<int MODE>
__global__ __launch_bounds__(256) void gemm_bt_kernel(
    const bf16_t* __restrict__ A,
    const bf16_t* __restrict__ W0, const bf16_t* __restrict__ W1, const bf16_t* __restrict__ W2,
    const float* __restrict__ bias0, const float* __restrict__ bias1, const float* __restrict__ bias2,
    void* out0, void* out1, void* out2)
{
  __shared__ bf16_t As[128 * 64];   // [row][64 bf16 = 128B], XOR-swizzled
  __shared__ bf16_t Bs[128 * 64];
  const int tid = threadIdx.x;
  const int lane = tid & 63;
  const int w = tid >> 6;
  const int mt = blockIdx.y, nt = blockIdx.x, z = blockIdx.z;
  const bf16_t* Wp = (z == 0) ? W0 : ((z == 1) ? W1 : W2);
  const float* bp  = (z == 0) ? bias0 : ((z == 1) ? bias1 : bias2);

  const int wr = w >> 1, wc = w & 1;
  const int fr = lane & 15, fq = lane >> 4;

  const int r_in = lane >> 3;
  const int cswz = ((lane & 7) ^ (r_in & 7)) << 4;
  const unsigned lbase = (unsigned)__builtin_amdgcn_readfirstlane(w * 4096);

  f32x4 acc[4][4] = {};

  const char* Ab = (const char*)(A + (size_t)mt * 128 * DMODEL);
  const char* Bb = (const char*)(Wp + (size_t)nt * 128 * DMODEL);

  for (int kt = 0; kt < DMODEL / 64; ++kt) {
    const size_t k0b = (size_t)kt * 128;
    #pragma unroll
    for (int i = 0; i < 4; ++i) {
      const size_t row = (size_t)(w * 32 + i * 8 + r_in);
      gload_lds16(Ab + row * (DMODEL * 2) + k0b + cswz, (char*)As + lbase + i * 1024);
      gload_lds16(Bb + row * (DMODEL * 2) + k0b + cswz, (char*)Bs + lbase + i * 1024);
    }
    __syncthreads();

    bf16x8 a[4][2], b[4][2];
    #pragma unroll
    for (int m = 0; m < 4; ++m)
      #pragma unroll
      for (int ks = 0; ks < 2; ++ks)
        a[m][ks] = *(const bf16x8*)((const char*)As + (wr * 64 + m * 16 + fr) * 128 +
                                    ((ks * 64 + fq * 16) ^ ((fr & 7) << 4)));
    #pragma unroll
    for (int n = 0; n < 4; ++n)
      #pragma unroll
      for (int ks = 0; ks < 2; ++ks)
        b[n][ks] = *(const bf16x8*)((const char*)Bs + (wc * 64 + n * 16 + fr) * 128 +
                                    ((ks * 64 + fq * 16) ^ ((fr & 7) << 4)));
    __builtin_amdgcn_s_setprio(1);
    #pragma unroll
    for (int m = 0; m < 4; ++m)
      #pragma unroll
      for (int n = 0; n < 4; ++n)
        #pragma unroll
        for (int ks = 0; ks < 2; ++ks)
          acc[m][n] = __builtin_amdgcn_mfma_f32_16x16x32_bf16(a[m][ks], b[n][ks], acc[m][n], 0, 0, 0);
    __builtin_amdgcn_s_setprio(0);
    __syncthreads();
  }

  float bv[4];
  const int cb = nt * 128 + wc * 64;
  #pragma unroll
  for (int n = 0; n < 4; ++n) bv[n] = bp[cb + n * 16 + fr];

  if constexpr (MODE == 0) {
    float* outp = (float*)out0;
    #pragma unroll
    for (int m = 0; m < 4; ++m) {
      #pragma unroll
      for (int j = 0; j < 4; ++j) {
        const int row = mt * 128 + wr * 64 + m * 16 + fq * 4 + j;
        float* orow = outp + (size_t)row * DMODEL + cb;
        #pragma unroll
        for (int n = 0; n < 4; ++n)
          orow[n * 16 + fr] = acc[m][n][j] + bv[n];
      }
    }
  } else {
    const int h = nt * 2 + wc;
    if (z < 2) {
      #pragma unroll
      for (int m = 0; m < 4; ++m) {
        #pragma unroll
        for (int j = 0; j < 4; ++j) {
          float v0 = acc[m][0][j] + bv[0];
          float v1 = acc[m][1][j] + bv[1];
          float v2 = acc[m][2][j] + bv[2];
          float v3 = acc[m][3][j] + bv[3];
          float ss = v0 * v0 + v1 * v1 + v2 * v2 + v3 * v3;
          ss += __shfl_xor(ss, 1);
          ss += __shfl_xor(ss, 2);
          ss += __shfl_xor(ss, 4);
          ss += __shfl_xor(ss, 8);
          const float inv = 1.0f / fmaxf(sqrtf(ss), 1e-10f);
          const int row = mt * 128 + wr * 64 + m * 16 + fq * 4 + j;
          const int bb = row >> 11, sr = row & (SEQ - 1);
          bf16_t* op = ((z == 0) ? (bf16_t*)out0 : (bf16_t*)out1)
                       + (((size_t)(bb * NHEAD + h)) * SEQ + sr) * DHEAD;
          op[0 * 16 + fr] = (bf16_t)(v0 * inv);
          op[1 * 16 + fr] = (bf16_t)(v1 * inv);
          op[2 * 16 + fr] = (bf16_t)(v2 * inv);
          op[3 * 16 + fr] = (bf16_t)(v3 * inv);
        }
      }
    } else {
      // V path: normalize, stage [128 seq][128 dh] bf16 tile in LDS (As = rows 0..63,
      // Bs = rows 64..127), then write V^T with coalesced 16B stores (8 seq / store).
      bf16_t* dsth = wr ? Bs : As;
      #pragma unroll
      for (int m = 0; m < 4; ++m) {
        #pragma unroll
        for (int j = 0; j < 4; ++j) {
          float v0 = acc[m][0][j] + bv[0];
          float v1 = acc[m][1][j] + bv[1];
          float v2 = acc[m][2][j] + bv[2];
          float v3 = acc[m][3][j] + bv[3];
          float ss = v0 * v0 + v1 * v1 + v2 * v2 + v3 * v3;
          ss += __shfl_xor(ss, 1);
          ss += __shfl_xor(ss, 2);
          ss += __shfl_xor(ss, 4);
          ss += __shfl_xor(ss, 8);
          const float inv = 1.0f / fmaxf(sqrtf(ss), 1e-10f);
          const int r64 = m * 16 + fq * 4 + j;           // seq-row within half
          dsth[r64 * 128 + wc * 64 + 0 * 16 + fr] = (bf16_t)(v0 * inv);
          dsth[r64 * 128 + wc * 64 + 1 * 16 + fr] = (bf16_t)(v1 * inv);
          dsth[r64 * 128 + wc * 64 + 2 * 16 + fr] = (bf16_t)(v2 * inv);
          dsth[r64 * 128 + wc * 64 + 3 * 16 + fr] = (bf16_t)(v3 * inv);
        }
      }
      __syncthreads();
      const int bb16 = (mt >> 4) * 16;       // batch*NHEAD base
      const int srbase = (mt & 15) * 128;    // seq base of this tile
      #pragma unroll
      for (int p = 0; p < 8; ++p) {
        const int id = p * 256 + tid;        // 0..2047 chunk id
        const int c = id >> 4;               // dh-col 0..127
        const int sc = (id & 15) * 8;        // seq offset 0..120
        const bf16_t* srch = (sc < 64) ? As : Bs;
        bf16x8 vv;
        #pragma unroll
        for (int i = 0; i < 8; ++i)
          vv[i] = srch[((sc & 63) + i) * 128 + c];
        const int hh = nt * 2 + (c >> 6);
        const int dh = c & 63;
        bf16_t* gp = (bf16_t*)out2 + (((size_t)(bb16 + hh)) * 64 + dh) * (size_t)SEQ + srbase + sc;
        *(bf16x8*)gp = vv;
      }
    }
  }
}

// ---------------- MFMA spherical flash attention: 8-wave, in-block key-split ----------
// Block = 512 thr = 8 waves: qw = w&3 (4 x 32 q-rows = 128 q), kh = w>>2 (2 x 1024 keys).
// LDS 64KB: [kh][buf][ K 8KB | V 8KB ], 64-key tiles, [32 rows][256B], c ^= (row&15)<<4.
// Counted-vmcnt double-buffer pipeline. Swapped QK^T (S[key][q], q=lane&31), P via
// cvt_pk + permlane32_swap, PV transposed. R13: no setprio in loop; both chunks' QK
// interleaved (accp0/accp1) so MFMA latency is hidden by independent chains, and each
// score phase overlaps the other chunk's MFMAs.
#define PSWAP(x, y) asm("v_permlane32_swap_b32 %0, %1" : "+v"(x), "+v"(y))
#define CVTPK(d, a, b) asm("v_cvt_pk_bf16_f32 %0, %1, %2" : "=v"(d) : "v"(a), "v"(b))
#define WAITVM(n) asm volatile("s_waitcnt vmcnt(" #n ")" ::: "memory")
#define V2(x) ((f32x2){(x), (x)})

// score transform w = exp(asin(c)/8) (scale-invariant, pure FMA) on packed f32x2,
// then pack to the PV B-fragment pair via cvt_pk + permlane32_swap.
__device__ inline void score_pack(const f32x16& accp, float& l_acc, bf16x8& pf0, bf16x8& pf1) {
  f32x2 p2[8];
  #pragma unroll
  for (int i = 0; i < 8; ++i) {
    f32x2 cv; cv[0] = accp[2 * i]; cv[1] = accp[2 * i + 1];
    const f32x2 c2 = cv * cv;
    f32x2 a = __builtin_elementwise_fma(c2, V2(0.00379774f), V2(0.00558036f));
    a = __builtin_elementwise_fma(c2, a, V2(0.00937500f));
    a = __builtin_elementwise_fma(c2, a, V2(0.02083333f));
    a = __builtin_elementwise_fma(c2, a, V2(0.12500000f));
    const f32x2 s = a * cv;                       // asin(c)/8
    f32x2 e = __builtin_elementwise_fma(s, V2(0.16666667f), V2(0.5f));
    e = __builtin_elementwise_fma(s, e, V2(1.0f));
    e = __builtin_elementwise_fma(s, e, V2(1.0f)); // exp(s), deg-3
    p2[i] = e;
  }
  const f32x2 t01 = p2[0] + p2[1], t23 = p2[2] + p2[3];
  const f32x2 t45 = p2[4] + p2[5], t67 = p2[6] + p2[7];
  const f32x2 tt = (t01 + t23) + (t45 + t67);
  l_acc += tt[0] + tt[1];
  unsigned dwA0, dwA1, dwA2, dwA3, dwB0, dwB1, dwB2, dwB3;
  CVTPK(dwA0, p2[0][0], p2[0][1]);  CVTPK(dwB0, p2[1][0], p2[1][1]);
  CVTPK(dwA1, p2[2][0], p2[2][1]);  CVTPK(dwB1, p2[3][0], p2[3][1]);
  CVTPK(dwA2, p2[4][0], p2[4][1]);  CVTPK(dwB2, p2[5][0], p2[5][1]);
  CVTPK(dwA3, p2[6][0], p2[6][1]);  CVTPK(dwB3, p2[7][0], p2[7][1]);
  PSWAP(dwA0, dwA1);  PSWAP(dwB0, dwB1);
  PSWAP(dwA2, dwA3);  PSWAP(dwB2, dwB3);
  typedef unsigned u32x4_ __attribute__((ext_vector_type(4)));
  u32x4_ t0_ = { dwA0, dwB0, dwA1, dwB1 };
  u32x4_ t1_ = { dwA2, dwB2, dwA3, dwB3 };
  pf0 = __builtin_bit_cast(bf16x8, t0_);
  pf1 = __builtin_bit_cast(bf16x8, t1_);
}

__global__ __launch_bounds__(512, 2) void mfma_attn_kernel(
    const bf16_t* __restrict__ Qb, const bf16_t* __restrict__ Kb,
    const bf16_t* __restrict__ Vt, bf16_t* __restrict__ Oat)
{
  __shared__ char smem[65536];   // [kh][buf][ K 8KB | V 8KB ]

  const int tid = threadIdx.x;
  const int lane = tid & 63;
  const int w = tid >> 6;
  const int qw = w & 3, kh = w >> 2;
  const int l31 = lane & 31, l5 = lane >> 5;

  // grid 512; XCD-aware: xcd gets heads 4*xcd..4*xcd+3 (L2 set ~2MB/XCD)
  const int p = blockIdx.x;
  const int xcd = p & 7;
  const int j = p >> 3;                 // 0..63
  const int bh = xcd * 4 + (j >> 4);
  const int qt = j & 15;
  const int q0 = qt * 128 + qw * 32;
  const int NT = 16;                    // 64-key tiles per key-half

  // persistent Q B-fragments: lane holds Q[q=q0+l31][seg*16 + l5*8 .. +7]
  const bf16_t* Qp = Qb + ((size_t)bh * SEQ + q0 + l31) * DHEAD + l5 * 8;
  bf16x8 b_q[4];
  #pragma unroll
  for (int m = 0; m < 4; ++m)
    b_q[m] = *(const bf16x8*)(Qp + m * 16);

  const char* KbaseH = (const char*)(Kb + (size_t)bh * SEQ * DHEAD) + (size_t)kh * 1024 * DHEAD * 2;
  const char* VbaseH = (const char*)(Vt + (size_t)bh * DHEAD * SEQ) + (size_t)kh * 1024 * 2;

  // staging: 8 chunks of 1KB per K (resp. V) tile; q-wave qw owns chunks 2qw, 2qw+1
  const int chA = 2 * qw, chB = 2 * qw + 1;
  int koffA, koffB, voffA, voffB;
  {
    const int rA = chA * 4 + (lane >> 4), rB = chB * 4 + (lane >> 4);
    const int c = (lane & 15) * 16;
    const int cpA = c ^ ((rA & 15) << 4), cpB = c ^ ((rB & 15) << 4);
    koffA = (rA + ((cpA >> 7) << 5)) * 128 + (cpA & 127);
    koffB = (rB + ((cpB >> 7) << 5)) * 128 + (cpB & 127);
    voffA = (rA + ((cpA >> 7) << 5)) * (SEQ * 2) + (cpA & 127);
    voffB = (rB + ((cpB >> 7) << 5)) * (SEQ * 2) + (cpB & 127);
  }
  const unsigned stKA = (unsigned)__builtin_amdgcn_readfirstlane(kh * 32768 + chA * 1024);
  const unsigned stKB = (unsigned)__builtin_amdgcn_readfirstlane(kh * 32768 + chB * 1024);
  const unsigned rb0  = (unsigned)__builtin_amdgcn_readfirstlane(kh * 32768);

  const int swz = (l31 & 15) << 4;
  const unsigned kRow = l31 * 256;

  f32x16 acc_o0 = {}, acc_o1 = {};
  float l_acc = 0.0f;

  #define STAGE(t, buf)                                                                    \
    do {                                                                                   \
      const char* Kt_ = KbaseH + (size_t)(t) * 8192;                                       \
      const char* Vc_ = VbaseH + (size_t)(t) * 128;                                        \
      gload_lds16(Kt_ + koffA, smem + stKA + (buf) * 16384);                               \
      gload_lds16(Kt_ + koffB, smem + stKB + (buf) * 16384);                               \
      gload_lds16(Vc_ + voffA, smem + stKA + (buf) * 16384 + 8192);                        \
      gload_lds16(Vc_ + voffB, smem + stKB + (buf) * 16384 + 8192);                        \
    } while (0)

  // one 64-key tile: QK of both 32-key chunks interleaved (independent accp0/accp1
  // chains), then per-chunk score+PV with PV alternating acc_o0/acc_o1 (depth-2).
  #define TILE(buf)                                                                        \
    do {                                                                                   \
      const char* kb_ = smem + rb0 + (buf) * 16384 + kRow;                                 \
      const char* vb_ = smem + rb0 + (buf) * 16384 + 8192 + kRow;                          \
      f32x16 accp0 = {}, accp1 = {};                                                       \
      _Pragma("unroll")                                                                    \
      for (int m = 0; m < 4; ++m) {                                                        \
        bf16x8 akA = *(const bf16x8*)(kb_ + ((m * 32 + l5 * 16) ^ swz));                   \
        bf16x8 akB = *(const bf16x8*)(kb_ + ((128 + m * 32 + l5 * 16) ^ swz));             \
        accp0 = __builtin_amdgcn_mfma_f32_32x32x16_bf16(akA, b_q[m], accp0, 0, 0, 0);      \
        accp1 = __builtin_amdgcn_mfma_f32_32x32x16_bf16(akB, b_q[m], accp1, 0, 0, 0);      \
      }                                                                                    \
      {                                                                                    \
        bf16x8 pf0, pf1;                                                                   \
        score_pack(accp0, l_acc, pf0, pf1);                                                \
        bf16x8 av00 = *(const bf16x8*)(vb_ + ((  0 + l5 * 16) ^ swz));                     \
        bf16x8 av01 = *(const bf16x8*)(vb_ + (( 32 + l5 * 16) ^ swz));                     \
        bf16x8 av10 = *(const bf16x8*)(vb_ + ((128 +  0 + l5 * 16) ^ swz));                \
        bf16x8 av11 = *(const bf16x8*)(vb_ + ((128 + 32 + l5 * 16) ^ swz));                \
        acc_o0 = __builtin_amdgcn_mfma_f32_32x32x16_bf16(av00, pf0, acc_o0, 0, 0, 0);      \
        acc_o1 = __builtin_amdgcn_mfma_f32_32x32x16_bf16(av10, pf0, acc_o1, 0, 0, 0);      \
        acc_o0 = __builtin_amdgcn_mfma_f32_32x32x16_bf16(av01, pf1, acc_o0, 0, 0, 0);      \
        acc_o1 = __builtin_amdgcn_mfma_f32_32x32x16_bf16(av11, pf1, acc_o1, 0, 0, 0);      \
      }                                                                                    \
      {                                                                                    \
        bf16x8 pf0, pf1;                                                                   \
        score_pack(accp1, l_acc, pf0, pf1);                                                \
        bf16x8 av00 = *(const bf16x8*)(vb_ + (( 64 +  0 + l5 * 16) ^ swz));                \
        bf16x8 av01 = *(const bf16x8*)(vb_ + (( 64 + 32 + l5 * 16) ^ swz));                \
        bf16x8 av10 = *(const bf16x8*)(vb_ + ((128 + 64 +  0 + l5 * 16) ^ swz));           \
        bf16x8 av11 = *(const bf16x8*)(vb_ + ((128 + 64 + 32 + l5 * 16) ^ swz));           \
        acc_o0 = __builtin_amdgcn_mfma_f32_32x32x16_bf16(av00, pf0, acc_o0, 0, 0, 0);      \
        acc_o1 = __builtin_amdgcn_mfma_f32_32x32x16_bf16(av10, pf0, acc_o1, 0, 0, 0);      \
        acc_o0 = __builtin_amdgcn_mfma_f32_32x32x16_bf16(av01, pf1, acc_o0, 0, 0, 0);      \
        acc_o1 = __builtin_amdgcn_mfma_f32_32x32x16_bf16(av11, pf1, acc_o1, 0, 0, 0);      \
      }                                                                                    \
    } while (0)

  // counted-vmcnt double-buffer pipeline: tiles t and t+1 always in flight.
  STAGE(0, 0);
  STAGE(1, 1);

  for (int t2 = 0; t2 < NT / 2 - 1; ++t2) {
    WAITVM(4);                          // tile 2*t2 landed (own 4 loads)
    __builtin_amdgcn_s_barrier();       // all waves' loads landed
    TILE(0);
    __builtin_amdgcn_s_barrier();       // all waves done reading buf 0
    STAGE(2 * t2 + 2, 0);
    WAITVM(4);                          // tile 2*t2+1 landed
    __builtin_amdgcn_s_barrier();
    TILE(1);
    __builtin_amdgcn_s_barrier();
    STAGE(2 * t2 + 3, 1);
  }
  // tail: tiles NT-2, NT-1 (no further prefetch)
  WAITVM(4);
  __builtin_amdgcn_s_barrier();
  TILE(0);
  WAITVM(0);
  __builtin_amdgcn_s_barrier();
  TILE(1);
  #undef TILE
  #undef STAGE

  // ---- epilogue: finish l within wave, combine key halves via LDS, write Oat ----
  l_acc += __shfl_xor(l_acc, 32);       // l for q = q0 + l31 over this key half

  __syncthreads();                      // all tile reads drained; smem reusable
  float* cO = (float*)smem;             // [qw][32][64] fp32 = 32 KB
  float* cL = (float*)(smem + 32768);   // [qw][64]
  if (kh == 1) {
    #pragma unroll
    for (int r = 0; r < 16; ++r) {
      cO[(qw * 32 + r) * 64 + lane] = acc_o0[r];
      cO[(qw * 32 + 16 + r) * 64 + lane] = acc_o1[r];
    }
    cL[qw * 64 + lane] = l_acc;
  }
  __syncthreads();
  if (kh == 0) {
    #pragma unroll
    for (int r = 0; r < 16; ++r) {
      acc_o0[r] += cO[(qw * 32 + r) * 64 + lane];
      acc_o1[r] += cO[(qw * 32 + 16 + r) * 64 + lane];
    }
    l_acc += cL[qw * 64 + lane];
    const float invl = __builtin_amdgcn_rcpf(l_acc);
    const int bb = bh >> 4, h = bh & 15;
    bf16_t* op = Oat + ((size_t)bb * SEQ + q0 + l31) * DMODEL + h * DHEAD;
    #pragma unroll
    for (int blk = 0; blk < 2; ++blk) {
      const f32x16& ao = blk ? acc_o1 : acc_o0;
      #pragma unroll
      for (int g = 0; g < 4; ++g) {
        bf16x4 ov;
        ov[0] = (bf16_t)(ao[4 * g + 0] * invl);
        ov[1] = (bf16_t)(ao[4 * g + 1] * invl);
        ov[2] = (bf16_t)(ao[4 * g + 2] * invl);
        ov[3] = (bf16_t)(ao[4 * g + 3] * invl);
        *(bf16x4*)(op + blk * 32 + 8 * g + 4 * l5) = ov;
      }
    }
  }
}

extern "C" void kernel_launch(void* const* d_in, const int* in_sizes, int n_in,
                              void* d_out, int out_size, void* d_ws, size_t ws_size,
                              hipStream_t stream)
{
  const float* H  = (const float*)d_in[0];
  const float* Wq = (const float*)d_in[1];
  const float* bq = (const float*)d_in[2];
  const float* Wk = (const float*)d_in[3];
  const float* bk = (const float*)d_in[4];
  const float* Wv = (const float*)d_in[5];
  const float* bv = (const float*)d_in[6];
  const float* Wo = (const float*)d_in[7];
  const float* bo = (const float*)d_in[8];
  float* out = (float*)d_out;

  char* ws = (char*)d_ws;
  bf16_t* Hb  = (bf16_t*)(ws);                    // 8 MB  [B*S][1024]
  bf16_t* Wqb = (bf16_t*)(ws + (8u << 20));       // 2 MB each
  bf16_t* Wkb = (bf16_t*)(ws + (10u << 20));
  bf16_t* Wvb = (bf16_t*)(ws + (12u << 20));
  bf16_t* Wob = (bf16_t*)(ws + (14u << 20));
  bf16_t* Qbf = (bf16_t*)(ws + (16u << 20));      // 8 MB  [BH][S][64]
  bf16_t* Kbf = (bf16_t*)(ws + (24u << 20));      // 8 MB  [BH][S][64]
  bf16_t* Vtb = (bf16_t*)(ws + (32u << 20));      // 8 MB  [BH][64][S]
  bf16_t* Oat = (bf16_t*)(ws + (40u << 20));      // 8 MB  [B][S][1024]

  // fp32 -> bf16 converts (single launch)
  cvt_all_kernel<<<8192, 256, 0, stream>>>(H, Wq, Wk, Wv, Wo, Hb, Wqb, Wkb, Wvb, Wob);

  // Q/K/V projections + bias + per-head normalize -> bf16 Q,K,[V^T]
  gemm_bt_kernel<1><<<dim3(8, 32, 3), 256, 0, stream>>>(
      Hb, Wqb, Wkb, Wvb, bq, bk, bv, Qbf, Kbf, Vtb);

  // MFMA spherical flash attention (8-wave, in-block key-split, counted-vmcnt pipeline)
  mfma_attn_kernel<<<512, 512, 0, stream>>>(Qbf, Kbf, Vtb, Oat);

  // output projection -> d_out fp32 [B][S][1024]
  gemm_bt_kernel<0><<<dim3(8, 32, 1), 256, 0, stream>>>(
      Oat, Wob, Wob, Wob, bo, bo, bo, out, out, out);
}

// Round 14
// 136.158 us; speedup vs baseline: 1.5069x; 1.0008x over previous
//
#include <hip/hip_runtime.h>
#include <hip/hip_bf16.h>

typedef __bf16 bf16_t;
typedef __bf16 bf16x8 __attribute__((ext_vector_type(8)));
typedef __bf16 bf16x4 __attribute__((ext_vector_type(4)));
typedef float f32x2 __attribute__((ext_vector_type(2)));
typedef float f32x4 __attribute__((ext_vector_type(4)));
typedef float f32x16 __attribute__((ext_vector_type(16)));

#define NB 2
#define SEQ 2048
#define DMODEL 1024
#define NHEAD 16
#define DHEAD 64

__device__ inline void gload_lds16(const void* g, void* lds) {
  __builtin_amdgcn_global_load_lds((const __attribute__((address_space(1))) void*)g,
                                   (__attribute__((address_space(3))) void*)lds,
                                   16, 0, 0);
}

// ---------------- fused fp32 -> bf16 convert (H + 4 weights, one launch) ----------------
__global__ __launch_bounds__(256) void cvt_all_kernel(
    const float* __restrict__ H,  const float* __restrict__ Wq, const float* __restrict__ Wk,
    const float* __restrict__ Wv, const float* __restrict__ Wo,
    bf16_t* __restrict__ Hb, bf16_t* __restrict__ Wqb, bf16_t* __restrict__ Wkb,
    bf16_t* __restrict__ Wvb, bf16_t* __restrict__ Wob)
{
  const int b = blockIdx.x;
  const float* src; bf16_t* dst; int idx;
  if (b < 4096) { src = H; dst = Hb; idx = b; }
  else {
    const int r = b - 4096; const int s = r >> 10; idx = r & 1023;
    src = (s == 0) ? Wq : (s == 1) ? Wk : (s == 2) ? Wv : Wo;
    dst = (s == 0) ? Wqb : (s == 1) ? Wkb : (s == 2) ? Wvb : Wob;
  }
  const int i = idx * 256 + threadIdx.x;
  float4 v = ((const float4*)src)[i];
  bf16x4 o;
  o[0] = (bf16_t)v.x; o[1] = (bf16_t)v.y; o[2] = (bf16_t)v.z; o[3] = (bf16_t)v.w;
  ((bf16x4*)dst)[i] = o;
}

// ---------------- bf16 TN GEMM: C[M][N] = A[M][K] * W[N][K]^T + bias ----------------
// MODE 0: plain fp32 out. MODE 1: per-head normalize; z=0/1 -> bf16 Q/K [BH][S][64];
// z=2 -> bf16 V^T [BH][64][S] via LDS-transposed coalesced epilogue (As/Bs reused).
template<int MODE>
__global__ __launch_bounds__(256) void gemm_bt_kernel(
    const bf16_t* __restrict__ A,
    const bf16_t* __restrict__ W0, const bf16_t* __restrict__ W1, const bf16_t* __restrict__ W2,
    const float* __restrict__ bias0, const float* __restrict__ bias1, const float* __restrict__ bias2,
    void* out0, void* out1, void* out2)
{
  __shared__ bf16_t As[128 * 64];   // [row][64 bf16 = 128B], XOR-swizzled
  __shared__ bf16_t Bs[128 * 64];
  const int tid = threadIdx.x;
  const int lane = tid & 63;
  const int w = tid >> 6;
  const int mt = blockIdx.y, nt = blockIdx.x, z = blockIdx.z;
  const bf16_t* Wp = (z == 0) ? W0 : ((z == 1) ? W1 : W2);
  const float* bp  = (z == 0) ? bias0 : ((z == 1) ? bias1 : bias2);

  const int wr = w >> 1, wc = w & 1;
  const int fr = lane & 15, fq = lane >> 4;

  const int r_in = lane >> 3;
  const int cswz = ((lane & 7) ^ (r_in & 7)) << 4;
  const unsigned lbase = (unsigned)__builtin_amdgcn_readfirstlane(w * 4096);

  f32x4 acc[4][4] = {};

  const char* Ab = (const char*)(A + (size_t)mt * 128 * DMODEL);
  const char* Bb = (const char*)(Wp + (size_t)nt * 128 * DMODEL);

  for (int kt = 0; kt < DMODEL / 64; ++kt) {
    const size_t k0b = (size_t)kt * 128;
    #pragma unroll
    for (int i = 0; i < 4; ++i) {
      const size_t row = (size_t)(w * 32 + i * 8 + r_in);
      gload_lds16(Ab + row * (DMODEL * 2) + k0b + cswz, (char*)As + lbase + i * 1024);
      gload_lds16(Bb + row * (DMODEL * 2) + k0b + cswz, (char*)Bs + lbase + i * 1024);
    }
    __syncthreads();

    bf16x8 a[4][2], b[4][2];
    #pragma unroll
    for (int m = 0; m < 4; ++m)
      #pragma unroll
      for (int ks = 0; ks < 2; ++ks)
        a[m][ks] = *(const bf16x8*)((const char*)As + (wr * 64 + m * 16 + fr) * 128 +
                                    ((ks * 64 + fq * 16) ^ ((fr & 7) << 4)));
    #pragma unroll
    for (int n = 0; n < 4; ++n)
      #pragma unroll
      for (int ks = 0; ks < 2; ++ks)
        b[n][ks] = *(const bf16x8*)((const char*)Bs + (wc * 64 + n * 16 + fr) * 128 +
                                    ((ks * 64 + fq * 16) ^ ((fr & 7) << 4)));
    __builtin_amdgcn_s_setprio(1);
    #pragma unroll
    for (int m = 0; m < 4; ++m)
      #pragma unroll
      for (int n = 0; n < 4; ++n)
        #pragma unroll
        for (int ks = 0; ks < 2; ++ks)
          acc[m][n] = __builtin_amdgcn_mfma_f32_16x16x32_bf16(a[m][ks], b[n][ks], acc[m][n], 0, 0, 0);
    __builtin_amdgcn_s_setprio(0);
    __syncthreads();
  }

  float bv[4];
  const int cb = nt * 128 + wc * 64;
  #pragma unroll
  for (int n = 0; n < 4; ++n) bv[n] = bp[cb + n * 16 + fr];

  if constexpr (MODE == 0) {
    float* outp = (float*)out0;
    #pragma unroll
    for (int m = 0; m < 4; ++m) {
      #pragma unroll
      for (int j = 0; j < 4; ++j) {
        const int row = mt * 128 + wr * 64 + m * 16 + fq * 4 + j;
        float* orow = outp + (size_t)row * DMODEL + cb;
        #pragma unroll
        for (int n = 0; n < 4; ++n)
          orow[n * 16 + fr] = acc[m][n][j] + bv[n];
      }
    }
  } else {
    const int h = nt * 2 + wc;
    if (z < 2) {
      #pragma unroll
      for (int m = 0; m < 4; ++m) {
        #pragma unroll
        for (int j = 0; j < 4; ++j) {
          float v0 = acc[m][0][j] + bv[0];
          float v1 = acc[m][1][j] + bv[1];
          float v2 = acc[m][2][j] + bv[2];
          float v3 = acc[m][3][j] + bv[3];
          float ss = v0 * v0 + v1 * v1 + v2 * v2 + v3 * v3;
          ss += __shfl_xor(ss, 1);
          ss += __shfl_xor(ss, 2);
          ss += __shfl_xor(ss, 4);
          ss += __shfl_xor(ss, 8);
          const float inv = 1.0f / fmaxf(sqrtf(ss), 1e-10f);
          const int row = mt * 128 + wr * 64 + m * 16 + fq * 4 + j;
          const int bb = row >> 11, sr = row & (SEQ - 1);
          bf16_t* op = ((z == 0) ? (bf16_t*)out0 : (bf16_t*)out1)
                       + (((size_t)(bb * NHEAD + h)) * SEQ + sr) * DHEAD;
          op[0 * 16 + fr] = (bf16_t)(v0 * inv);
          op[1 * 16 + fr] = (bf16_t)(v1 * inv);
          op[2 * 16 + fr] = (bf16_t)(v2 * inv);
          op[3 * 16 + fr] = (bf16_t)(v3 * inv);
        }
      }
    } else {
      // V path: normalize, stage [128 seq][128 dh] bf16 tile in LDS (As = rows 0..63,
      // Bs = rows 64..127), then write V^T with coalesced 16B stores (8 seq / store).
      bf16_t* dsth = wr ? Bs : As;
      #pragma unroll
      for (int m = 0; m < 4; ++m) {
        #pragma unroll
        for (int j = 0; j < 4; ++j) {
          float v0 = acc[m][0][j] + bv[0];
          float v1 = acc[m][1][j] + bv[1];
          float v2 = acc[m][2][j] + bv[2];
          float v3 = acc[m][3][j] + bv[3];
          float ss = v0 * v0 + v1 * v1 + v2 * v2 + v3 * v3;
          ss += __shfl_xor(ss, 1);
          ss += __shfl_xor(ss, 2);
          ss += __shfl_xor(ss, 4);
          ss += __shfl_xor(ss, 8);
          const float inv = 1.0f / fmaxf(sqrtf(ss), 1e-10f);
          const int r64 = m * 16 + fq * 4 + j;           // seq-row within half
          dsth[r64 * 128 + wc * 64 + 0 * 16 + fr] = (bf16_t)(v0 * inv);
          dsth[r64 * 128 + wc * 64 + 1 * 16 + fr] = (bf16_t)(v1 * inv);
          dsth[r64 * 128 + wc * 64 + 2 * 16 + fr] = (bf16_t)(v2 * inv);
          dsth[r64 * 128 + wc * 64 + 3 * 16 + fr] = (bf16_t)(v3 * inv);
        }
      }
      __syncthreads();
      const int bb16 = (mt >> 4) * 16;       // batch*NHEAD base
      const int srbase = (mt & 15) * 128;    // seq base of this tile
      #pragma unroll
      for (int p = 0; p < 8; ++p) {
        const int id = p * 256 + tid;        // 0..2047 chunk id
        const int c = id >> 4;               // dh-col 0..127
        const int sc = (id & 15) * 8;        // seq offset 0..120
        const bf16_t* srch = (sc < 64) ? As : Bs;
        bf16x8 vv;
        #pragma unroll
        for (int i = 0; i < 8; ++i)
          vv[i] = srch[((sc & 63) + i) * 128 + c];
        const int hh = nt * 2 + (c >> 6);
        const int dh = c & 63;
        bf16_t* gp = (bf16_t*)out2 + (((size_t)(bb16 + hh)) * 64 + dh) * (size_t)SEQ + srbase + sc;
        *(bf16x8*)gp = vv;
      }
    }
  }
}

// ---------------- MFMA spherical flash attention: 8-wave, in-block key-split ----------
// Block = 512 thr = 8 waves: qw = w&3 (4 x 32 q-rows = 128 q), kh = w>>2 (2 x 1024 keys).
// LDS 64KB: [kh][buf][ K 8KB | V 8KB ], 64-key tiles, [32 rows][256B], c ^= (row&15)<<4.
// Counted-vmcnt double-buffer pipeline. Swapped QK^T (S[key][q], q=lane&31), P via
// cvt_pk + permlane32_swap, PV transposed. R14: score math fully vectorized over the
// f32x16 MFMA accumulator (no f32x2 marshalling movs).
#define PSWAP(x, y) asm("v_permlane32_swap_b32 %0, %1" : "+v"(x), "+v"(y))
#define CVTPK(d, a, b) asm("v_cvt_pk_bf16_f32 %0, %1, %2" : "=v"(d) : "v"(a), "v"(b))
#define WAITVM(n) asm volatile("s_waitcnt vmcnt(" #n ")" ::: "memory")

__device__ inline f32x16 sp16(float x) {
  f32x16 v;
  #pragma unroll
  for (int i = 0; i < 16; ++i) v[i] = x;
  return v;
}

// score transform w = exp(asin(c)/8) (scale-invariant, pure FMA) on the whole f32x16
// accumulator (operates in-place on the MFMA result registers; no pack/unpack movs),
// then pack to the PV B-fragment pair via cvt_pk + permlane32_swap.
__device__ inline void score_pack(const f32x16& accp, float& l_acc, bf16x8& pf0, bf16x8& pf1) {
  const f32x16 c2 = accp * accp;
  f32x16 a = __builtin_elementwise_fma(c2, sp16(0.00379774f), sp16(0.00558036f));
  a = __builtin_elementwise_fma(c2, a, sp16(0.00937500f));
  a = __builtin_elementwise_fma(c2, a, sp16(0.02083333f));
  a = __builtin_elementwise_fma(c2, a, sp16(0.12500000f));
  const f32x16 s = a * accp;                              // asin(c)/8
  f32x16 e = __builtin_elementwise_fma(s, sp16(0.16666667f), sp16(0.5f));
  e = __builtin_elementwise_fma(s, e, sp16(1.0f));
  e = __builtin_elementwise_fma(s, e, sp16(1.0f));        // exp(s), deg-3
  // l sum (15-op tree)
  const float t0 = (e[0] + e[1]) + (e[2] + e[3]);
  const float t1 = (e[4] + e[5]) + (e[6] + e[7]);
  const float t2 = (e[8] + e[9]) + (e[10] + e[11]);
  const float t3 = (e[12] + e[13]) + (e[14] + e[15]);
  l_acc += (t0 + t1) + (t2 + t3);
  unsigned dwA0, dwA1, dwA2, dwA3, dwB0, dwB1, dwB2, dwB3;
  CVTPK(dwA0, e[0], e[1]);   CVTPK(dwB0, e[2], e[3]);
  CVTPK(dwA1, e[4], e[5]);   CVTPK(dwB1, e[6], e[7]);
  CVTPK(dwA2, e[8], e[9]);   CVTPK(dwB2, e[10], e[11]);
  CVTPK(dwA3, e[12], e[13]); CVTPK(dwB3, e[14], e[15]);
  PSWAP(dwA0, dwA1);  PSWAP(dwB0, dwB1);
  PSWAP(dwA2, dwA3);  PSWAP(dwB2, dwB3);
  typedef unsigned u32x4_ __attribute__((ext_vector_type(4)));
  u32x4_ t0_ = { dwA0, dwB0, dwA1, dwB1 };
  u32x4_ t1_ = { dwA2, dwB2, dwA3, dwB3 };
  pf0 = __builtin_bit_cast(bf16x8, t0_);
  pf1 = __builtin_bit_cast(bf16x8, t1_);
}

__global__ __launch_bounds__(512, 2) void mfma_attn_kernel(
    const bf16_t* __restrict__ Qb, const bf16_t* __restrict__ Kb,
    const bf16_t* __restrict__ Vt, bf16_t* __restrict__ Oat)
{
  __shared__ char smem[65536];   // [kh][buf][ K 8KB | V 8KB ]

  const int tid = threadIdx.x;
  const int lane = tid & 63;
  const int w = tid >> 6;
  const int qw = w & 3, kh = w >> 2;
  const int l31 = lane & 31, l5 = lane >> 5;

  // grid 512; XCD-aware: xcd gets heads 4*xcd..4*xcd+3 (L2 set ~2MB/XCD)
  const int p = blockIdx.x;
  const int xcd = p & 7;
  const int j = p >> 3;                 // 0..63
  const int bh = xcd * 4 + (j >> 4);
  const int qt = j & 15;
  const int q0 = qt * 128 + qw * 32;
  const int NT = 16;                    // 64-key tiles per key-half

  // persistent Q B-fragments: lane holds Q[q=q0+l31][seg*16 + l5*8 .. +7]
  const bf16_t* Qp = Qb + ((size_t)bh * SEQ + q0 + l31) * DHEAD + l5 * 8;
  bf16x8 b_q[4];
  #pragma unroll
  for (int m = 0; m < 4; ++m)
    b_q[m] = *(const bf16x8*)(Qp + m * 16);

  const char* KbaseH = (const char*)(Kb + (size_t)bh * SEQ * DHEAD) + (size_t)kh * 1024 * DHEAD * 2;
  const char* VbaseH = (const char*)(Vt + (size_t)bh * DHEAD * SEQ) + (size_t)kh * 1024 * 2;

  // staging: 8 chunks of 1KB per K (resp. V) tile; q-wave qw owns chunks 2qw, 2qw+1
  const int chA = 2 * qw, chB = 2 * qw + 1;
  int koffA, koffB, voffA, voffB;
  {
    const int rA = chA * 4 + (lane >> 4), rB = chB * 4 + (lane >> 4);
    const int c = (lane & 15) * 16;
    const int cpA = c ^ ((rA & 15) << 4), cpB = c ^ ((rB & 15) << 4);
    koffA = (rA + ((cpA >> 7) << 5)) * 128 + (cpA & 127);
    koffB = (rB + ((cpB >> 7) << 5)) * 128 + (cpB & 127);
    voffA = (rA + ((cpA >> 7) << 5)) * (SEQ * 2) + (cpA & 127);
    voffB = (rB + ((cpB >> 7) << 5)) * (SEQ * 2) + (cpB & 127);
  }
  const unsigned stKA = (unsigned)__builtin_amdgcn_readfirstlane(kh * 32768 + chA * 1024);
  const unsigned stKB = (unsigned)__builtin_amdgcn_readfirstlane(kh * 32768 + chB * 1024);
  const unsigned rb0  = (unsigned)__builtin_amdgcn_readfirstlane(kh * 32768);

  const int swz = (l31 & 15) << 4;
  const unsigned kRow = l31 * 256;

  f32x16 acc_o0 = {}, acc_o1 = {};
  float l_acc = 0.0f;

  #define STAGE(t, buf)                                                                    \
    do {                                                                                   \
      const char* Kt_ = KbaseH + (size_t)(t) * 8192;                                       \
      const char* Vc_ = VbaseH + (size_t)(t) * 128;                                        \
      gload_lds16(Kt_ + koffA, smem + stKA + (buf) * 16384);                               \
      gload_lds16(Kt_ + koffB, smem + stKB + (buf) * 16384);                               \
      gload_lds16(Vc_ + voffA, smem + stKA + (buf) * 16384 + 8192);                        \
      gload_lds16(Vc_ + voffB, smem + stKB + (buf) * 16384 + 8192);                        \
    } while (0)

  // one 64-key tile: QK of both 32-key chunks interleaved (independent accp0/accp1
  // chains), then per-chunk score+PV with PV alternating acc_o0/acc_o1 (depth-2).
  #define TILE(buf)                                                                        \
    do {                                                                                   \
      const char* kb_ = smem + rb0 + (buf) * 16384 + kRow;                                 \
      const char* vb_ = smem + rb0 + (buf) * 16384 + 8192 + kRow;                          \
      f32x16 accp0 = {}, accp1 = {};                                                       \
      _Pragma("unroll")                                                                    \
      for (int m = 0; m < 4; ++m) {                                                        \
        bf16x8 akA = *(const bf16x8*)(kb_ + ((m * 32 + l5 * 16) ^ swz));                   \
        bf16x8 akB = *(const bf16x8*)(kb_ + ((128 + m * 32 + l5 * 16) ^ swz));             \
        accp0 = __builtin_amdgcn_mfma_f32_32x32x16_bf16(akA, b_q[m], accp0, 0, 0, 0);      \
        accp1 = __builtin_amdgcn_mfma_f32_32x32x16_bf16(akB, b_q[m], accp1, 0, 0, 0);      \
      }                                                                                    \
      {                                                                                    \
        bf16x8 pf0, pf1;                                                                   \
        score_pack(accp0, l_acc, pf0, pf1);                                                \
        bf16x8 av00 = *(const bf16x8*)(vb_ + ((  0 + l5 * 16) ^ swz));                     \
        bf16x8 av01 = *(const bf16x8*)(vb_ + (( 32 + l5 * 16) ^ swz));                     \
        bf16x8 av10 = *(const bf16x8*)(vb_ + ((128 +  0 + l5 * 16) ^ swz));                \
        bf16x8 av11 = *(const bf16x8*)(vb_ + ((128 + 32 + l5 * 16) ^ swz));                \
        acc_o0 = __builtin_amdgcn_mfma_f32_32x32x16_bf16(av00, pf0, acc_o0, 0, 0, 0);      \
        acc_o1 = __builtin_amdgcn_mfma_f32_32x32x16_bf16(av10, pf0, acc_o1, 0, 0, 0);      \
        acc_o0 = __builtin_amdgcn_mfma_f32_32x32x16_bf16(av01, pf1, acc_o0, 0, 0, 0);      \
        acc_o1 = __builtin_amdgcn_mfma_f32_32x32x16_bf16(av11, pf1, acc_o1, 0, 0, 0);      \
      }                                                                                    \
      {                                                                                    \
        bf16x8 pf0, pf1;                                                                   \
        score_pack(accp1, l_acc, pf0, pf1);                                                \
        bf16x8 av00 = *(const bf16x8*)(vb_ + (( 64 +  0 + l5 * 16) ^ swz));                \
        bf16x8 av01 = *(const bf16x8*)(vb_ + (( 64 + 32 + l5 * 16) ^ swz));                \
        bf16x8 av10 = *(const bf16x8*)(vb_ + ((128 + 64 +  0 + l5 * 16) ^ swz));           \
        bf16x8 av11 = *(const bf16x8*)(vb_ + ((128 + 64 + 32 + l5 * 16) ^ swz));           \
        acc_o0 = __builtin_amdgcn_mfma_f32_32x32x16_bf16(av00, pf0, acc_o0, 0, 0, 0);      \
        acc_o1 = __builtin_amdgcn_mfma_f32_32x32x16_bf16(av10, pf0, acc_o1, 0, 0, 0);      \
        acc_o0 = __builtin_amdgcn_mfma_f32_32x32x16_bf16(av01, pf1, acc_o0, 0, 0, 0);      \
        acc_o1 = __builtin_amdgcn_mfma_f32_32x32x16_bf16(av11, pf1, acc_o1, 0, 0, 0);      \
      }                                                                                    \
    } while (0)

  // counted-vmcnt double-buffer pipeline: tiles t and t+1 always in flight.
  STAGE(0, 0);
  STAGE(1, 1);

  for (int t2 = 0; t2 < NT / 2 - 1; ++t2) {
    WAITVM(4);                          // tile 2*t2 landed (own 4 loads)
    __builtin_amdgcn_s_barrier();       // all waves' loads landed
    TILE(0);
    __builtin_amdgcn_s_barrier();       // all waves done reading buf 0
    STAGE(2 * t2 + 2, 0);
    WAITVM(4);                          // tile 2*t2+1 landed
    __builtin_amdgcn_s_barrier();
    TILE(1);
    __builtin_amdgcn_s_barrier();
    STAGE(2 * t2 + 3, 1);
  }
  // tail: tiles NT-2, NT-1 (no further prefetch)
  WAITVM(4);
  __builtin_amdgcn_s_barrier();
  TILE(0);
  WAITVM(0);
  __builtin_amdgcn_s_barrier();
  TILE(1);
  #undef TILE
  #undef STAGE

  // ---- epilogue: finish l within wave, combine key halves via LDS, write Oat ----
  l_acc += __shfl_xor(l_acc, 32);       // l for q = q0 + l31 over this key half

  __syncthreads();                      // all tile reads drained; smem reusable
  float* cO = (float*)smem;             // [qw][32][64] fp32 = 32 KB
  float* cL = (float*)(smem + 32768);   // [qw][64]
  if (kh == 1) {
    #pragma unroll
    for (int r = 0; r < 16; ++r) {
      cO[(qw * 32 + r) * 64 + lane] = acc_o0[r];
      cO[(qw * 32 + 16 + r) * 64 + lane] = acc_o1[r];
    }
    cL[qw * 64 + lane] = l_acc;
  }
  __syncthreads();
  if (kh == 0) {
    #pragma unroll
    for (int r = 0; r < 16; ++r) {
      acc_o0[r] += cO[(qw * 32 + r) * 64 + lane];
      acc_o1[r] += cO[(qw * 32 + 16 + r) * 64 + lane];
    }
    l_acc += cL[qw * 64 + lane];
    const float invl = __builtin_amdgcn_rcpf(l_acc);
    const int bb = bh >> 4, h = bh & 15;
    bf16_t* op = Oat + ((size_t)bb * SEQ + q0 + l31) * DMODEL + h * DHEAD;
    #pragma unroll
    for (int blk = 0; blk < 2; ++blk) {
      const f32x16& ao = blk ? acc_o1 : acc_o0;
      #pragma unroll
      for (int g = 0; g < 4; ++g) {
        bf16x4 ov;
        ov[0] = (bf16_t)(ao[4 * g + 0] * invl);
        ov[1] = (bf16_t)(ao[4 * g + 1] * invl);
        ov[2] = (bf16_t)(ao[4 * g + 2] * invl);
        ov[3] = (bf16_t)(ao[4 * g + 3] * invl);
        *(bf16x4*)(op + blk * 32 + 8 * g + 4 * l5) = ov;
      }
    }
  }
}

extern "C" void kernel_launch(void* const* d_in, const int* in_sizes, int n_in,
                              void* d_out, int out_size, void* d_ws, size_t ws_size,
                              hipStream_t stream)
{
  const float* H  = (const float*)d_in[0];
  const float* Wq = (const float*)d_in[1];
  const float* bq = (const float*)d_in[2];
  const float* Wk = (const float*)d_in[3];
  const float* bk = (const float*)d_in[4];
  const float* Wv = (const float*)d_in[5];
  const float* bv = (const float*)d_in[6];
  const float* Wo = (const float*)d_in[7];
  const float* bo = (const float*)d_in[8];
  float* out = (float*)d_out;

  char* ws = (char*)d_ws;
  bf16_t* Hb  = (bf16_t*)(ws);                    // 8 MB  [B*S][1024]
  bf16_t* Wqb = (bf16_t*)(ws + (8u << 20));       // 2 MB each
  bf16_t* Wkb = (bf16_t*)(ws + (10u << 20));
  bf16_t* Wvb = (bf16_t*)(ws + (12u << 20));
  bf16_t* Wob = (bf16_t*)(ws + (14u << 20));
  bf16_t* Qbf = (bf16_t*)(ws + (16u << 20));      // 8 MB  [BH][S][64]
  bf16_t* Kbf = (bf16_t*)(ws + (24u << 20));      // 8 MB  [BH][S][64]
  bf16_t* Vtb = (bf16_t*)(ws + (32u << 20));      // 8 MB  [BH][64][S]
  bf16_t* Oat = (bf16_t*)(ws + (40u << 20));      // 8 MB  [B][S][1024]

  // fp32 -> bf16 converts (single launch)
  cvt_all_kernel<<<8192, 256, 0, stream>>>(H, Wq, Wk, Wv, Wo, Hb, Wqb, Wkb, Wvb, Wob);

  // Q/K/V projections + bias + per-head normalize -> bf16 Q,K,[V^T]
  gemm_bt_kernel<1><<<dim3(8, 32, 3), 256, 0, stream>>>(
      Hb, Wqb, Wkb, Wvb, bq, bk, bv, Qbf, Kbf, Vtb);

  // MFMA spherical flash attention (8-wave, in-block key-split, counted-vmcnt pipeline)
  mfma_attn_kernel<<<512, 512, 0, stream>>>(Qbf, Kbf, Vtb, Oat);

  // output projection -> d_out fp32 [B][S][1024]
  gemm_bt_kernel<0><<<dim3(8, 32, 1), 256, 0, stream>>>(
      Oat, Wob, Wob, Wob, bo, bo, bo, out, out, out);
}

// Round 15
// 134.954 us; speedup vs baseline: 1.5204x; 1.0089x over previous
//
#include <hip/hip_runtime.h>
#include <hip/hip_bf16.h>

typedef __bf16 bf16_t;
typedef __bf16 bf16x8 __attribute__((ext_vector_type(8)));
typedef __bf16 bf16x4 __attribute__((ext_vector_type(4)));
typedef float f32x2 __attribute__((ext_vector_type(2)));
typedef float f32x4 __attribute__((ext_vector_type(4)));
typedef float f32x16 __attribute__((ext_vector_type(16)));

#define NB 2
#define SEQ 2048
#define DMODEL 1024
#define NHEAD 16
#define DHEAD 64

__device__ inline void gload_lds16(const void* g, void* lds) {
  __builtin_amdgcn_global_load_lds((const __attribute__((address_space(1))) void*)g,
                                   (__attribute__((address_space(3))) void*)lds,
                                   16, 0, 0);
}

// ---------------- fused fp32 -> bf16 convert (H + 4 weights, one launch) ----------------
__global__ __launch_bounds__(256) void cvt_all_kernel(
    const float* __restrict__ H,  const float* __restrict__ Wq, const float* __restrict__ Wk,
    const float* __restrict__ Wv, const float* __restrict__ Wo,
    bf16_t* __restrict__ Hb, bf16_t* __restrict__ Wqb, bf16_t* __restrict__ Wkb,
    bf16_t* __restrict__ Wvb, bf16_t* __restrict__ Wob)
{
  const int b = blockIdx.x;
  const float* src; bf16_t* dst; int idx;
  if (b < 4096) { src = H; dst = Hb; idx = b; }
  else {
    const int r = b - 4096; const int s = r >> 10; idx = r & 1023;
    src = (s == 0) ? Wq : (s == 1) ? Wk : (s == 2) ? Wv : Wo;
    dst = (s == 0) ? Wqb : (s == 1) ? Wkb : (s == 2) ? Wvb : Wob;
  }
  const int i = idx * 256 + threadIdx.x;
  float4 v = ((const float4*)src)[i];
  bf16x4 o;
  o[0] = (bf16_t)v.x; o[1] = (bf16_t)v.y; o[2] = (bf16_t)v.z; o[3] = (bf16_t)v.w;
  ((bf16x4*)dst)[i] = o;
}

// ---------------- bf16 TN GEMM: C[M][N] = A[M][K] * W[N][K]^T + bias ----------------
// Tile BM x 128, BK=64, XOR-swizzled LDS, 4 waves (2x2), 16x16x32 MFMA.
// MODE 0: plain fp32 out (BM=64 for occupancy: small-N output projection).
// MODE 1 (BM=128): per-head normalize; z=0/1 -> bf16 Q/K [BH][S][64];
//                  z=2 -> bf16 V^T [BH][64][S] via LDS-transposed coalesced epilogue.
template<int MODE, int BM>
__global__ __launch_bounds__(256) void gemm_bt_kernel(
    const bf16_t* __restrict__ A,
    const bf16_t* __restrict__ W0, const bf16_t* __restrict__ W1, const bf16_t* __restrict__ W2,
    const float* __restrict__ bias0, const float* __restrict__ bias1, const float* __restrict__ bias2,
    void* out0, void* out1, void* out2)
{
  constexpr int MF = BM / 32;          // m-fragments per wave
  __shared__ bf16_t As[BM * 64];       // [row][64 bf16 = 128B], XOR-swizzled
  __shared__ bf16_t Bs[128 * 64];
  const int tid = threadIdx.x;
  const int lane = tid & 63;
  const int w = tid >> 6;
  const int mt = blockIdx.y, nt = blockIdx.x, z = blockIdx.z;
  const bf16_t* Wp = (z == 0) ? W0 : ((z == 1) ? W1 : W2);
  const float* bp  = (z == 0) ? bias0 : ((z == 1) ? bias1 : bias2);

  const int wr = w & 1, wc = w >> 1;
  const int fr = lane & 15, fq = lane >> 4;

  const int r_in = lane >> 3;
  const int cswz = ((lane & 7) ^ (r_in & 7)) << 4;

  f32x4 acc[MF][4] = {};

  const char* Ab = (const char*)(A + (size_t)mt * BM * DMODEL);
  const char* Bb = (const char*)(Wp + (size_t)nt * 128 * DMODEL);

  for (int kt = 0; kt < DMODEL / 64; ++kt) {
    const size_t k0b = (size_t)kt * 128;
    #pragma unroll
    for (int i = 0; i < MF; ++i) {
      const size_t rowA = (size_t)(w * (BM / 4) + i * 8 + r_in);
      gload_lds16(Ab + rowA * (DMODEL * 2) + k0b + cswz,
                  (char*)As + (unsigned)(w * (BM * 32) + i * 1024));
    }
    #pragma unroll
    for (int i = 0; i < 4; ++i) {
      const size_t rowB = (size_t)(w * 32 + i * 8 + r_in);
      gload_lds16(Bb + rowB * (DMODEL * 2) + k0b + cswz,
                  (char*)Bs + (unsigned)(w * 4096 + i * 1024));
    }
    __syncthreads();

    bf16x8 a[MF][2], b[4][2];
    #pragma unroll
    for (int m = 0; m < MF; ++m)
      #pragma unroll
      for (int ks = 0; ks < 2; ++ks)
        a[m][ks] = *(const bf16x8*)((const char*)As + (wr * (BM / 2) + m * 16 + fr) * 128 +
                                    ((ks * 64 + fq * 16) ^ ((fr & 7) << 4)));
    #pragma unroll
    for (int n = 0; n < 4; ++n)
      #pragma unroll
      for (int ks = 0; ks < 2; ++ks)
        b[n][ks] = *(const bf16x8*)((const char*)Bs + (wc * 64 + n * 16 + fr) * 128 +
                                    ((ks * 64 + fq * 16) ^ ((fr & 7) << 4)));
    __builtin_amdgcn_s_setprio(1);
    #pragma unroll
    for (int m = 0; m < MF; ++m)
      #pragma unroll
      for (int n = 0; n < 4; ++n)
        #pragma unroll
        for (int ks = 0; ks < 2; ++ks)
          acc[m][n] = __builtin_amdgcn_mfma_f32_16x16x32_bf16(a[m][ks], b[n][ks], acc[m][n], 0, 0, 0);
    __builtin_amdgcn_s_setprio(0);
    __syncthreads();
  }

  float bv[4];
  const int cb = nt * 128 + wc * 64;
  #pragma unroll
  for (int n = 0; n < 4; ++n) bv[n] = bp[cb + n * 16 + fr];

  if constexpr (MODE == 0) {
    float* outp = (float*)out0;
    #pragma unroll
    for (int m = 0; m < MF; ++m) {
      #pragma unroll
      for (int j = 0; j < 4; ++j) {
        const int row = mt * BM + wr * (BM / 2) + m * 16 + fq * 4 + j;
        float* orow = outp + (size_t)row * DMODEL + cb;
        #pragma unroll
        for (int n = 0; n < 4; ++n)
          orow[n * 16 + fr] = acc[m][n][j] + bv[n];
      }
    }
  } else {
    const int h = nt * 2 + wc;
    if (z < 2) {
      #pragma unroll
      for (int m = 0; m < MF; ++m) {
        #pragma unroll
        for (int j = 0; j < 4; ++j) {
          float v0 = acc[m][0][j] + bv[0];
          float v1 = acc[m][1][j] + bv[1];
          float v2 = acc[m][2][j] + bv[2];
          float v3 = acc[m][3][j] + bv[3];
          float ss = v0 * v0 + v1 * v1 + v2 * v2 + v3 * v3;
          ss += __shfl_xor(ss, 1);
          ss += __shfl_xor(ss, 2);
          ss += __shfl_xor(ss, 4);
          ss += __shfl_xor(ss, 8);
          const float inv = 1.0f / fmaxf(sqrtf(ss), 1e-10f);
          const int row = mt * BM + wr * (BM / 2) + m * 16 + fq * 4 + j;
          const int bb = row >> 11, sr = row & (SEQ - 1);
          bf16_t* op = ((z == 0) ? (bf16_t*)out0 : (bf16_t*)out1)
                       + (((size_t)(bb * NHEAD + h)) * SEQ + sr) * DHEAD;
          op[0 * 16 + fr] = (bf16_t)(v0 * inv);
          op[1 * 16 + fr] = (bf16_t)(v1 * inv);
          op[2 * 16 + fr] = (bf16_t)(v2 * inv);
          op[3 * 16 + fr] = (bf16_t)(v3 * inv);
        }
      }
    } else {
      // V path (BM=128): normalize, stage [128 seq][128 dh] bf16 tile in LDS (As = rows
      // 0..63, Bs = rows 64..127), then write V^T with coalesced 16B stores.
      bf16_t* dsth = wr ? Bs : As;
      #pragma unroll
      for (int m = 0; m < MF; ++m) {
        #pragma unroll
        for (int j = 0; j < 4; ++j) {
          float v0 = acc[m][0][j] + bv[0];
          float v1 = acc[m][1][j] + bv[1];
          float v2 = acc[m][2][j] + bv[2];
          float v3 = acc[m][3][j] + bv[3];
          float ss = v0 * v0 + v1 * v1 + v2 * v2 + v3 * v3;
          ss += __shfl_xor(ss, 1);
          ss += __shfl_xor(ss, 2);
          ss += __shfl_xor(ss, 4);
          ss += __shfl_xor(ss, 8);
          const float inv = 1.0f / fmaxf(sqrtf(ss), 1e-10f);
          const int r64 = m * 16 + fq * 4 + j;           // seq-row within half
          dsth[r64 * 128 + wc * 64 + 0 * 16 + fr] = (bf16_t)(v0 * inv);
          dsth[r64 * 128 + wc * 64 + 1 * 16 + fr] = (bf16_t)(v1 * inv);
          dsth[r64 * 128 + wc * 64 + 2 * 16 + fr] = (bf16_t)(v2 * inv);
          dsth[r64 * 128 + wc * 64 + 3 * 16 + fr] = (bf16_t)(v3 * inv);
        }
      }
      __syncthreads();
      const int bb16 = (mt >> 4) * 16;       // batch*NHEAD base
      const int srbase = (mt & 15) * 128;    // seq base of this tile
      #pragma unroll
      for (int p = 0; p < 8; ++p) {
        const int id = p * 256 + tid;        // 0..2047 chunk id
        const int c = id >> 4;               // dh-col 0..127
        const int sc = (id & 15) * 8;        // seq offset 0..120
        const bf16_t* srch = (sc < 64) ? As : Bs;
        bf16x8 vv;
        #pragma unroll
        for (int i = 0; i < 8; ++i)
          vv[i] = srch[((sc & 63) + i) * 128 + c];
        const int hh = nt * 2 + (c >> 6);
        const int dh = c & 63;
        bf16_t* gp = (bf16_t*)out2 + (((size_t)(bb16 + hh)) * 64 + dh) * (size_t)SEQ + srbase + sc;
        *(bf16x8*)gp = vv;
      }
    }
  }
}

// ---------------- MFMA spherical flash attention: 8-wave, in-block key-split ----------
// Block = 512 thr = 8 waves: qw = w&3 (4 x 32 q-rows = 128 q), kh = w>>2 (2 x 1024 keys).
// LDS 64KB: [kh][buf][ K 8KB | V 8KB ], 64-key tiles, [32 rows][256B], c ^= (row&15)<<4.
// Counted-vmcnt double-buffer pipeline. Swapped QK^T (S[key][q], q=lane&31), P via
// cvt_pk + permlane32_swap, PV transposed. Score math vectorized over f32x16.
#define PSWAP(x, y) asm("v_permlane32_swap_b32 %0, %1" : "+v"(x), "+v"(y))
#define CVTPK(d, a, b) asm("v_cvt_pk_bf16_f32 %0, %1, %2" : "=v"(d) : "v"(a), "v"(b))
#define WAITVM(n) asm volatile("s_waitcnt vmcnt(" #n ")" ::: "memory")

__device__ inline f32x16 sp16(float x) {
  f32x16 v;
  #pragma unroll
  for (int i = 0; i < 16; ++i) v[i] = x;
  return v;
}

// score transform w = exp(asin(c)/8) (scale-invariant, pure FMA) on the whole f32x16
// accumulator, then pack to the PV B-fragment pair via cvt_pk + permlane32_swap.
__device__ inline void score_pack(const f32x16& accp, float& l_acc, bf16x8& pf0, bf16x8& pf1) {
  const f32x16 c2 = accp * accp;
  f32x16 a = __builtin_elementwise_fma(c2, sp16(0.00379774f), sp16(0.00558036f));
  a = __builtin_elementwise_fma(c2, a, sp16(0.00937500f));
  a = __builtin_elementwise_fma(c2, a, sp16(0.02083333f));
  a = __builtin_elementwise_fma(c2, a, sp16(0.12500000f));
  const f32x16 s = a * accp;                              // asin(c)/8
  f32x16 e = __builtin_elementwise_fma(s, sp16(0.16666667f), sp16(0.5f));
  e = __builtin_elementwise_fma(s, e, sp16(1.0f));
  e = __builtin_elementwise_fma(s, e, sp16(1.0f));        // exp(s), deg-3
  const float t0 = (e[0] + e[1]) + (e[2] + e[3]);
  const float t1 = (e[4] + e[5]) + (e[6] + e[7]);
  const float t2 = (e[8] + e[9]) + (e[10] + e[11]);
  const float t3 = (e[12] + e[13]) + (e[14] + e[15]);
  l_acc += (t0 + t1) + (t2 + t3);
  unsigned dwA0, dwA1, dwA2, dwA3, dwB0, dwB1, dwB2, dwB3;
  CVTPK(dwA0, e[0], e[1]);   CVTPK(dwB0, e[2], e[3]);
  CVTPK(dwA1, e[4], e[5]);   CVTPK(dwB1, e[6], e[7]);
  CVTPK(dwA2, e[8], e[9]);   CVTPK(dwB2, e[10], e[11]);
  CVTPK(dwA3, e[12], e[13]); CVTPK(dwB3, e[14], e[15]);
  PSWAP(dwA0, dwA1);  PSWAP(dwB0, dwB1);
  PSWAP(dwA2, dwA3);  PSWAP(dwB2, dwB3);
  typedef unsigned u32x4_ __attribute__((ext_vector_type(4)));
  u32x4_ t0_ = { dwA0, dwB0, dwA1, dwB1 };
  u32x4_ t1_ = { dwA2, dwB2, dwA3, dwB3 };
  pf0 = __builtin_bit_cast(bf16x8, t0_);
  pf1 = __builtin_bit_cast(bf16x8, t1_);
}

__global__ __launch_bounds__(512, 2) void mfma_attn_kernel(
    const bf16_t* __restrict__ Qb, const bf16_t* __restrict__ Kb,
    const bf16_t* __restrict__ Vt, bf16_t* __restrict__ Oat)
{
  __shared__ char smem[65536];   // [kh][buf][ K 8KB | V 8KB ]

  const int tid = threadIdx.x;
  const int lane = tid & 63;
  const int w = tid >> 6;
  const int qw = w & 3, kh = w >> 2;
  const int l31 = lane & 31, l5 = lane >> 5;

  // grid 512; XCD-aware: xcd gets heads 4*xcd..4*xcd+3 (L2 set ~2MB/XCD)
  const int p = blockIdx.x;
  const int xcd = p & 7;
  const int j = p >> 3;                 // 0..63
  const int bh = xcd * 4 + (j >> 4);
  const int qt = j & 15;
  const int q0 = qt * 128 + qw * 32;
  const int NT = 16;                    // 64-key tiles per key-half

  // persistent Q B-fragments: lane holds Q[q=q0+l31][seg*16 + l5*8 .. +7]
  const bf16_t* Qp = Qb + ((size_t)bh * SEQ + q0 + l31) * DHEAD + l5 * 8;
  bf16x8 b_q[4];
  #pragma unroll
  for (int m = 0; m < 4; ++m)
    b_q[m] = *(const bf16x8*)(Qp + m * 16);

  const char* KbaseH = (const char*)(Kb + (size_t)bh * SEQ * DHEAD) + (size_t)kh * 1024 * DHEAD * 2;
  const char* VbaseH = (const char*)(Vt + (size_t)bh * DHEAD * SEQ) + (size_t)kh * 1024 * 2;

  // staging: 8 chunks of 1KB per K (resp. V) tile; q-wave qw owns chunks 2qw, 2qw+1
  const int chA = 2 * qw, chB = 2 * qw + 1;
  int koffA, koffB, voffA, voffB;
  {
    const int rA = chA * 4 + (lane >> 4), rB = chB * 4 + (lane >> 4);
    const int c = (lane & 15) * 16;
    const int cpA = c ^ ((rA & 15) << 4), cpB = c ^ ((rB & 15) << 4);
    koffA = (rA + ((cpA >> 7) << 5)) * 128 + (cpA & 127);
    koffB = (rB + ((cpB >> 7) << 5)) * 128 + (cpB & 127);
    voffA = (rA + ((cpA >> 7) << 5)) * (SEQ * 2) + (cpA & 127);
    voffB = (rB + ((cpB >> 7) << 5)) * (SEQ * 2) + (cpB & 127);
  }
  const unsigned stKA = (unsigned)__builtin_amdgcn_readfirstlane(kh * 32768 + chA * 1024);
  const unsigned stKB = (unsigned)__builtin_amdgcn_readfirstlane(kh * 32768 + chB * 1024);
  const unsigned rb0  = (unsigned)__builtin_amdgcn_readfirstlane(kh * 32768);

  const int swz = (l31 & 15) << 4;
  const unsigned kRow = l31 * 256;

  f32x16 acc_o0 = {}, acc_o1 = {};
  float l_acc = 0.0f;

  #define STAGE(t, buf)                                                                    \
    do {                                                                                   \
      const char* Kt_ = KbaseH + (size_t)(t) * 8192;                                       \
      const char* Vc_ = VbaseH + (size_t)(t) * 128;                                        \
      gload_lds16(Kt_ + koffA, smem + stKA + (buf) * 16384);                               \
      gload_lds16(Kt_ + koffB, smem + stKB + (buf) * 16384);                               \
      gload_lds16(Vc_ + voffA, smem + stKA + (buf) * 16384 + 8192);                        \
      gload_lds16(Vc_ + voffB, smem + stKB + (buf) * 16384 + 8192);                        \
    } while (0)

  // one 64-key tile: QK of both 32-key chunks interleaved (independent accp0/accp1
  // chains), then per-chunk score+PV with PV alternating acc_o0/acc_o1 (depth-2).
  #define TILE(buf)                                                                        \
    do {                                                                                   \
      const char* kb_ = smem + rb0 + (buf) * 16384 + kRow;                                 \
      const char* vb_ = smem + rb0 + (buf) * 16384 + 8192 + kRow;                          \
      f32x16 accp0 = {}, accp1 = {};                                                       \
      _Pragma("unroll")                                                                    \
      for (int m = 0; m < 4; ++m) {                                                        \
        bf16x8 akA = *(const bf16x8*)(kb_ + ((m * 32 + l5 * 16) ^ swz));                   \
        bf16x8 akB = *(const bf16x8*)(kb_ + ((128 + m * 32 + l5 * 16) ^ swz));             \
        accp0 = __builtin_amdgcn_mfma_f32_32x32x16_bf16(akA, b_q[m], accp0, 0, 0, 0);      \
        accp1 = __builtin_amdgcn_mfma_f32_32x32x16_bf16(akB, b_q[m], accp1, 0, 0, 0);      \
      }                                                                                    \
      {                                                                                    \
        bf16x8 pf0, pf1;                                                                   \
        score_pack(accp0, l_acc, pf0, pf1);                                                \
        bf16x8 av00 = *(const bf16x8*)(vb_ + ((  0 + l5 * 16) ^ swz));                     \
        bf16x8 av01 = *(const bf16x8*)(vb_ + (( 32 + l5 * 16) ^ swz));                     \
        bf16x8 av10 = *(const bf16x8*)(vb_ + ((128 +  0 + l5 * 16) ^ swz));                \
        bf16x8 av11 = *(const bf16x8*)(vb_ + ((128 + 32 + l5 * 16) ^ swz));                \
        acc_o0 = __builtin_amdgcn_mfma_f32_32x32x16_bf16(av00, pf0, acc_o0, 0, 0, 0);      \
        acc_o1 = __builtin_amdgcn_mfma_f32_32x32x16_bf16(av10, pf0, acc_o1, 0, 0, 0);      \
        acc_o0 = __builtin_amdgcn_mfma_f32_32x32x16_bf16(av01, pf1, acc_o0, 0, 0, 0);      \
        acc_o1 = __builtin_amdgcn_mfma_f32_32x32x16_bf16(av11, pf1, acc_o1, 0, 0, 0);      \
      }                                                                                    \
      {                                                                                    \
        bf16x8 pf0, pf1;                                                                   \
        score_pack(accp1, l_acc, pf0, pf1);                                                \
        bf16x8 av00 = *(const bf16x8*)(vb_ + (( 64 +  0 + l5 * 16) ^ swz));                \
        bf16x8 av01 = *(const bf16x8*)(vb_ + (( 64 + 32 + l5 * 16) ^ swz));                \
        bf16x8 av10 = *(const bf16x8*)(vb_ + ((128 + 64 +  0 + l5 * 16) ^ swz));           \
        bf16x8 av11 = *(const bf16x8*)(vb_ + ((128 + 64 + 32 + l5 * 16) ^ swz));           \
        acc_o0 = __builtin_amdgcn_mfma_f32_32x32x16_bf16(av00, pf0, acc_o0, 0, 0, 0);      \
        acc_o1 = __builtin_amdgcn_mfma_f32_32x32x16_bf16(av10, pf0, acc_o1, 0, 0, 0);      \
        acc_o0 = __builtin_amdgcn_mfma_f32_32x32x16_bf16(av01, pf1, acc_o0, 0, 0, 0);      \
        acc_o1 = __builtin_amdgcn_mfma_f32_32x32x16_bf16(av11, pf1, acc_o1, 0, 0, 0);      \
      }                                                                                    \
    } while (0)

  // counted-vmcnt double-buffer pipeline: tiles t and t+1 always in flight.
  STAGE(0, 0);
  STAGE(1, 1);

  for (int t2 = 0; t2 < NT / 2 - 1; ++t2) {
    WAITVM(4);                          // tile 2*t2 landed (own 4 loads)
    __builtin_amdgcn_s_barrier();       // all waves' loads landed
    TILE(0);
    __builtin_amdgcn_s_barrier();       // all waves done reading buf 0
    STAGE(2 * t2 + 2, 0);
    WAITVM(4);                          // tile 2*t2+1 landed
    __builtin_amdgcn_s_barrier();
    TILE(1);
    __builtin_amdgcn_s_barrier();
    STAGE(2 * t2 + 3, 1);
  }
  // tail: tiles NT-2, NT-1 (no further prefetch)
  WAITVM(4);
  __builtin_amdgcn_s_barrier();
  TILE(0);
  WAITVM(0);
  __builtin_amdgcn_s_barrier();
  TILE(1);
  #undef TILE
  #undef STAGE

  // ---- epilogue: finish l within wave, combine key halves via LDS, write Oat ----
  l_acc += __shfl_xor(l_acc, 32);       // l for q = q0 + l31 over this key half

  __syncthreads();                      // all tile reads drained; smem reusable
  float* cO = (float*)smem;             // [qw][32][64] fp32 = 32 KB
  float* cL = (float*)(smem + 32768);   // [qw][64]
  if (kh == 1) {
    #pragma unroll
    for (int r = 0; r < 16; ++r) {
      cO[(qw * 32 + r) * 64 + lane] = acc_o0[r];
      cO[(qw * 32 + 16 + r) * 64 + lane] = acc_o1[r];
    }
    cL[qw * 64 + lane] = l_acc;
  }
  __syncthreads();
  if (kh == 0) {
    #pragma unroll
    for (int r = 0; r < 16; ++r) {
      acc_o0[r] += cO[(qw * 32 + r) * 64 + lane];
      acc_o1[r] += cO[(qw * 32 + 16 + r) * 64 + lane];
    }
    l_acc += cL[qw * 64 + lane];
    const float invl = __builtin_amdgcn_rcpf(l_acc);
    const int bb = bh >> 4, h = bh & 15;
    bf16_t* op = Oat + ((size_t)bb * SEQ + q0 + l31) * DMODEL + h * DHEAD;
    #pragma unroll
    for (int blk = 0; blk < 2; ++blk) {
      const f32x16& ao = blk ? acc_o1 : acc_o0;
      #pragma unroll
      for (int g = 0; g < 4; ++g) {
        bf16x4 ov;
        ov[0] = (bf16_t)(ao[4 * g + 0] * invl);
        ov[1] = (bf16_t)(ao[4 * g + 1] * invl);
        ov[2] = (bf16_t)(ao[4 * g + 2] * invl);
        ov[3] = (bf16_t)(ao[4 * g + 3] * invl);
        *(bf16x4*)(op + blk * 32 + 8 * g + 4 * l5) = ov;
      }
    }
  }
}

extern "C" void kernel_launch(void* const* d_in, const int* in_sizes, int n_in,
                              void* d_out, int out_size, void* d_ws, size_t ws_size,
                              hipStream_t stream)
{
  const float* H  = (const float*)d_in[0];
  const float* Wq = (const float*)d_in[1];
  const float* bq = (const float*)d_in[2];
  const float* Wk = (const float*)d_in[3];
  const float* bk = (const float*)d_in[4];
  const float* Wv = (const float*)d_in[5];
  const float* bv = (const float*)d_in[6];
  const float* Wo = (const float*)d_in[7];
  const float* bo = (const float*)d_in[8];
  float* out = (float*)d_out;

  char* ws = (char*)d_ws;
  bf16_t* Hb  = (bf16_t*)(ws);                    // 8 MB  [B*S][1024]
  bf16_t* Wqb = (bf16_t*)(ws + (8u << 20));       // 2 MB each
  bf16_t* Wkb = (bf16_t*)(ws + (10u << 20));
  bf16_t* Wvb = (bf16_t*)(ws + (12u << 20));
  bf16_t* Wob = (bf16_t*)(ws + (14u << 20));
  bf16_t* Qbf = (bf16_t*)(ws + (16u << 20));      // 8 MB  [BH][S][64]
  bf16_t* Kbf = (bf16_t*)(ws + (24u << 20));      // 8 MB  [BH][S][64]
  bf16_t* Vtb = (bf16_t*)(ws + (32u << 20));      // 8 MB  [BH][64][S]
  bf16_t* Oat = (bf16_t*)(ws + (40u << 20));      // 8 MB  [B][S][1024]

  // fp32 -> bf16 converts (single launch)
  cvt_all_kernel<<<8192, 256, 0, stream>>>(H, Wq, Wk, Wv, Wo, Hb, Wqb, Wkb, Wvb, Wob);

  // Q/K/V projections + bias + per-head normalize -> bf16 Q,K,[V^T]  (BM=128)
  gemm_bt_kernel<1, 128><<<dim3(8, 32, 3), 256, 0, stream>>>(
      Hb, Wqb, Wkb, Wvb, bq, bk, bv, Qbf, Kbf, Vtb);

  // MFMA spherical flash attention (8-wave, in-block key-split, counted-vmcnt pipeline)
  mfma_attn_kernel<<<512, 512, 0, stream>>>(Qbf, Kbf, Vtb, Oat);

  // output projection -> d_out fp32 [B][S][1024]  (BM=64: 512 blocks, 2/CU)
  gemm_bt_kernel<0, 64><<<dim3(8, 64, 1), 256, 0, stream>>>(
      Oat, Wob, Wob, Wob, bo, bo, bo, out, out, out);
}

// Round 16
// 122.976 us; speedup vs baseline: 1.6685x; 1.0974x over previous
//
#include <hip/hip_runtime.h>
#include <hip/hip_bf16.h>

typedef __bf16 bf16_t;
typedef __bf16 bf16x8 __attribute__((ext_vector_type(8)));
typedef __bf16 bf16x4 __attribute__((ext_vector_type(4)));
typedef float f32x2 __attribute__((ext_vector_type(2)));
typedef float f32x4 __attribute__((ext_vector_type(4)));
typedef float f32x16 __attribute__((ext_vector_type(16)));

#define NB 2
#define SEQ 2048
#define DMODEL 1024
#define NHEAD 16
#define DHEAD 64

#define PSWAP(x, y) asm("v_permlane32_swap_b32 %0, %1" : "+v"(x), "+v"(y))
#define CVTPK(d, a, b) asm("v_cvt_pk_bf16_f32 %0, %1, %2" : "=v"(d) : "v"(a), "v"(b))
#define WAITVM(n) asm volatile("s_waitcnt vmcnt(" #n ")" ::: "memory")

__device__ inline void gload_lds16(const void* g, void* lds) {
  __builtin_amdgcn_global_load_lds((const __attribute__((address_space(1))) void*)g,
                                   (__attribute__((address_space(3))) void*)lds,
                                   16, 0, 0);
}

// ---------------- fused fp32 -> bf16 convert (H + 4 weights, one launch) ----------------
__global__ __launch_bounds__(256) void cvt_all_kernel(
    const float* __restrict__ H,  const float* __restrict__ Wq, const float* __restrict__ Wk,
    const float* __restrict__ Wv, const float* __restrict__ Wo,
    bf16_t* __restrict__ Hb, bf16_t* __restrict__ Wqb, bf16_t* __restrict__ Wkb,
    bf16_t* __restrict__ Wvb, bf16_t* __restrict__ Wob)
{
  const int b = blockIdx.x;
  const float* src; bf16_t* dst; int idx;
  if (b < 4096) { src = H; dst = Hb; idx = b; }
  else {
    const int r = b - 4096; const int s = r >> 10; idx = r & 1023;
    src = (s == 0) ? Wq : (s == 1) ? Wk : (s == 2) ? Wv : Wo;
    dst = (s == 0) ? Wqb : (s == 1) ? Wkb : (s == 2) ? Wvb : Wob;
  }
  const int i = idx * 256 + threadIdx.x;
  float4 v = ((const float4*)src)[i];
  bf16x4 o;
  o[0] = (bf16_t)v.x; o[1] = (bf16_t)v.y; o[2] = (bf16_t)v.z; o[3] = (bf16_t)v.w;
  ((bf16x4*)dst)[i] = o;
}

// ---------------- bf16 TN GEMM, counted-vmcnt double-buffer (R10 skeleton) ------------
// Tile 64x128, BK=64, 4 waves (wr = w&1 row-half, wc = w>>1 col-half).
// LDS 48KB: A[2]x8KB @ 0, B[2]x16KB @ 16KB. 6 gload_lds per wave per K-step,
// s_waitcnt vmcnt(6) + raw s_barrier pipeline (tiles t, t+1 always in flight).
// MODE 0: fp32 out. MODE 1: per-head normalize; z=0/1 -> bf16 Q/K [BH][S][64];
// z=2 -> bf16 V^T [BH][64][S] via LDS-transposed coalesced epilogue.
template<int MODE>
__global__ __launch_bounds__(256, 3) void gemm_bt_kernel(
    const bf16_t* __restrict__ A,
    const bf16_t* __restrict__ W0, const bf16_t* __restrict__ W1, const bf16_t* __restrict__ W2,
    const float* __restrict__ bias0, const float* __restrict__ bias1, const float* __restrict__ bias2,
    void* out0, void* out1, void* out2)
{
  __shared__ char gsm[49152];
  const int tid = threadIdx.x;
  const int lane = tid & 63;
  const int w = tid >> 6;
  const int mt = blockIdx.y, nt = blockIdx.x, z = blockIdx.z;
  const bf16_t* Wp = (z == 0) ? W0 : ((z == 1) ? W1 : W2);
  const float* bp  = (z == 0) ? bias0 : ((z == 1) ? bias1 : bias2);

  const int wr = w & 1, wc = w >> 1;
  const int fr = lane & 15, fq = lane >> 4;

  const int r_in = lane >> 3;                       // row within 8-row chunk
  const int cswz = ((lane & 7) ^ (r_in & 7)) << 4;  // pre-swizzled source col byte

  f32x4 acc[2][4] = {};

  const char* Ab = (const char*)(A + (size_t)mt * 64 * DMODEL);
  const char* Bb = (const char*)(Wp + (size_t)nt * 128 * DMODEL);

  const unsigned aA0 = (unsigned)__builtin_amdgcn_readfirstlane(w * 2048);
  const unsigned bB0 = (unsigned)__builtin_amdgcn_readfirstlane(16384 + w * 4096);

  #define GSTAGE(t, buf)                                                                   \
    do {                                                                                   \
      const size_t k0b_ = (size_t)(t) * 128;                                               \
      _Pragma("unroll")                                                                    \
      for (int i = 0; i < 2; ++i) {                                                        \
        const size_t rowA_ = (size_t)(w * 16 + i * 8 + r_in);                              \
        gload_lds16(Ab + rowA_ * (DMODEL * 2) + k0b_ + cswz,                               \
                    gsm + aA0 + (buf) * 8192 + i * 1024);                                  \
      }                                                                                    \
      _Pragma("unroll")                                                                    \
      for (int i = 0; i < 4; ++i) {                                                        \
        const size_t rowB_ = (size_t)(w * 32 + i * 8 + r_in);                              \
        gload_lds16(Bb + rowB_ * (DMODEL * 2) + k0b_ + cswz,                               \
                    gsm + bB0 + (buf) * 16384 + i * 1024);                                 \
      }                                                                                    \
    } while (0)

  #define GCOMPUTE(buf)                                                                    \
    do {                                                                                   \
      const char* As_ = gsm + (buf) * 8192;                                                \
      const char* Bs_ = gsm + 16384 + (buf) * 16384;                                       \
      bf16x8 a_[2][2], b_[4][2];                                                           \
      _Pragma("unroll")                                                                    \
      for (int m = 0; m < 2; ++m)                                                          \
        _Pragma("unroll")                                                                  \
        for (int ks = 0; ks < 2; ++ks)                                                     \
          a_[m][ks] = *(const bf16x8*)(As_ + (wr * 32 + m * 16 + fr) * 128 +               \
                                       ((ks * 64 + fq * 16) ^ ((fr & 7) << 4)));           \
      _Pragma("unroll")                                                                    \
      for (int n = 0; n < 4; ++n)                                                          \
        _Pragma("unroll")                                                                  \
        for (int ks = 0; ks < 2; ++ks)                                                     \
          b_[n][ks] = *(const bf16x8*)(Bs_ + (wc * 64 + n * 16 + fr) * 128 +               \
                                       ((ks * 64 + fq * 16) ^ ((fr & 7) << 4)));           \
      __builtin_amdgcn_s_setprio(1);                                                       \
      _Pragma("unroll")                                                                    \
      for (int m = 0; m < 2; ++m)                                                          \
        _Pragma("unroll")                                                                  \
        for (int n = 0; n < 4; ++n)                                                        \
          _Pragma("unroll")                                                                \
          for (int ks = 0; ks < 2; ++ks)                                                   \
            acc[m][n] = __builtin_amdgcn_mfma_f32_16x16x32_bf16(a_[m][ks], b_[n][ks],      \
                                                                acc[m][n], 0, 0, 0);       \
      __builtin_amdgcn_s_setprio(0);                                                       \
    } while (0)

  // counted-vmcnt pipeline over 16 K-tiles
  GSTAGE(0, 0);
  GSTAGE(1, 1);
  for (int t2 = 0; t2 < 7; ++t2) {
    WAITVM(6);
    __builtin_amdgcn_s_barrier();
    GCOMPUTE(0);
    __builtin_amdgcn_s_barrier();
    GSTAGE(2 * t2 + 2, 0);
    WAITVM(6);
    __builtin_amdgcn_s_barrier();
    GCOMPUTE(1);
    __builtin_amdgcn_s_barrier();
    GSTAGE(2 * t2 + 3, 1);
  }
  WAITVM(6);
  __builtin_amdgcn_s_barrier();
  GCOMPUTE(0);
  WAITVM(0);
  __builtin_amdgcn_s_barrier();
  GCOMPUTE(1);
  #undef GCOMPUTE
  #undef GSTAGE

  float bv[4];
  const int cb = nt * 128 + wc * 64;
  #pragma unroll
  for (int n = 0; n < 4; ++n) bv[n] = bp[cb + n * 16 + fr];

  if constexpr (MODE == 0) {
    float* outp = (float*)out0;
    #pragma unroll
    for (int m = 0; m < 2; ++m) {
      #pragma unroll
      for (int j = 0; j < 4; ++j) {
        const int row = mt * 64 + wr * 32 + m * 16 + fq * 4 + j;
        float* orow = outp + (size_t)row * DMODEL + cb;
        #pragma unroll
        for (int n = 0; n < 4; ++n)
          orow[n * 16 + fr] = acc[m][n][j] + bv[n];
      }
    }
  } else {
    const int h = nt * 2 + wc;
    if (z < 2) {
      #pragma unroll
      for (int m = 0; m < 2; ++m) {
        #pragma unroll
        for (int j = 0; j < 4; ++j) {
          float v0 = acc[m][0][j] + bv[0];
          float v1 = acc[m][1][j] + bv[1];
          float v2 = acc[m][2][j] + bv[2];
          float v3 = acc[m][3][j] + bv[3];
          float ss = v0 * v0 + v1 * v1 + v2 * v2 + v3 * v3;
          ss += __shfl_xor(ss, 1);
          ss += __shfl_xor(ss, 2);
          ss += __shfl_xor(ss, 4);
          ss += __shfl_xor(ss, 8);
          const float inv = 1.0f / fmaxf(sqrtf(ss), 1e-10f);
          const int row = mt * 64 + wr * 32 + m * 16 + fq * 4 + j;
          const int bb = row >> 11, sr = row & (SEQ - 1);
          bf16_t* op = ((z == 0) ? (bf16_t*)out0 : (bf16_t*)out1)
                       + (((size_t)(bb * NHEAD + h)) * SEQ + sr) * DHEAD;
          op[0 * 16 + fr] = (bf16_t)(v0 * inv);
          op[1 * 16 + fr] = (bf16_t)(v1 * inv);
          op[2 * 16 + fr] = (bf16_t)(v2 * inv);
          op[3 * 16 + fr] = (bf16_t)(v3 * inv);
        }
      }
    } else {
      // V path: normalize, stage [64 seq][128 dh] bf16 tile in LDS (A-buffer region),
      // then write V^T with coalesced 16B stores (8 seq / store).
      __syncthreads();                    // all compute reads of gsm done
      bf16_t* vt = (bf16_t*)gsm;          // [64][128] = 16KB
      #pragma unroll
      for (int m = 0; m < 2; ++m) {
        #pragma unroll
        for (int j = 0; j < 4; ++j) {
          float v0 = acc[m][0][j] + bv[0];
          float v1 = acc[m][1][j] + bv[1];
          float v2 = acc[m][2][j] + bv[2];
          float v3 = acc[m][3][j] + bv[3];
          float ss = v0 * v0 + v1 * v1 + v2 * v2 + v3 * v3;
          ss += __shfl_xor(ss, 1);
          ss += __shfl_xor(ss, 2);
          ss += __shfl_xor(ss, 4);
          ss += __shfl_xor(ss, 8);
          const float inv = 1.0f / fmaxf(sqrtf(ss), 1e-10f);
          const int r64 = wr * 32 + m * 16 + fq * 4 + j;   // seq-row in tile
          vt[r64 * 128 + wc * 64 + 0 * 16 + fr] = (bf16_t)(v0 * inv);
          vt[r64 * 128 + wc * 64 + 1 * 16 + fr] = (bf16_t)(v1 * inv);
          vt[r64 * 128 + wc * 64 + 2 * 16 + fr] = (bf16_t)(v2 * inv);
          vt[r64 * 128 + wc * 64 + 3 * 16 + fr] = (bf16_t)(v3 * inv);
        }
      }
      __syncthreads();
      const int bb16 = (mt >> 5) * 16;       // batch*NHEAD base
      const int srbase = (mt & 31) * 64;     // seq base of this tile
      #pragma unroll
      for (int p = 0; p < 4; ++p) {
        const int id = p * 256 + tid;        // 0..1023 chunk id
        const int c = id >> 3;               // dh-col 0..127
        const int sc = (id & 7) * 8;         // seq offset 0..56
        bf16x8 vv;
        #pragma unroll
        for (int i = 0; i < 8; ++i)
          vv[i] = vt[(sc + i) * 128 + c];
        const int hh = nt * 2 + (c >> 6);
        const int dh = c & 63;
        bf16_t* gp = (bf16_t*)out2 + (((size_t)(bb16 + hh)) * 64 + dh) * (size_t)SEQ + srbase + sc;
        *(bf16x8*)gp = vv;
      }
    }
  }
}

// ---------------- MFMA spherical flash attention: 8-wave, in-block key-split ----------
// Block = 512 thr = 8 waves: qw = w&3 (4 x 32 q-rows = 128 q), kh = w>>2 (2 x 1024 keys).
// LDS 64KB: [kh][buf][ K 8KB | V 8KB ], 64-key tiles, [32 rows][256B], c ^= (row&15)<<4.
// Counted-vmcnt double-buffer pipeline. Swapped QK^T (S[key][q], q=lane&31), P via
// cvt_pk + permlane32_swap, PV transposed. Score math vectorized over f32x16.
__device__ inline f32x16 sp16(float x) {
  f32x16 v;
  #pragma unroll
  for (int i = 0; i < 16; ++i) v[i] = x;
  return v;
}

// score transform w = exp(asin(c)/8) (scale-invariant, pure FMA) on the whole f32x16
// accumulator, then pack to the PV B-fragment pair via cvt_pk + permlane32_swap.
__device__ inline void score_pack(const f32x16& accp, float& l_acc, bf16x8& pf0, bf16x8& pf1) {
  const f32x16 c2 = accp * accp;
  f32x16 a = __builtin_elementwise_fma(c2, sp16(0.00379774f), sp16(0.00558036f));
  a = __builtin_elementwise_fma(c2, a, sp16(0.00937500f));
  a = __builtin_elementwise_fma(c2, a, sp16(0.02083333f));
  a = __builtin_elementwise_fma(c2, a, sp16(0.12500000f));
  const f32x16 s = a * accp;                              // asin(c)/8
  f32x16 e = __builtin_elementwise_fma(s, sp16(0.16666667f), sp16(0.5f));
  e = __builtin_elementwise_fma(s, e, sp16(1.0f));
  e = __builtin_elementwise_fma(s, e, sp16(1.0f));        // exp(s), deg-3
  const float t0 = (e[0] + e[1]) + (e[2] + e[3]);
  const float t1 = (e[4] + e[5]) + (e[6] + e[7]);
  const float t2 = (e[8] + e[9]) + (e[10] + e[11]);
  const float t3 = (e[12] + e[13]) + (e[14] + e[15]);
  l_acc += (t0 + t1) + (t2 + t3);
  unsigned dwA0, dwA1, dwA2, dwA3, dwB0, dwB1, dwB2, dwB3;
  CVTPK(dwA0, e[0], e[1]);   CVTPK(dwB0, e[2], e[3]);
  CVTPK(dwA1, e[4], e[5]);   CVTPK(dwB1, e[6], e[7]);
  CVTPK(dwA2, e[8], e[9]);   CVTPK(dwB2, e[10], e[11]);
  CVTPK(dwA3, e[12], e[13]); CVTPK(dwB3, e[14], e[15]);
  PSWAP(dwA0, dwA1);  PSWAP(dwB0, dwB1);
  PSWAP(dwA2, dwA3);  PSWAP(dwB2, dwB3);
  typedef unsigned u32x4_ __attribute__((ext_vector_type(4)));
  u32x4_ t0_ = { dwA0, dwB0, dwA1, dwB1 };
  u32x4_ t1_ = { dwA2, dwB2, dwA3, dwB3 };
  pf0 = __builtin_bit_cast(bf16x8, t0_);
  pf1 = __builtin_bit_cast(bf16x8, t1_);
}

__global__ __launch_bounds__(512, 2) void mfma_attn_kernel(
    const bf16_t* __restrict__ Qb, const bf16_t* __restrict__ Kb,
    const bf16_t* __restrict__ Vt, bf16_t* __restrict__ Oat)
{
  __shared__ char smem[65536];   // [kh][buf][ K 8KB | V 8KB ]

  const int tid = threadIdx.x;
  const int lane = tid & 63;
  const int w = tid >> 6;
  const int qw = w & 3, kh = w >> 2;
  const int l31 = lane & 31, l5 = lane >> 5;

  // grid 512; XCD-aware: xcd gets heads 4*xcd..4*xcd+3 (L2 set ~2MB/XCD)
  const int p = blockIdx.x;
  const int xcd = p & 7;
  const int j = p >> 3;                 // 0..63
  const int bh = xcd * 4 + (j >> 4);
  const int qt = j & 15;
  const int q0 = qt * 128 + qw * 32;
  const int NT = 16;                    // 64-key tiles per key-half

  // persistent Q B-fragments: lane holds Q[q=q0+l31][seg*16 + l5*8 .. +7]
  const bf16_t* Qp = Qb + ((size_t)bh * SEQ + q0 + l31) * DHEAD + l5 * 8;
  bf16x8 b_q[4];
  #pragma unroll
  for (int m = 0; m < 4; ++m)
    b_q[m] = *(const bf16x8*)(Qp + m * 16);

  const char* KbaseH = (const char*)(Kb + (size_t)bh * SEQ * DHEAD) + (size_t)kh * 1024 * DHEAD * 2;
  const char* VbaseH = (const char*)(Vt + (size_t)bh * DHEAD * SEQ) + (size_t)kh * 1024 * 2;

  // staging: 8 chunks of 1KB per K (resp. V) tile; q-wave qw owns chunks 2qw, 2qw+1
  const int chA = 2 * qw, chB = 2 * qw + 1;
  int koffA, koffB, voffA, voffB;
  {
    const int rA = chA * 4 + (lane >> 4), rB = chB * 4 + (lane >> 4);
    const int c = (lane & 15) * 16;
    const int cpA = c ^ ((rA & 15) << 4), cpB = c ^ ((rB & 15) << 4);
    koffA = (rA + ((cpA >> 7) << 5)) * 128 + (cpA & 127);
    koffB = (rB + ((cpB >> 7) << 5)) * 128 + (cpB & 127);
    voffA = (rA + ((cpA >> 7) << 5)) * (SEQ * 2) + (cpA & 127);
    voffB = (rB + ((cpB >> 7) << 5)) * (SEQ * 2) + (cpB & 127);
  }
  const unsigned stKA = (unsigned)__builtin_amdgcn_readfirstlane(kh * 32768 + chA * 1024);
  const unsigned stKB = (unsigned)__builtin_amdgcn_readfirstlane(kh * 32768 + chB * 1024);
  const unsigned rb0  = (unsigned)__builtin_amdgcn_readfirstlane(kh * 32768);

  const int swz = (l31 & 15) << 4;
  const unsigned kRow = l31 * 256;

  f32x16 acc_o0 = {}, acc_o1 = {};
  float l_acc = 0.0f;

  #define STAGE(t, buf)                                                                    \
    do {                                                                                   \
      const char* Kt_ = KbaseH + (size_t)(t) * 8192;                                       \
      const char* Vc_ = VbaseH + (size_t)(t) * 128;                                        \
      gload_lds16(Kt_ + koffA, smem + stKA + (buf) * 16384);                               \
      gload_lds16(Kt_ + koffB, smem + stKB + (buf) * 16384);                               \
      gload_lds16(Vc_ + voffA, smem + stKA + (buf) * 16384 + 8192);                        \
      gload_lds16(Vc_ + voffB, smem + stKB + (buf) * 16384 + 8192);                        \
    } while (0)

  // one 64-key tile: QK of both 32-key chunks interleaved (independent accp0/accp1
  // chains), then per-chunk score+PV with PV alternating acc_o0/acc_o1 (depth-2).
  #define TILE(buf)                                                                        \
    do {                                                                                   \
      const char* kb_ = smem + rb0 + (buf) * 16384 + kRow;                                 \
      const char* vb_ = smem + rb0 + (buf) * 16384 + 8192 + kRow;                          \
      f32x16 accp0 = {}, accp1 = {};                                                       \
      _Pragma("unroll")                                                                    \
      for (int m = 0; m < 4; ++m) {                                                        \
        bf16x8 akA = *(const bf16x8*)(kb_ + ((m * 32 + l5 * 16) ^ swz));                   \
        bf16x8 akB = *(const bf16x8*)(kb_ + ((128 + m * 32 + l5 * 16) ^ swz));             \
        accp0 = __builtin_amdgcn_mfma_f32_32x32x16_bf16(akA, b_q[m], accp0, 0, 0, 0);      \
        accp1 = __builtin_amdgcn_mfma_f32_32x32x16_bf16(akB, b_q[m], accp1, 0, 0, 0);      \
      }                                                                                    \
      {                                                                                    \
        bf16x8 pf0, pf1;                                                                   \
        score_pack(accp0, l_acc, pf0, pf1);                                                \
        bf16x8 av00 = *(const bf16x8*)(vb_ + ((  0 + l5 * 16) ^ swz));                     \
        bf16x8 av01 = *(const bf16x8*)(vb_ + (( 32 + l5 * 16) ^ swz));                     \
        bf16x8 av10 = *(const bf16x8*)(vb_ + ((128 +  0 + l5 * 16) ^ swz));                \
        bf16x8 av11 = *(const bf16x8*)(vb_ + ((128 + 32 + l5 * 16) ^ swz));                \
        acc_o0 = __builtin_amdgcn_mfma_f32_32x32x16_bf16(av00, pf0, acc_o0, 0, 0, 0);      \
        acc_o1 = __builtin_amdgcn_mfma_f32_32x32x16_bf16(av10, pf0, acc_o1, 0, 0, 0);      \
        acc_o0 = __builtin_amdgcn_mfma_f32_32x32x16_bf16(av01, pf1, acc_o0, 0, 0, 0);      \
        acc_o1 = __builtin_amdgcn_mfma_f32_32x32x16_bf16(av11, pf1, acc_o1, 0, 0, 0);      \
      }                                                                                    \
      {                                                                                    \
        bf16x8 pf0, pf1;                                                                   \
        score_pack(accp1, l_acc, pf0, pf1);                                                \
        bf16x8 av00 = *(const bf16x8*)(vb_ + (( 64 +  0 + l5 * 16) ^ swz));                \
        bf16x8 av01 = *(const bf16x8*)(vb_ + (( 64 + 32 + l5 * 16) ^ swz));                \
        bf16x8 av10 = *(const bf16x8*)(vb_ + ((128 + 64 +  0 + l5 * 16) ^ swz));           \
        bf16x8 av11 = *(const bf16x8*)(vb_ + ((128 + 64 + 32 + l5 * 16) ^ swz));           \
        acc_o0 = __builtin_amdgcn_mfma_f32_32x32x16_bf16(av00, pf0, acc_o0, 0, 0, 0);      \
        acc_o1 = __builtin_amdgcn_mfma_f32_32x32x16_bf16(av10, pf0, acc_o1, 0, 0, 0);      \
        acc_o0 = __builtin_amdgcn_mfma_f32_32x32x16_bf16(av01, pf1, acc_o0, 0, 0, 0);      \
        acc_o1 = __builtin_amdgcn_mfma_f32_32x32x16_bf16(av11, pf1, acc_o1, 0, 0, 0);      \
      }                                                                                    \
    } while (0)

  // counted-vmcnt double-buffer pipeline: tiles t and t+1 always in flight.
  STAGE(0, 0);
  STAGE(1, 1);

  for (int t2 = 0; t2 < NT / 2 - 1; ++t2) {
    WAITVM(4);                          // tile 2*t2 landed (own 4 loads)
    __builtin_amdgcn_s_barrier();       // all waves' loads landed
    TILE(0);
    __builtin_amdgcn_s_barrier();       // all waves done reading buf 0
    STAGE(2 * t2 + 2, 0);
    WAITVM(4);                          // tile 2*t2+1 landed
    __builtin_amdgcn_s_barrier();
    TILE(1);
    __builtin_amdgcn_s_barrier();
    STAGE(2 * t2 + 3, 1);
  }
  // tail: tiles NT-2, NT-1 (no further prefetch)
  WAITVM(4);
  __builtin_amdgcn_s_barrier();
  TILE(0);
  WAITVM(0);
  __builtin_amdgcn_s_barrier();
  TILE(1);
  #undef TILE
  #undef STAGE

  // ---- epilogue: finish l within wave, combine key halves via LDS, write Oat ----
  l_acc += __shfl_xor(l_acc, 32);       // l for q = q0 + l31 over this key half

  __syncthreads();                      // all tile reads drained; smem reusable
  float* cO = (float*)smem;             // [qw][32][64] fp32 = 32 KB
  float* cL = (float*)(smem + 32768);   // [qw][64]
  if (kh == 1) {
    #pragma unroll
    for (int r = 0; r < 16; ++r) {
      cO[(qw * 32 + r) * 64 + lane] = acc_o0[r];
      cO[(qw * 32 + 16 + r) * 64 + lane] = acc_o1[r];
    }
    cL[qw * 64 + lane] = l_acc;
  }
  __syncthreads();
  if (kh == 0) {
    #pragma unroll
    for (int r = 0; r < 16; ++r) {
      acc_o0[r] += cO[(qw * 32 + r) * 64 + lane];
      acc_o1[r] += cO[(qw * 32 + 16 + r) * 64 + lane];
    }
    l_acc += cL[qw * 64 + lane];
    const float invl = __builtin_amdgcn_rcpf(l_acc);
    const int bb = bh >> 4, h = bh & 15;
    bf16_t* op = Oat + ((size_t)bb * SEQ + q0 + l31) * DMODEL + h * DHEAD;
    #pragma unroll
    for (int blk = 0; blk < 2; ++blk) {
      const f32x16& ao = blk ? acc_o1 : acc_o0;
      #pragma unroll
      for (int g = 0; g < 4; ++g) {
        bf16x4 ov;
        ov[0] = (bf16_t)(ao[4 * g + 0] * invl);
        ov[1] = (bf16_t)(ao[4 * g + 1] * invl);
        ov[2] = (bf16_t)(ao[4 * g + 2] * invl);
        ov[3] = (bf16_t)(ao[4 * g + 3] * invl);
        *(bf16x4*)(op + blk * 32 + 8 * g + 4 * l5) = ov;
      }
    }
  }
}

extern "C" void kernel_launch(void* const* d_in, const int* in_sizes, int n_in,
                              void* d_out, int out_size, void* d_ws, size_t ws_size,
                              hipStream_t stream)
{
  const float* H  = (const float*)d_in[0];
  const float* Wq = (const float*)d_in[1];
  const float* bq = (const float*)d_in[2];
  const float* Wk = (const float*)d_in[3];
  const float* bk = (const float*)d_in[4];
  const float* Wv = (const float*)d_in[5];
  const float* bv = (const float*)d_in[6];
  const float* Wo = (const float*)d_in[7];
  const float* bo = (const float*)d_in[8];
  float* out = (float*)d_out;

  char* ws = (char*)d_ws;
  bf16_t* Hb  = (bf16_t*)(ws);                    // 8 MB  [B*S][1024]
  bf16_t* Wqb = (bf16_t*)(ws + (8u << 20));       // 2 MB each
  bf16_t* Wkb = (bf16_t*)(ws + (10u << 20));
  bf16_t* Wvb = (bf16_t*)(ws + (12u << 20));
  bf16_t* Wob = (bf16_t*)(ws + (14u << 20));
  bf16_t* Qbf = (bf16_t*)(ws + (16u << 20));      // 8 MB  [BH][S][64]
  bf16_t* Kbf = (bf16_t*)(ws + (24u << 20));      // 8 MB  [BH][S][64]
  bf16_t* Vtb = (bf16_t*)(ws + (32u << 20));      // 8 MB  [BH][64][S]
  bf16_t* Oat = (bf16_t*)(ws + (40u << 20));      // 8 MB  [B][S][1024]

  // fp32 -> bf16 converts (single launch)
  cvt_all_kernel<<<8192, 256, 0, stream>>>(H, Wq, Wk, Wv, Wo, Hb, Wqb, Wkb, Wvb, Wob);

  // Q/K/V projections + bias + per-head normalize -> bf16 Q,K,[V^T]
  gemm_bt_kernel<1><<<dim3(8, 64, 3), 256, 0, stream>>>(
      Hb, Wqb, Wkb, Wvb, bq, bk, bv, Qbf, Kbf, Vtb);

  // MFMA spherical flash attention (8-wave, in-block key-split, counted-vmcnt pipeline)
  mfma_attn_kernel<<<512, 512, 0, stream>>>(Qbf, Kbf, Vtb, Oat);

  // output projection -> d_out fp32 [B][S][1024]
  gemm_bt_kernel<0><<<dim3(8, 64, 1), 256, 0, stream>>>(
      Oat, Wob, Wob, Wob, bo, bo, bo, out, out, out);
}